// Round 17
// baseline (1251.093 us; speedup 1.0000x reference)
//
#include <hip/hip_runtime.h>

#define NROWS 131072
#define KE 2048
#define CAND_CAP 4096

typedef unsigned long long u64_t;
typedef unsigned int u32;
typedef __attribute__((ext_vector_type(8))) short bf16x8;
typedef __attribute__((ext_vector_type(4))) float f32x4;

__device__ __forceinline__ unsigned f32_key(float f) {
  unsigned u = __float_as_uint(f);
  return (u & 0x80000000u) ? ~u : (u | 0x80000000u);
}

__device__ __forceinline__ unsigned short bf16_rne(float f) {
  unsigned u = __float_as_uint(f);
  u += 0x7FFFu + ((u >> 16) & 1u);
  return (unsigned short)(u >> 16);
}

// async global -> LDS: per-lane 16B src; dst = wave-uniform base + lane*16
__device__ __forceinline__ void gl_lds16(const void* g, const void* l) {
  __builtin_amdgcn_global_load_lds((const __attribute__((address_space(1))) u32*)g,
                                   (__attribute__((address_space(3))) u32*)l, 16, 0, 0);
}

// ---------------------------------------------------------------------------
// 64x64 tile f32 GEMM (UNCHANGED — enc1). MODE 0 only.
// ---------------------------------------------------------------------------
template <int MODE>
__global__ __launch_bounds__(256) void gemm64(
    const float* __restrict__ A, const float* __restrict__ B,
    const float* __restrict__ bias, float* __restrict__ C,
    int M, int N, int K,
    const int* __restrict__ gidx) {
  __shared__ __align__(16) float As[16][68];
  __shared__ __align__(16) float Bs[16][68];

  const int tid = threadIdx.x;
  const int tx = tid & 15;
  const int ty = tid >> 4;
  const int arow = blockIdx.x * 64;
  const int bcol = blockIdx.y * 64;

  const int lr = tid >> 2;
  const int lc = (tid & 3) * 4;
  int ga = arow + lr;
  if (MODE == 1) ga = gidx[ga];
  const float* Ap = A + (size_t)ga * K + lc;

  const int bkr = tid >> 4;
  const int bc4 = (tid & 15) * 4;
  const float* Bp = B + (size_t)bkr * N + bcol + bc4;

  float acc[4][4] = {};

  for (int kt = 0; kt < K; kt += 16) {
    float4 av = *reinterpret_cast<const float4*>(Ap);
    As[lc + 0][lr] = av.x;
    As[lc + 1][lr] = av.y;
    As[lc + 2][lr] = av.z;
    As[lc + 3][lr] = av.w;
    float4 bv = *reinterpret_cast<const float4*>(Bp);
    *reinterpret_cast<float4*>(&Bs[bkr][bc4]) = bv;
    Bp += (size_t)16 * N;
    Ap += 16;
    __syncthreads();
#pragma unroll
    for (int k = 0; k < 16; ++k) {
      float4 a = *reinterpret_cast<const float4*>(&As[k][ty * 4]);
      float4 b = *reinterpret_cast<const float4*>(&Bs[k][tx * 4]);
      acc[0][0] += a.x * b.x; acc[0][1] += a.x * b.y; acc[0][2] += a.x * b.z; acc[0][3] += a.x * b.w;
      acc[1][0] += a.y * b.x; acc[1][1] += a.y * b.y; acc[1][2] += a.y * b.z; acc[1][3] += a.y * b.w;
      acc[2][0] += a.z * b.x; acc[2][1] += a.z * b.y; acc[2][2] += a.z * b.z; acc[2][3] += a.z * b.w;
      acc[3][0] += a.w * b.x; acc[3][1] += a.w * b.y; acc[3][2] += a.w * b.z; acc[3][3] += a.w * b.w;
    }
    __syncthreads();
  }

#pragma unroll
  for (int i = 0; i < 4; ++i) {
    const int row = arow + ty * 4 + i;
    float4 v;
    v.x = fmaxf(acc[i][0] + bias[bcol + tx * 4 + 0], 0.f);
    v.y = fmaxf(acc[i][1] + bias[bcol + tx * 4 + 1], 0.f);
    v.z = fmaxf(acc[i][2] + bias[bcol + tx * 4 + 2], 0.f);
    v.w = fmaxf(acc[i][3] + bias[bcol + tx * 4 + 3], 0.f);
    *reinterpret_cast<float4*>(&C[(size_t)row * N + bcol + tx * 4]) = v;
  }
}

// ---------------------------------------------------------------------------
// 128x128 tile f32 GEMM (UNCHANGED — enc2/enc3). Mode 0 only instantiated.
// ---------------------------------------------------------------------------
template <int MODE>
__global__ __launch_bounds__(256) void gemm128(
    const float* __restrict__ A, const float* __restrict__ B,
    const float* __restrict__ bias, float* __restrict__ C,
    int N, int K,
    const int* __restrict__ gidx,
    const float* __restrict__ X,
    float* __restrict__ parts) {
  __shared__ __align__(16) char smem[17408];
  float (*As)[132] = (float(*)[132])smem;
  float (*Bs)[132] = (float(*)[132])(smem + 8448);

  const int tid = threadIdx.x;
  const int tx = tid & 15;
  const int ty = tid >> 4;
  const int arow = blockIdx.x * 128;
  const int bcol = blockIdx.y * 128;

  const int r0 = tid >> 2;
  const int r1 = r0 + 64;
  const int lc = (tid & 3) * 4;
  int ga0 = arow + r0, ga1 = arow + r1;
  if (MODE == 1) { ga0 = gidx[ga0]; ga1 = gidx[ga1]; }
  const float* Ap0 = A + (size_t)ga0 * K + lc;
  const float* Ap1 = A + (size_t)ga1 * K + lc;

  const int bk0 = tid >> 5;
  const int bc0 = (tid & 31) * 4;
  const float* Bp0 = B + (size_t)bk0 * N + bcol + bc0;
  const float* Bp1 = B + (size_t)(bk0 + 8) * N + bcol + bc0;

  float acc[8][8] = {};

  for (int kt = 0; kt < K; kt += 16) {
    float4 a0 = *reinterpret_cast<const float4*>(Ap0);
    float4 a1 = *reinterpret_cast<const float4*>(Ap1);
    As[lc + 0][r0] = a0.x; As[lc + 1][r0] = a0.y; As[lc + 2][r0] = a0.z; As[lc + 3][r0] = a0.w;
    As[lc + 0][r1] = a1.x; As[lc + 1][r1] = a1.y; As[lc + 2][r1] = a1.z; As[lc + 3][r1] = a1.w;
    float4 b0 = *reinterpret_cast<const float4*>(Bp0);
    float4 b1 = *reinterpret_cast<const float4*>(Bp1);
    *reinterpret_cast<float4*>(&Bs[bk0][bc0]) = b0;
    *reinterpret_cast<float4*>(&Bs[bk0 + 8][bc0]) = b1;
    Bp0 += (size_t)16 * N; Bp1 += (size_t)16 * N;
    Ap0 += 16; Ap1 += 16;
    __syncthreads();
#pragma unroll
    for (int k = 0; k < 16; ++k) {
      float4 av0 = *reinterpret_cast<const float4*>(&As[k][ty * 4]);
      float4 av1 = *reinterpret_cast<const float4*>(&As[k][64 + ty * 4]);
      float4 bv0 = *reinterpret_cast<const float4*>(&Bs[k][tx * 4]);
      float4 bv1 = *reinterpret_cast<const float4*>(&Bs[k][64 + tx * 4]);
      const float a[8] = {av0.x, av0.y, av0.z, av0.w, av1.x, av1.y, av1.z, av1.w};
      const float b[8] = {bv0.x, bv0.y, bv0.z, bv0.w, bv1.x, bv1.y, bv1.z, bv1.w};
#pragma unroll
      for (int i = 0; i < 8; ++i)
#pragma unroll
        for (int j = 0; j < 8; ++j) acc[i][j] += a[i] * b[j];
    }
    __syncthreads();
  }

#pragma unroll
  for (int i = 0; i < 8; ++i) {
    const int row = arow + (i >> 2) * 64 + ty * 4 + (i & 3);
    const int c0 = bcol + tx * 4;
    const int c1 = bcol + 64 + tx * 4;
    float4 v0, v1;
    v0.x = fmaxf(acc[i][0] + bias[c0 + 0], 0.f);
    v0.y = fmaxf(acc[i][1] + bias[c0 + 1], 0.f);
    v0.z = fmaxf(acc[i][2] + bias[c0 + 2], 0.f);
    v0.w = fmaxf(acc[i][3] + bias[c0 + 3], 0.f);
    v1.x = fmaxf(acc[i][4] + bias[c1 + 0], 0.f);
    v1.y = fmaxf(acc[i][5] + bias[c1 + 1], 0.f);
    v1.z = fmaxf(acc[i][6] + bias[c1 + 2], 0.f);
    v1.w = fmaxf(acc[i][7] + bias[c1 + 3], 0.f);
    *reinterpret_cast<float4*>(&C[(size_t)row * N + c0]) = v0;
    *reinterpret_cast<float4*>(&C[(size_t)row * N + c1]) = v1;
  }
}

// z16t for 256-row blocks (UNCHANGED from r14-16)
__global__ __launch_bounds__(256) void cvt_z16t(const float* __restrict__ z_e,
                                                unsigned short* __restrict__ z16t) {
  const int c = blockIdx.x * 256 + threadIdx.x;
  const int lane = c & 63;
  const int kb = (c >> 6) & 7;
  const int fr = (c >> 9) & 3;
  const int w = (c >> 11) & 3;
  const int rowblk = c >> 13;
  const int row = rowblk * 256 + w * 64 + fr * 16 + (lane & 15);
  const int k0 = kb * 32 + (lane >> 4) * 8;
  const float* p = z_e + (size_t)row * 256 + k0;
  const float4 v0 = *reinterpret_cast<const float4*>(p);
  const float4 v1 = *reinterpret_cast<const float4*>(p + 4);
  const float f[8] = {v0.x, v0.y, v0.z, v0.w, v1.x, v1.y, v1.z, v1.w};
  unsigned short s[8];
#pragma unroll
  for (int j = 0; j < 8; ++j) s[j] = bf16_rne(f[j]);
  uint4 o;
  o.x = (u32)s[0] | ((u32)s[1] << 16);
  o.y = (u32)s[2] | ((u32)s[3] << 16);
  o.z = (u32)s[4] | ((u32)s[5] << 16);
  o.w = (u32)s[6] | ((u32)s[7] << 16);
  *reinterpret_cast<uint4*>(z16t + (size_t)c * 8) = o;
}

// e16f: FRAGMENT-MAJOR emb tiles (UNCHANGED from r13-16)
__global__ __launch_bounds__(256) void cvt_e16f(const float* __restrict__ emb,
                                                unsigned short* __restrict__ e16f) {
  const int c = blockIdx.x * 256 + threadIdx.x;  // 65536 chunks
  const int l = c & 63;
  const int fc = (c >> 6) & 7;
  const int t = c >> 9;
  const int kb = t & 7;
  const int ct = t >> 3;
  const int col = ct * 128 + fc * 16 + (l & 15);
  const int k0 = kb * 32 + (l >> 4) * 8;
  const float* p = emb + (size_t)col * 256 + k0;
  const float4 v0 = *reinterpret_cast<const float4*>(p);
  const float4 v1 = *reinterpret_cast<const float4*>(p + 4);
  const float f[8] = {v0.x, v0.y, v0.z, v0.w, v1.x, v1.y, v1.z, v1.w};
  unsigned short s8[8];
#pragma unroll
  for (int j = 0; j < 8; ++j) s8[j] = bf16_rne(f[j]);
  uint4 o;
  o.x = (u32)s8[0] | ((u32)s8[1] << 16);
  o.y = (u32)s8[2] | ((u32)s8[3] << 16);
  o.z = (u32)s8[4] | ((u32)s8[5] << 16);
  o.w = (u32)s8[6] | ((u32)s8[7] << 16);
  *reinterpret_cast<uint4*>(e16f + (size_t)c * 8) = o;
}

// plain f32 -> bf16 row-major (emb16), 8 elems/thread
__global__ __launch_bounds__(256) void cvt_rows16(const float* __restrict__ src,
                                                  unsigned short* __restrict__ dst) {
  const int i = blockIdx.x * 256 + threadIdx.x;
  const float4 v0 = *reinterpret_cast<const float4*>(src + (size_t)i * 8);
  const float4 v1 = *reinterpret_cast<const float4*>(src + (size_t)i * 8 + 4);
  const float f[8] = {v0.x, v0.y, v0.z, v0.w, v1.x, v1.y, v1.z, v1.w};
  unsigned short s[8];
#pragma unroll
  for (int j = 0; j < 8; ++j) s[j] = bf16_rne(f[j]);
  uint4 o;
  o.x = (u32)s[0] | ((u32)s[1] << 16);
  o.y = (u32)s[2] | ((u32)s[3] << 16);
  o.z = (u32)s[4] | ((u32)s[5] << 16);
  o.w = (u32)s[6] | ((u32)s[7] << 16);
  *reinterpret_cast<uint4*>(dst + (size_t)i * 8) = o;
}

// weights -> fragment-major bf16 (UNCHANGED from r16)
__global__ __launch_bounds__(256) void cvt_w16f(const float* __restrict__ W,
                                                unsigned short* __restrict__ Wf,
                                                int N, int total) {
  const int c = blockIdx.x * 256 + threadIdx.x;
  if (c >= total) return;
  const int l = c & 63;
  const int f = c >> 6;
  const int ng = N >> 4;
  const int cg = f % ng;
  const int kb = f / ng;
  const int col = cg * 16 + (l & 15);
  const int k0 = kb * 32 + ((l >> 4) & 3) * 8;
  unsigned short s[8];
#pragma unroll
  for (int j = 0; j < 8; ++j) s[j] = bf16_rne(W[(size_t)(k0 + j) * N + col]);
  uint4 o;
  o.x = (u32)s[0] | ((u32)s[1] << 16);
  o.y = (u32)s[2] | ((u32)s[3] << 16);
  o.z = (u32)s[4] | ((u32)s[5] << 16);
  o.w = (u32)s[6] | ((u32)s[7] << 16);
  *reinterpret_cast<uint4*>(Wf + (size_t)c * 8) = o;
}

// ---------------------------------------------------------------------------
// dist_lds (r17): LDS-staged B with block-shared pull (per-CU TCP traffic
// 8MB -> 2MB vs reg-streaming), 64 phases x (32 cols x full K = 16KB),
// double-buffered gl_lds, ONE barrier per phase (r12-validated schedule).
// Per wave: 64 rows (a[4][8] VGPR), acc[4][2] (32 AGPR), rowmin/margin in
// registers -> ~215 regs total, __launch_bounds__(256,2) -> 2 waves/SIMD,
// 2 blocks/CU (cross-block overlap hides barrier drains, m114).
// First ct processed twice: pass 1 min-only (seeds rowmin), pass 2 appends
// (thresholds never +inf; no duplicate appends). Margins + deferred exact
// rescore identical to r15/16 (bit-exact validated):
//   thr = rowmin + 1.25*2^-7*||z||*(||e_col|| + ||e||max) + 1e-7
//   rescore = ascending-k f32 fma chain, (zs-2p)+esq, u64 atomicMin.
// ---------------------------------------------------------------------------
__global__ __launch_bounds__(256, 2) void dist_lds(
    const unsigned short* __restrict__ z16t, const unsigned short* __restrict__ e16f,
    const float* __restrict__ zf, const float* __restrict__ ef,
    const float* __restrict__ zsq, const float* __restrict__ esq,
    const float* __restrict__ maxesq, u64_t* __restrict__ keys) {
  __shared__ __align__(16) unsigned short Bsm[2][8192];  // 2 x 16KB
  __shared__ float esq_lds[2048];
  __shared__ unsigned cand[CAND_CAP];
  __shared__ unsigned cnt;

  const int tid = threadIdx.x;
  const int l = tid & 63;
  const int w = tid >> 6;
  const int l15 = tid & 15;
  const int lk = (tid >> 4) & 3;
  const int arow = blockIdx.x * 256;

  if (tid == 0) cnt = 0;
  for (int i = tid; i < 2048; i += 256) esq_lds[i] = esq[i];
  const float semax = sqrtf(maxesq[0]);

  // A fragments (register-resident, coalesced 1KB loads from z16t)
  bf16x8 a[4][8];
  {
    const char* zb = (const char*)z16t + (size_t)blockIdx.x * 131072 + w * 32768 + l * 16;
#pragma unroll
    for (int fr = 0; fr < 4; ++fr)
#pragma unroll
      for (int kb = 0; kb < 8; ++kb)
        a[fr][kb] = *reinterpret_cast<const bf16x8*>(zb + fr * 8192 + kb * 1024);
  }

  // per-slot row margin scale + running/row minima in registers
  float me1[4][4], runmin[4][4], rowmin[4][4];
#pragma unroll
  for (int fr = 0; fr < 4; ++fr)
#pragma unroll
    for (int rg = 0; rg < 4; ++rg) {
      const int row = w * 64 + fr * 16 + lk * 4 + rg;
      me1[fr][rg] = 0.009765625f * sqrtf(zsq[arow + row]);  // 1.25 * 2^-7
      runmin[fr][rg] = 3.402823466e38f;
      rowmin[fr][rg] = 3.402823466e38f;
    }

  auto rescore = [&](unsigned e) {  // exact ascending-k chain (bit-exact)
    const int row = arow + (int)(e >> 11);
    const int col = (int)(e & 2047u);
    const float* zp = zf + (size_t)row * 256;
    const float* ep = ef + (size_t)col * 256;
    float p = 0.f;
#pragma unroll 8
    for (int k4 = 0; k4 < 256; k4 += 4) {
      const float4 zv = *reinterpret_cast<const float4*>(zp + k4);
      const float4 ev = *reinterpret_cast<const float4*>(ep + k4);
      p = fmaf(zv.x, ev.x, p);
      p = fmaf(zv.y, ev.y, p);
      p = fmaf(zv.z, ev.z, p);
      p = fmaf(zv.w, ev.w, p);
    }
    const float dsc = (zsq[row] - 2.f * p) + esq[col];
    const u64_t kk = ((u64_t)f32_key(dsc) << 32) | (unsigned)col;
    atomicMin(&keys[row], kk);
  };

  const int ct0 = (int)((blockIdx.x * 5u) & 15u);  // stagger e16f walk
  const char* ebase = (const char*)e16f + (size_t)l * 16;

  // pp 0..3: first ct, min-only pass; pp 4..67: append passes (ct re-run)
  auto phase_ctq = [&](int pp, int& ct, int& q) {
    if (pp < 4) { ct = ct0; q = pp; }
    else { ct = (ct0 + ((pp - 4) >> 2)) & 15; q = (pp - 4) & 3; }
  };

  // stage phase pp into buffer bsel: 4 x 1KB gl_lds per wave (kb = 2w, 2w+1)
  auto stage = [&](int pp, int bsel) {
    int ct, q;
    phase_ctq(pp, ct, q);
    char* dbase = (char*)&Bsm[bsel][0];
#pragma unroll
    for (int q2 = 0; q2 < 2; ++q2) {
      const int kb = w * 2 + q2;
#pragma unroll
      for (int j = 0; j < 2; ++j) {
        const int fc = q * 2 + j;
        gl_lds16(ebase + ((size_t)((ct * 8 + kb) * 8 + fc) << 10),
                 dbase + kb * 2048 + j * 1024);
      }
    }
  };

  f32x4 acc[4][2];
#pragma unroll
  for (int fr = 0; fr < 4; ++fr) {
    acc[fr][0] = (f32x4){0.f, 0.f, 0.f, 0.f};
    acc[fr][1] = (f32x4){0.f, 0.f, 0.f, 0.f};
  }

  stage(0, 0);
  __syncthreads();

#pragma unroll 1
  for (int pp = 0; pp < 68; ++pp) {
    const int bsel = pp & 1;
    if (pp < 67) stage(pp + 1, bsel ^ 1);
    {
      const char* bp = (const char*)&Bsm[bsel][0];
#pragma unroll
      for (int kb = 0; kb < 8; ++kb) {
        const bf16x8 b0 = *reinterpret_cast<const bf16x8*>(bp + kb * 2048 + l * 16);
        const bf16x8 b1 = *reinterpret_cast<const bf16x8*>(bp + kb * 2048 + 1024 + l * 16);
#pragma unroll
        for (int fr = 0; fr < 4; ++fr) {
          acc[fr][0] = __builtin_amdgcn_mfma_f32_16x16x32_bf16(a[fr][kb], b0, acc[fr][0], 0, 0, 0);
          acc[fr][1] = __builtin_amdgcn_mfma_f32_16x16x32_bf16(a[fr][kb], b1, acc[fr][1], 0, 0, 0);
        }
      }
    }
    // epilogue: scores for 32 cols; lane-local min; append (pp>=4 only)
    {
      int ct, q;
      phase_ctq(pp, ct, q);
      const int colbase = ct * 128 + q * 32;
      const float ev0 = esq_lds[colbase + l15];
      const float ev1 = esq_lds[colbase + 16 + l15];
      const float m0 = sqrtf(ev0) + semax;
      const float m1 = sqrtf(ev1) + semax;
      const bool append = (pp >= 4);
#pragma unroll
      for (int fr = 0; fr < 4; ++fr)
#pragma unroll
        for (int rg = 0; rg < 4; ++rg) {
          const float s0 = fmaf(-2.f, acc[fr][0][rg], ev0);
          const float s1 = fmaf(-2.f, acc[fr][1][rg], ev1);
          runmin[fr][rg] = fminf(runmin[fr][rg], fminf(s0, s1));
          if (append) {
            const int row = w * 64 + fr * 16 + lk * 4 + rg;
            const float rm = rowmin[fr][rg];
            const float sc = me1[fr][rg];
            if (s0 <= fmaf(sc, m0, rm) + 1e-7f) {
              const unsigned idx = atomicAdd(&cnt, 1u);
              const unsigned code = ((unsigned)row << 11) | (unsigned)(colbase + l15);
              if (idx < CAND_CAP) cand[idx] = code;
              else rescore(code);
            }
            if (s1 <= fmaf(sc, m1, rm) + 1e-7f) {
              const unsigned idx = atomicAdd(&cnt, 1u);
              const unsigned code = ((unsigned)row << 11) | (unsigned)(colbase + 16 + l15);
              if (idx < CAND_CAP) cand[idx] = code;
              else rescore(code);
            }
          }
          acc[fr][0][rg] = 0.f;
          acc[fr][1][rg] = 0.f;
        }
      if (q == 3) {  // ct boundary: fold lane minima into per-row minima
#pragma unroll
        for (int fr = 0; fr < 4; ++fr)
#pragma unroll
          for (int rg = 0; rg < 4; ++rg) {
            float lm = runmin[fr][rg];
#pragma unroll
            for (int m = 1; m < 16; m <<= 1) lm = fminf(lm, __shfl_xor(lm, m, 64));
            rowmin[fr][rg] = lm;
          }
      }
    }
    __syncthreads();  // next buffer staged & visible; this buffer free
  }

  __syncthreads();  // candidate list complete
  const unsigned nc = cnt < CAND_CAP ? cnt : CAND_CAP;
  for (unsigned i = tid; i < nc; i += 256) rescore(cand[i]);
}

__global__ __launch_bounds__(256) void max_esq(const float* __restrict__ esq,
                                               float* __restrict__ outv) {
  __shared__ float red[256];
  float m = 0.f;
  for (int i = threadIdx.x; i < KE; i += 256) m = fmaxf(m, esq[i]);
  red[threadIdx.x] = m;
  __syncthreads();
  for (int off = 128; off > 0; off >>= 1) {
    if (threadIdx.x < off) red[threadIdx.x] = fmaxf(red[threadIdx.x], red[threadIdx.x + off]);
    __syncthreads();
  }
  if (threadIdx.x == 0) outv[0] = red[0];
}

// ---------------------------------------------------------------------------
// dec_mfma (UNCHANGED from r16 — validated). bf16 MFMA decoder layer.
// ---------------------------------------------------------------------------
template <int K, int NT, int NTOT, bool GATHER, bool LOSS>
__global__ __launch_bounds__(256, 1) void dec_mfma(
    const unsigned short* __restrict__ A16, const unsigned short* __restrict__ Wf,
    const float* __restrict__ bias, unsigned short* __restrict__ C16,
    const float* __restrict__ X, float* __restrict__ parts,
    const int* __restrict__ gidx) {
  constexpr int CH = K / 8;
  constexpr int KB = K / 32;
  constexpr int CG = NT / 16;
  constexpr int NB = NTOT / NT;
  __shared__ __align__(16) unsigned short Atile[128 * K];
  __shared__ int idx_l[128];
  __shared__ float rbuf[256];

  const int tid = threadIdx.x;
  const int l = tid & 63;
  const int w = tid >> 6;
  const int arow = (int)(blockIdx.x / NB) * 128;
  const int bcol = (int)(blockIdx.x % NB) * NT;

  if (GATHER) {
    if (tid < 128) idx_l[tid] = gidx[arow + tid];
    __syncthreads();
  }
  for (int q = tid; q < 128 * CH; q += 256) {
    const int r = q / CH;
    const int c = q % CH;
    const unsigned short* src = GATHER
        ? A16 + (size_t)idx_l[r] * K + c * 8
        : A16 + (size_t)(arow + r) * K + c * 8;
    const uint4 v = *reinterpret_cast<const uint4*>(src);
    *reinterpret_cast<uint4*>(&Atile[(r * CH + (c ^ (r & 7))) * 8]) = v;
  }

  bf16x8 wf[KB][CG];
#pragma unroll
  for (int kb = 0; kb < KB; ++kb)
#pragma unroll
    for (int cg = 0; cg < CG; ++cg)
      wf[kb][cg] = *reinterpret_cast<const bf16x8*>(
          Wf + ((size_t)(kb * (NTOT / 16) + bcol / 16 + cg) * 64 + l) * 8);

  __syncthreads();

  f32x4 acc[2][CG];
#pragma unroll
  for (int fr = 0; fr < 2; ++fr)
#pragma unroll
    for (int cg = 0; cg < CG; ++cg) acc[fr][cg] = (f32x4){0.f, 0.f, 0.f, 0.f};

#pragma unroll
  for (int kb = 0; kb < KB; ++kb) {
    bf16x8 af[2];
#pragma unroll
    for (int fr = 0; fr < 2; ++fr) {
      const int r = w * 32 + fr * 16 + (l & 15);
      const int c = (kb * 4 + ((l >> 4) & 3)) ^ (r & 7);
      af[fr] = *reinterpret_cast<const bf16x8*>(&Atile[(r * CH + c) * 8]);
    }
#pragma unroll
    for (int fr = 0; fr < 2; ++fr)
#pragma unroll
      for (int cg = 0; cg < CG; ++cg)
        acc[fr][cg] = __builtin_amdgcn_mfma_f32_16x16x32_bf16(af[fr], wf[kb][cg], acc[fr][cg], 0, 0, 0);
  }

  if (!LOSS) {
#pragma unroll
    for (int fr = 0; fr < 2; ++fr)
#pragma unroll
      for (int cg = 0; cg < CG; ++cg) {
        const int col = bcol + cg * 16 + (l & 15);
        const float bv = bias[col];
#pragma unroll
        for (int rg = 0; rg < 4; ++rg) {
          const int row = arow + w * 32 + fr * 16 + ((l >> 4) & 3) * 4 + rg;
          const float v = fmaxf(acc[fr][cg][rg] + bv, 0.f);
          C16[(size_t)row * NTOT + col] = bf16_rne(v);
        }
      }
  } else {
    float local = 0.f;
#pragma unroll
    for (int fr = 0; fr < 2; ++fr)
#pragma unroll
      for (int cg = 0; cg < CG; ++cg) {
        const int col = bcol + cg * 16 + (l & 15);
        const float bv = bias[col];
#pragma unroll
        for (int rg = 0; rg < 4; ++rg) {
          const int row = arow + w * 32 + fr * 16 + ((l >> 4) & 3) * 4 + rg;
          const float v = fmaxf(acc[fr][cg][rg] + bv, 0.f);
          const float d = v - X[(size_t)row * NTOT + col];
          local = fmaf(d, d, local);
        }
      }
    rbuf[tid] = local;
    __syncthreads();
    for (int off = 128; off > 0; off >>= 1) {
      if (tid < off) rbuf[tid] += rbuf[tid + off];
      __syncthreads();
    }
    if (tid == 0) parts[blockIdx.x] = rbuf[0];
  }
}

// sum of squares per row (256 cols); block = 4 rows x 64 lanes
__global__ __launch_bounds__(256) void rowsq(const float* __restrict__ src,
                                             float* __restrict__ dst, int rows) {
  const int sub = threadIdx.x >> 6;
  const int lane = threadIdx.x & 63;
  const int r = blockIdx.x * 4 + sub;
  if (r >= rows) return;
  const float* p = src + (size_t)r * 256;
  float s = 0.f;
#pragma unroll
  for (int j = 0; j < 4; ++j) {
    float v = p[lane + 64 * j];
    s += v * v;
  }
#pragma unroll
  for (int off = 32; off > 0; off >>= 1) s += __shfl_down(s, off, 64);
  if (lane == 0) dst[r] = s;
}

__global__ __launch_bounds__(256) void init_keys(u64_t* __restrict__ keys) {
  keys[(size_t)blockIdx.x * 256 + threadIdx.x] = ~0ull;
}

// per row: idx from key, write z_latent = z + (e - z), quant-loss partial sums
__global__ __launch_bounds__(256) void gather_quant(
    const u64_t* __restrict__ keys, const float* __restrict__ emb,
    const float* __restrict__ z_e, float* __restrict__ zlat,
    int* __restrict__ idx_out, float* __restrict__ qparts) {
  const int sub = threadIdx.x >> 6;
  const int lane = threadIdx.x & 63;
  const int r = blockIdx.x * 4 + sub;
  const int idx = (int)(keys[r] & 0xFFFFFFFFull);
  if (lane == 0) idx_out[r] = idx;
  float s = 0.f;
#pragma unroll
  for (int j = 0; j < 4; ++j) {
    const int d = lane + 64 * j;
    float e = emb[(size_t)idx * 256 + d];
    float z = z_e[(size_t)r * 256 + d];
    float df = e - z;
    s += df * df;
    zlat[(size_t)r * 256 + d] = z + df;  // fl(z_e + fl(z_q - z_e)) — exact ref order
  }
#pragma unroll
  for (int off = 32; off > 0; off >>= 1) s += __shfl_down(s, off, 64);
  __shared__ float red[4];
  if (lane == 0) red[sub] = s;
  __syncthreads();
  if (threadIdx.x == 0) qparts[blockIdx.x] = (red[0] + red[1]) + (red[2] + red[3]);
}

__global__ __launch_bounds__(256) void final_loss(
    const float* __restrict__ qparts, int nq,
    const float* __restrict__ rparts, int nr, float* __restrict__ out) {
  const int tid = threadIdx.x;
  double sq = 0.0, sr = 0.0;
  for (int i = tid; i < nq; i += 256) sq += (double)qparts[i];
  for (int i = tid; i < nr; i += 256) sr += (double)rparts[i];
  __shared__ double bq[256], br[256];
  bq[tid] = sq;
  br[tid] = sr;
  __syncthreads();
  for (int off = 128; off > 0; off >>= 1) {
    if (tid < off) {
      bq[tid] += bq[tid + off];
      br[tid] += br[tid + off];
    }
    __syncthreads();
  }
  if (tid == 0) {
    double qm = bq[0] / ((double)NROWS * 256.0);
    double rm = br[0] / ((double)NROWS * 512.0);
    out[(size_t)NROWS * 256] = (float)(rm + 1.25 * qm);  // recon + (1+BETA)*quant
  }
}

extern "C" void kernel_launch(void* const* d_in, const int* in_sizes, int n_in,
                              void* d_out, int out_size, void* d_ws, size_t ws_size,
                              hipStream_t stream) {
  const float* x   = (const float*)d_in[0];
  const float* ew1 = (const float*)d_in[1];
  const float* eb1 = (const float*)d_in[2];
  const float* ew2 = (const float*)d_in[3];
  const float* eb2 = (const float*)d_in[4];
  const float* ew3 = (const float*)d_in[5];
  const float* eb3 = (const float*)d_in[6];
  const float* dw1 = (const float*)d_in[7];
  const float* db1 = (const float*)d_in[8];
  const float* dw2 = (const float*)d_in[9];
  const float* db2 = (const float*)d_in[10];
  const float* dw3 = (const float*)d_in[11];
  const float* db3 = (const float*)d_in[12];
  const float* emb = (const float*)d_in[13];

  char* ws = (char*)d_ws;
  // region A (0..33.5MB): enc h1 f32 -> {e16f, maxesq, emb16, w*f} after enc2
  float* h1            = (float*)(ws);
  unsigned short* e16f = (unsigned short*)(ws);               // 1 MB
  float* maxesq        = (float*)(ws + 2097152ull);           // 256 B
  unsigned short* emb16 = (unsigned short*)(ws + 4194304ull); // 1 MB
  unsigned short* w1f  = (unsigned short*)(ws + 5242880ull);  // 64 KB
  unsigned short* w2f  = (unsigned short*)(ws + 5308416ull);  // 16 KB
  unsigned short* w3f  = (unsigned short*)(ws + 5324800ull);  // 64 KB
  // region B (33.5..100.6MB): enc h2 f32 -> z16t -> {h2_16, h1_16} after dist
  float* h2            = (float*)(ws + 33554432ull);
  unsigned short* z16t = (unsigned short*)(ws + 33554432ull);   // 67 MB
  unsigned short* h2_16 = (unsigned short*)(ws + 33554432ull);  // 33.5 MB
  unsigned short* h1_16 = (unsigned short*)(ws + 67108864ull);  // 16.8 MB
  // persistent
  float* z_e    = (float*)(ws + 100663296ull);   // N x 256
  float* zsq    = (float*)(ws + 234881024ull);   // N
  float* esq    = (float*)(ws + 235405312ull);   // KE
  u64_t* keys   = (u64_t*)(ws + 235413504ull);   // N
  int* idx      = (int*)(ws + 236462080ull);     // N
  float* qparts = (float*)(ws + 236986368ull);   // N/4
  float* rparts = (float*)(ws + 237117440ull);   // 2048

  float* out = (float*)d_out;
  dim3 blk(256);

  // encoder: 512 -> 64 -> 128 -> 256  (unchanged -> bit-exact z_e)
  gemm64<0><<<dim3(NROWS / 64, 1), blk, 0, stream>>>(x, ew1, eb1, h1, NROWS, 64, 512,
      nullptr);
  gemm128<0><<<dim3(NROWS / 128, 1), blk, 0, stream>>>(h1, ew2, eb2, h2,
      128, 64, nullptr, nullptr, nullptr);
  // h1 (region A) dead: decoder-side conversions (independent of z_e)
  cvt_rows16<<<dim3(KE * 256 / 8 / 256), blk, 0, stream>>>(emb, emb16);
  cvt_w16f<<<dim3(16), blk, 0, stream>>>(dw1, w1f, 128, 4096);
  cvt_w16f<<<dim3(4), blk, 0, stream>>>(dw2, w2f, 64, 1024);
  cvt_w16f<<<dim3(16), blk, 0, stream>>>(dw3, w3f, 512, 4096);
  gemm128<0><<<dim3(NROWS / 128, 2), blk, 0, stream>>>(h2, ew3, eb3, z_e,
      256, 128, nullptr, nullptr, nullptr);

  rowsq<<<dim3(NROWS / 4), blk, 0, stream>>>(z_e, zsq, NROWS);
  rowsq<<<dim3(KE / 4), blk, 0, stream>>>(emb, esq, KE);
  max_esq<<<dim3(1), blk, 0, stream>>>(esq, maxesq);
  init_keys<<<dim3(NROWS / 256), blk, 0, stream>>>(keys);

  cvt_z16t<<<dim3(NROWS * 256 / 8 / 256), blk, 0, stream>>>(z_e, z16t);
  cvt_e16f<<<dim3(KE * 256 / 8 / 256), blk, 0, stream>>>(emb, e16f);

  // LDS-staged bound + deferred exact rescore (bit-identical selection)
  dist_lds<<<dim3(NROWS / 256), blk, 0, stream>>>(z16t, e16f, z_e, emb, zsq, esq,
      maxesq, keys);

  gather_quant<<<dim3(NROWS / 4), blk, 0, stream>>>(keys, emb, z_e, out, idx, qparts);

  // decoder: bf16 MFMA (loss-only path, 2% threshold; z16t dead -> h*_16)
  dec_mfma<256, 128, 128, true, false><<<dim3(NROWS / 128), blk, 0, stream>>>(
      emb16, w1f, db1, h2_16, nullptr, nullptr, idx);
  dec_mfma<128, 64, 64, false, false><<<dim3(NROWS / 128), blk, 0, stream>>>(
      h2_16, w2f, db2, h1_16, nullptr, nullptr, nullptr);
  dec_mfma<64, 256, 512, false, true><<<dim3((NROWS / 128) * 2), blk, 0, stream>>>(
      h1_16, w3f, db3, nullptr, x, rparts, nullptr);

  final_loss<<<dim3(1), blk, 0, stream>>>(qparts, NROWS / 4, rparts, 2048, out);
}

// Round 18
// 1211.825 us; speedup vs baseline: 1.0324x; 1.0324x over previous
//
#include <hip/hip_runtime.h>

#define NROWS 131072
#define KE 2048
#define CAND_CAP 8192

typedef unsigned long long u64_t;
typedef unsigned int u32;
typedef __attribute__((ext_vector_type(8))) short bf16x8;
typedef __attribute__((ext_vector_type(4))) float f32x4;

__device__ __forceinline__ unsigned f32_key(float f) {
  unsigned u = __float_as_uint(f);
  return (u & 0x80000000u) ? ~u : (u | 0x80000000u);
}

__device__ __forceinline__ unsigned short bf16_rne(float f) {
  unsigned u = __float_as_uint(f);
  u += 0x7FFFu + ((u >> 16) & 1u);
  return (unsigned short)(u >> 16);
}

// ---------------------------------------------------------------------------
// 64x64 tile f32 GEMM (UNCHANGED — enc1). MODE 0 only.
// ---------------------------------------------------------------------------
template <int MODE>
__global__ __launch_bounds__(256) void gemm64(
    const float* __restrict__ A, const float* __restrict__ B,
    const float* __restrict__ bias, float* __restrict__ C,
    int M, int N, int K,
    const int* __restrict__ gidx) {
  __shared__ __align__(16) float As[16][68];
  __shared__ __align__(16) float Bs[16][68];

  const int tid = threadIdx.x;
  const int tx = tid & 15;
  const int ty = tid >> 4;
  const int arow = blockIdx.x * 64;
  const int bcol = blockIdx.y * 64;

  const int lr = tid >> 2;
  const int lc = (tid & 3) * 4;
  int ga = arow + lr;
  if (MODE == 1) ga = gidx[ga];
  const float* Ap = A + (size_t)ga * K + lc;

  const int bkr = tid >> 4;
  const int bc4 = (tid & 15) * 4;
  const float* Bp = B + (size_t)bkr * N + bcol + bc4;

  float acc[4][4] = {};

  for (int kt = 0; kt < K; kt += 16) {
    float4 av = *reinterpret_cast<const float4*>(Ap);
    As[lc + 0][lr] = av.x;
    As[lc + 1][lr] = av.y;
    As[lc + 2][lr] = av.z;
    As[lc + 3][lr] = av.w;
    float4 bv = *reinterpret_cast<const float4*>(Bp);
    *reinterpret_cast<float4*>(&Bs[bkr][bc4]) = bv;
    Bp += (size_t)16 * N;
    Ap += 16;
    __syncthreads();
#pragma unroll
    for (int k = 0; k < 16; ++k) {
      float4 a = *reinterpret_cast<const float4*>(&As[k][ty * 4]);
      float4 b = *reinterpret_cast<const float4*>(&Bs[k][tx * 4]);
      acc[0][0] += a.x * b.x; acc[0][1] += a.x * b.y; acc[0][2] += a.x * b.z; acc[0][3] += a.x * b.w;
      acc[1][0] += a.y * b.x; acc[1][1] += a.y * b.y; acc[1][2] += a.y * b.z; acc[1][3] += a.y * b.w;
      acc[2][0] += a.z * b.x; acc[2][1] += a.z * b.y; acc[2][2] += a.z * b.z; acc[2][3] += a.z * b.w;
      acc[3][0] += a.w * b.x; acc[3][1] += a.w * b.y; acc[3][2] += a.w * b.z; acc[3][3] += a.w * b.w;
    }
    __syncthreads();
  }

#pragma unroll
  for (int i = 0; i < 4; ++i) {
    const int row = arow + ty * 4 + i;
    float4 v;
    v.x = fmaxf(acc[i][0] + bias[bcol + tx * 4 + 0], 0.f);
    v.y = fmaxf(acc[i][1] + bias[bcol + tx * 4 + 1], 0.f);
    v.z = fmaxf(acc[i][2] + bias[bcol + tx * 4 + 2], 0.f);
    v.w = fmaxf(acc[i][3] + bias[bcol + tx * 4 + 3], 0.f);
    *reinterpret_cast<float4*>(&C[(size_t)row * N + bcol + tx * 4]) = v;
  }
}

// ---------------------------------------------------------------------------
// 128x128 tile f32 GEMM (enc2/enc3). MODE 0 only. Z16: also emit bf16 tiled
// z16t chunks from the epilogue registers (value-identical to the old
// cvt_z16t pass; saves a full 134MB read + 67MB write kernel).
// z16t chunk layout (matches dist_g256 reads): 16B chunk index =
//   (((row>>8)*4 + ((row>>6)&3))*4 + ((row>>4)&3))*8 + (k>>5))*64
//   + ((k>>3)&3)*16 + (row&15);  byte sub-offset = (k&7)*2.
// ---------------------------------------------------------------------------
template <int MODE, bool Z16>
__global__ __launch_bounds__(256) void gemm128(
    const float* __restrict__ A, const float* __restrict__ B,
    const float* __restrict__ bias, float* __restrict__ C,
    int N, int K,
    const int* __restrict__ gidx,
    const float* __restrict__ X,
    float* __restrict__ parts,
    unsigned short* __restrict__ z16t) {
  __shared__ __align__(16) char smem[17408];
  float (*As)[132] = (float(*)[132])smem;
  float (*Bs)[132] = (float(*)[132])(smem + 8448);

  const int tid = threadIdx.x;
  const int tx = tid & 15;
  const int ty = tid >> 4;
  const int arow = blockIdx.x * 128;
  const int bcol = blockIdx.y * 128;

  const int r0 = tid >> 2;
  const int r1 = r0 + 64;
  const int lc = (tid & 3) * 4;
  int ga0 = arow + r0, ga1 = arow + r1;
  if (MODE == 1) { ga0 = gidx[ga0]; ga1 = gidx[ga1]; }
  const float* Ap0 = A + (size_t)ga0 * K + lc;
  const float* Ap1 = A + (size_t)ga1 * K + lc;

  const int bk0 = tid >> 5;
  const int bc0 = (tid & 31) * 4;
  const float* Bp0 = B + (size_t)bk0 * N + bcol + bc0;
  const float* Bp1 = B + (size_t)(bk0 + 8) * N + bcol + bc0;

  float acc[8][8] = {};

  for (int kt = 0; kt < K; kt += 16) {
    float4 a0 = *reinterpret_cast<const float4*>(Ap0);
    float4 a1 = *reinterpret_cast<const float4*>(Ap1);
    As[lc + 0][r0] = a0.x; As[lc + 1][r0] = a0.y; As[lc + 2][r0] = a0.z; As[lc + 3][r0] = a0.w;
    As[lc + 0][r1] = a1.x; As[lc + 1][r1] = a1.y; As[lc + 2][r1] = a1.z; As[lc + 3][r1] = a1.w;
    float4 b0 = *reinterpret_cast<const float4*>(Bp0);
    float4 b1 = *reinterpret_cast<const float4*>(Bp1);
    *reinterpret_cast<float4*>(&Bs[bk0][bc0]) = b0;
    *reinterpret_cast<float4*>(&Bs[bk0 + 8][bc0]) = b1;
    Bp0 += (size_t)16 * N; Bp1 += (size_t)16 * N;
    Ap0 += 16; Ap1 += 16;
    __syncthreads();
#pragma unroll
    for (int k = 0; k < 16; ++k) {
      float4 av0 = *reinterpret_cast<const float4*>(&As[k][ty * 4]);
      float4 av1 = *reinterpret_cast<const float4*>(&As[k][64 + ty * 4]);
      float4 bv0 = *reinterpret_cast<const float4*>(&Bs[k][tx * 4]);
      float4 bv1 = *reinterpret_cast<const float4*>(&Bs[k][64 + tx * 4]);
      const float a[8] = {av0.x, av0.y, av0.z, av0.w, av1.x, av1.y, av1.z, av1.w};
      const float b[8] = {bv0.x, bv0.y, bv0.z, bv0.w, bv1.x, bv1.y, bv1.z, bv1.w};
#pragma unroll
      for (int i = 0; i < 8; ++i)
#pragma unroll
        for (int j = 0; j < 8; ++j) acc[i][j] += a[i] * b[j];
    }
    __syncthreads();
  }

#pragma unroll
  for (int i = 0; i < 8; ++i) {
    const int row = arow + (i >> 2) * 64 + ty * 4 + (i & 3);
    const int c0 = bcol + tx * 4;
    const int c1 = bcol + 64 + tx * 4;
    float4 v0, v1;
    v0.x = fmaxf(acc[i][0] + bias[c0 + 0], 0.f);
    v0.y = fmaxf(acc[i][1] + bias[c0 + 1], 0.f);
    v0.z = fmaxf(acc[i][2] + bias[c0 + 2], 0.f);
    v0.w = fmaxf(acc[i][3] + bias[c0 + 3], 0.f);
    v1.x = fmaxf(acc[i][4] + bias[c1 + 0], 0.f);
    v1.y = fmaxf(acc[i][5] + bias[c1 + 1], 0.f);
    v1.z = fmaxf(acc[i][6] + bias[c1 + 2], 0.f);
    v1.w = fmaxf(acc[i][7] + bias[c1 + 3], 0.f);
    *reinterpret_cast<float4*>(&C[(size_t)row * N + c0]) = v0;
    *reinterpret_cast<float4*>(&C[(size_t)row * N + c1]) = v1;
    if (Z16) {
      const int rbits = (((row >> 8) * 4 + ((row >> 6) & 3)) * 4 + ((row >> 4) & 3));
#pragma unroll
      for (int h = 0; h < 2; ++h) {
        const int k0 = h ? c1 : c0;
        const float4 v = h ? v1 : v0;
        const u64_t pk = (u64_t)bf16_rne(v.x) | ((u64_t)bf16_rne(v.y) << 16) |
                         ((u64_t)bf16_rne(v.z) << 32) | ((u64_t)bf16_rne(v.w) << 48);
        const size_t chunk = ((size_t)rbits * 8 + (k0 >> 5)) * 64 +
                             ((k0 >> 3) & 3) * 16 + (row & 15);
        *reinterpret_cast<u64_t*>((char*)z16t + chunk * 16 + (k0 & 7) * 2) = pk;
      }
    }
  }
}

// e16f: FRAGMENT-MAJOR emb tiles (UNCHANGED from r13-17)
__global__ __launch_bounds__(256) void cvt_e16f(const float* __restrict__ emb,
                                                unsigned short* __restrict__ e16f) {
  const int c = blockIdx.x * 256 + threadIdx.x;  // 65536 chunks
  const int l = c & 63;
  const int fc = (c >> 6) & 7;
  const int t = c >> 9;
  const int kb = t & 7;
  const int ct = t >> 3;
  const int col = ct * 128 + fc * 16 + (l & 15);
  const int k0 = kb * 32 + (l >> 4) * 8;
  const float* p = emb + (size_t)col * 256 + k0;
  const float4 v0 = *reinterpret_cast<const float4*>(p);
  const float4 v1 = *reinterpret_cast<const float4*>(p + 4);
  const float f[8] = {v0.x, v0.y, v0.z, v0.w, v1.x, v1.y, v1.z, v1.w};
  unsigned short s8[8];
#pragma unroll
  for (int j = 0; j < 8; ++j) s8[j] = bf16_rne(f[j]);
  uint4 o;
  o.x = (u32)s8[0] | ((u32)s8[1] << 16);
  o.y = (u32)s8[2] | ((u32)s8[3] << 16);
  o.z = (u32)s8[4] | ((u32)s8[5] << 16);
  o.w = (u32)s8[6] | ((u32)s8[7] << 16);
  *reinterpret_cast<uint4*>(e16f + (size_t)c * 8) = o;
}

// plain f32 -> bf16 row-major (emb16), 8 elems/thread
__global__ __launch_bounds__(256) void cvt_rows16(const float* __restrict__ src,
                                                  unsigned short* __restrict__ dst) {
  const int i = blockIdx.x * 256 + threadIdx.x;
  const float4 v0 = *reinterpret_cast<const float4*>(src + (size_t)i * 8);
  const float4 v1 = *reinterpret_cast<const float4*>(src + (size_t)i * 8 + 4);
  const float f[8] = {v0.x, v0.y, v0.z, v0.w, v1.x, v1.y, v1.z, v1.w};
  unsigned short s[8];
#pragma unroll
  for (int j = 0; j < 8; ++j) s[j] = bf16_rne(f[j]);
  uint4 o;
  o.x = (u32)s[0] | ((u32)s[1] << 16);
  o.y = (u32)s[2] | ((u32)s[3] << 16);
  o.z = (u32)s[4] | ((u32)s[5] << 16);
  o.w = (u32)s[6] | ((u32)s[7] << 16);
  *reinterpret_cast<uint4*>(dst + (size_t)i * 8) = o;
}

// weights -> fragment-major bf16 (UNCHANGED from r16)
__global__ __launch_bounds__(256) void cvt_w16f(const float* __restrict__ W,
                                                unsigned short* __restrict__ Wf,
                                                int N, int total) {
  const int c = blockIdx.x * 256 + threadIdx.x;
  if (c >= total) return;
  const int l = c & 63;
  const int f = c >> 6;
  const int ng = N >> 4;
  const int cg = f % ng;
  const int kb = f / ng;
  const int col = cg * 16 + (l & 15);
  const int k0 = kb * 32 + ((l >> 4) & 3) * 8;
  unsigned short s[8];
#pragma unroll
  for (int j = 0; j < 8; ++j) s[j] = bf16_rne(W[(size_t)(k0 + j) * N + col]);
  uint4 o;
  o.x = (u32)s[0] | ((u32)s[1] << 16);
  o.y = (u32)s[2] | ((u32)s[3] << 16);
  o.z = (u32)s[4] | ((u32)s[5] << 16);
  o.w = (u32)s[6] | ((u32)s[7] << 16);
  *reinterpret_cast<uint4*>(Wf + (size_t)c * 8) = o;
}

// ---------------------------------------------------------------------------
// dist_g256 (r15 version verbatim — best-measured dist variant; parked).
// ---------------------------------------------------------------------------
__global__ __launch_bounds__(256, 1) void dist_g256(
    const unsigned short* __restrict__ z16t, const unsigned short* __restrict__ e16f,
    const float* __restrict__ zf, const float* __restrict__ ef,
    const float* __restrict__ zsq, const float* __restrict__ esq,
    const float* __restrict__ maxesq, u64_t* __restrict__ keys) {
  __shared__ float esq_lds[2048];
  __shared__ float me1_lds[256];
  __shared__ float rowmin_lds[256];
  __shared__ unsigned cand[CAND_CAP];
  __shared__ unsigned cnt;

  const int tid = threadIdx.x;
  const int l = tid & 63;
  const int w = tid >> 6;
  const int l15 = tid & 15;
  const int lk = (tid >> 4) & 3;
  const int arow = blockIdx.x * 256;

  if (tid == 0) cnt = 0;
  {
    for (int i = tid; i < 2048; i += 256) esq_lds[i] = esq[i];
    me1_lds[tid] = 0.009765625f * sqrtf(zsq[arow + tid]);  // 1.25 * 2^-7
    rowmin_lds[tid] = 3.402823466e38f;
  }
  const float semax = sqrtf(maxesq[0]);

  bf16x8 a[4][8];
  {
    const char* zb = (const char*)z16t + (size_t)blockIdx.x * 131072 + w * 32768 + l * 16;
#pragma unroll
    for (int fr = 0; fr < 4; ++fr)
#pragma unroll
      for (int kb = 0; kb < 8; ++kb)
        a[fr][kb] = *reinterpret_cast<const bf16x8*>(zb + fr * 8192 + kb * 1024);
  }

  auto rescore = [&](unsigned e) {  // exact ascending-k chain (bit-exact)
    const int row = arow + (int)(e >> 11);
    const int col = (int)(e & 2047u);
    const float* zp = zf + (size_t)row * 256;
    const float* ep = ef + (size_t)col * 256;
    float p = 0.f;
#pragma unroll 8
    for (int k4 = 0; k4 < 256; k4 += 4) {
      const float4 zv = *reinterpret_cast<const float4*>(zp + k4);
      const float4 ev = *reinterpret_cast<const float4*>(ep + k4);
      p = fmaf(zv.x, ev.x, p);
      p = fmaf(zv.y, ev.y, p);
      p = fmaf(zv.z, ev.z, p);
      p = fmaf(zv.w, ev.w, p);
    }
    const float dsc = (zsq[row] - 2.f * p) + esq[col];
    const u64_t kk = ((u64_t)f32_key(dsc) << 32) | (unsigned)col;
    atomicMin(&keys[row], kk);
  };

  __syncthreads();

  const char* eb = (const char*)e16f + (size_t)l * 16;
  const int ct0 = (int)((blockIdx.x * 5u) & 15u);

  f32x4 acc[4][8];
#pragma unroll
  for (int fr = 0; fr < 4; ++fr)
#pragma unroll
    for (int fc = 0; fc < 8; ++fc) acc[fr][fc] = (f32x4){0.f, 0.f, 0.f, 0.f};

  bf16x8 bc[8], bn[8];
#pragma unroll
  for (int fc = 0; fc < 8; ++fc)
    bc[fc] = *reinterpret_cast<const bf16x8*>(eb + (size_t)(ct0 * 8) * 8192 + fc * 1024);

#pragma unroll 1
  for (int ctl = 0; ctl < 16; ++ctl) {
    const int ct = (ct0 + ctl) & 15;
#pragma unroll
    for (int kb = 0; kb < 8; ++kb) {
      const int nctl = (kb == 7) ? ctl + 1 : ctl;
      const int nkb = (kb == 7) ? 0 : kb + 1;
      if (nctl < 16) {
        const int nct = (ct0 + nctl) & 15;
        const char* tb = eb + (size_t)(nct * 8 + nkb) * 8192;
#pragma unroll
        for (int fc = 0; fc < 8; ++fc)
          bn[fc] = *reinterpret_cast<const bf16x8*>(tb + fc * 1024);
      }
#pragma unroll
      for (int fr = 0; fr < 4; ++fr)
#pragma unroll
        for (int fc = 0; fc < 8; ++fc)
          acc[fr][fc] = __builtin_amdgcn_mfma_f32_16x16x32_bf16(a[fr][kb], bc[fc], acc[fr][fc], 0, 0, 0);
#pragma unroll
      for (int fc = 0; fc < 8; ++fc) bc[fc] = bn[fc];
    }
    {
      float esqv[8], se[8];
#pragma unroll
      for (int fc = 0; fc < 8; ++fc) {
        esqv[fc] = esq_lds[ct * 128 + fc * 16 + l15];
        se[fc] = sqrtf(esqv[fc]);
      }
#pragma unroll
      for (int fr = 0; fr < 4; ++fr)
#pragma unroll
        for (int rg = 0; rg < 4; ++rg) {
          float s8[8];
          float lm = 3.402823466e38f;
#pragma unroll
          for (int fc = 0; fc < 8; ++fc) {
            s8[fc] = fmaf(-2.f, acc[fr][fc][rg], esqv[fc]);
            lm = fminf(lm, s8[fc]);
          }
#pragma unroll
          for (int m = 1; m < 16; m <<= 1) lm = fminf(lm, __shfl_xor(lm, m, 64));
          const int row = w * 64 + fr * 16 + lk * 4 + rg;
          const float rm = fminf(rowmin_lds[row], lm);
          if (l15 == 0) rowmin_lds[row] = rm;
          const float me1 = me1_lds[row];
#pragma unroll
          for (int fc = 0; fc < 8; ++fc) {
            const float thr = rm + me1 * (se[fc] + semax) + 1e-7f;
            if (s8[fc] <= thr) {
              const unsigned code =
                  ((unsigned)row << 11) | (unsigned)(ct * 128 + fc * 16 + l15);
              const unsigned idx = atomicAdd(&cnt, 1u);
              if (idx < CAND_CAP) cand[idx] = code;
              else rescore(code);
            }
          }
        }
#pragma unroll
      for (int fr = 0; fr < 4; ++fr)
#pragma unroll
        for (int fc = 0; fc < 8; ++fc) acc[fr][fc] = (f32x4){0.f, 0.f, 0.f, 0.f};
    }
  }

  __syncthreads();
  const unsigned nc = cnt < CAND_CAP ? cnt : CAND_CAP;
  for (unsigned i = tid; i < nc; i += 256) rescore(cand[i]);
}

// ---------------------------------------------------------------------------
// dec_mfma (UNCHANGED from r16 — validated). bf16 MFMA decoder layer.
// ---------------------------------------------------------------------------
template <int K, int NT, int NTOT, bool GATHER, bool LOSS>
__global__ __launch_bounds__(256, 1) void dec_mfma(
    const unsigned short* __restrict__ A16, const unsigned short* __restrict__ Wf,
    const float* __restrict__ bias, unsigned short* __restrict__ C16,
    const float* __restrict__ X, float* __restrict__ parts,
    const int* __restrict__ gidx) {
  constexpr int CH = K / 8;
  constexpr int KB = K / 32;
  constexpr int CG = NT / 16;
  constexpr int NB = NTOT / NT;
  __shared__ __align__(16) unsigned short Atile[128 * K];
  __shared__ int idx_l[128];
  __shared__ float rbuf[256];

  const int tid = threadIdx.x;
  const int l = tid & 63;
  const int w = tid >> 6;
  const int arow = (int)(blockIdx.x / NB) * 128;
  const int bcol = (int)(blockIdx.x % NB) * NT;

  if (GATHER) {
    if (tid < 128) idx_l[tid] = gidx[arow + tid];
    __syncthreads();
  }
  for (int q = tid; q < 128 * CH; q += 256) {
    const int r = q / CH;
    const int c = q % CH;
    const unsigned short* src = GATHER
        ? A16 + (size_t)idx_l[r] * K + c * 8
        : A16 + (size_t)(arow + r) * K + c * 8;
    const uint4 v = *reinterpret_cast<const uint4*>(src);
    *reinterpret_cast<uint4*>(&Atile[(r * CH + (c ^ (r & 7))) * 8]) = v;
  }

  bf16x8 wf[KB][CG];
#pragma unroll
  for (int kb = 0; kb < KB; ++kb)
#pragma unroll
    for (int cg = 0; cg < CG; ++cg)
      wf[kb][cg] = *reinterpret_cast<const bf16x8*>(
          Wf + ((size_t)(kb * (NTOT / 16) + bcol / 16 + cg) * 64 + l) * 8);

  __syncthreads();

  f32x4 acc[2][CG];
#pragma unroll
  for (int fr = 0; fr < 2; ++fr)
#pragma unroll
    for (int cg = 0; cg < CG; ++cg) acc[fr][cg] = (f32x4){0.f, 0.f, 0.f, 0.f};

#pragma unroll
  for (int kb = 0; kb < KB; ++kb) {
    bf16x8 af[2];
#pragma unroll
    for (int fr = 0; fr < 2; ++fr) {
      const int r = w * 32 + fr * 16 + (l & 15);
      const int c = (kb * 4 + ((l >> 4) & 3)) ^ (r & 7);
      af[fr] = *reinterpret_cast<const bf16x8*>(&Atile[(r * CH + c) * 8]);
    }
#pragma unroll
    for (int fr = 0; fr < 2; ++fr)
#pragma unroll
      for (int cg = 0; cg < CG; ++cg)
        acc[fr][cg] = __builtin_amdgcn_mfma_f32_16x16x32_bf16(af[fr], wf[kb][cg], acc[fr][cg], 0, 0, 0);
  }

  if (!LOSS) {
#pragma unroll
    for (int fr = 0; fr < 2; ++fr)
#pragma unroll
      for (int cg = 0; cg < CG; ++cg) {
        const int col = bcol + cg * 16 + (l & 15);
        const float bv = bias[col];
#pragma unroll
        for (int rg = 0; rg < 4; ++rg) {
          const int row = arow + w * 32 + fr * 16 + ((l >> 4) & 3) * 4 + rg;
          const float v = fmaxf(acc[fr][cg][rg] + bv, 0.f);
          C16[(size_t)row * NTOT + col] = bf16_rne(v);
        }
      }
  } else {
    float local = 0.f;
#pragma unroll
    for (int fr = 0; fr < 2; ++fr)
#pragma unroll
      for (int cg = 0; cg < CG; ++cg) {
        const int col = bcol + cg * 16 + (l & 15);
        const float bv = bias[col];
#pragma unroll
        for (int rg = 0; rg < 4; ++rg) {
          const int row = arow + w * 32 + fr * 16 + ((l >> 4) & 3) * 4 + rg;
          const float v = fmaxf(acc[fr][cg][rg] + bv, 0.f);
          const float d = v - X[(size_t)row * NTOT + col];
          local = fmaf(d, d, local);
        }
      }
    rbuf[tid] = local;
    __syncthreads();
    for (int off = 128; off > 0; off >>= 1) {
      if (tid < off) rbuf[tid] += rbuf[tid + off];
      __syncthreads();
    }
    if (tid == 0) parts[blockIdx.x] = rbuf[0];
  }
}

__global__ __launch_bounds__(256) void max_esq(const float* __restrict__ esq,
                                               float* __restrict__ outv) {
  __shared__ float red[256];
  float m = 0.f;
  for (int i = threadIdx.x; i < KE; i += 256) m = fmaxf(m, esq[i]);
  red[threadIdx.x] = m;
  __syncthreads();
  for (int off = 128; off > 0; off >>= 1) {
    if (threadIdx.x < off) red[threadIdx.x] = fmaxf(red[threadIdx.x], red[threadIdx.x + off]);
    __syncthreads();
  }
  if (threadIdx.x == 0) outv[0] = red[0];
}

// sum of squares per row (256 cols); block = 4 rows x 64 lanes
__global__ __launch_bounds__(256) void rowsq(const float* __restrict__ src,
                                             float* __restrict__ dst, int rows) {
  const int sub = threadIdx.x >> 6;
  const int lane = threadIdx.x & 63;
  const int r = blockIdx.x * 4 + sub;
  if (r >= rows) return;
  const float* p = src + (size_t)r * 256;
  float s = 0.f;
#pragma unroll
  for (int j = 0; j < 4; ++j) {
    float v = p[lane + 64 * j];
    s += v * v;
  }
#pragma unroll
  for (int off = 32; off > 0; off >>= 1) s += __shfl_down(s, off, 64);
  if (lane == 0) dst[r] = s;
}

__global__ __launch_bounds__(256) void init_keys(u64_t* __restrict__ keys) {
  keys[(size_t)blockIdx.x * 256 + threadIdx.x] = ~0ull;
}

// per row: idx from key, write z_latent = z + (e - z), quant-loss partial sums
__global__ __launch_bounds__(256) void gather_quant(
    const u64_t* __restrict__ keys, const float* __restrict__ emb,
    const float* __restrict__ z_e, float* __restrict__ zlat,
    int* __restrict__ idx_out, float* __restrict__ qparts) {
  const int sub = threadIdx.x >> 6;
  const int lane = threadIdx.x & 63;
  const int r = blockIdx.x * 4 + sub;
  const int idx = (int)(keys[r] & 0xFFFFFFFFull);
  if (lane == 0) idx_out[r] = idx;
  float s = 0.f;
#pragma unroll
  for (int j = 0; j < 4; ++j) {
    const int d = lane + 64 * j;
    float e = emb[(size_t)idx * 256 + d];
    float z = z_e[(size_t)r * 256 + d];
    float df = e - z;
    s += df * df;
    zlat[(size_t)r * 256 + d] = z + df;  // fl(z_e + fl(z_q - z_e)) — exact ref order
  }
#pragma unroll
  for (int off = 32; off > 0; off >>= 1) s += __shfl_down(s, off, 64);
  __shared__ float red[4];
  if (lane == 0) red[sub] = s;
  __syncthreads();
  if (threadIdx.x == 0) qparts[blockIdx.x] = (red[0] + red[1]) + (red[2] + red[3]);
}

__global__ __launch_bounds__(256) void final_loss(
    const float* __restrict__ qparts, int nq,
    const float* __restrict__ rparts, int nr, float* __restrict__ out) {
  const int tid = threadIdx.x;
  double sq = 0.0, sr = 0.0;
  for (int i = tid; i < nq; i += 256) sq += (double)qparts[i];
  for (int i = tid; i < nr; i += 256) sr += (double)rparts[i];
  __shared__ double bq[256], br[256];
  bq[tid] = sq;
  br[tid] = sr;
  __syncthreads();
  for (int off = 128; off > 0; off >>= 1) {
    if (tid < off) {
      bq[tid] += bq[tid + off];
      br[tid] += br[tid + off];
    }
    __syncthreads();
  }
  if (tid == 0) {
    double qm = bq[0] / ((double)NROWS * 256.0);
    double rm = br[0] / ((double)NROWS * 512.0);
    out[(size_t)NROWS * 256] = (float)(rm + 1.25 * qm);  // recon + (1+BETA)*quant
  }
}

extern "C" void kernel_launch(void* const* d_in, const int* in_sizes, int n_in,
                              void* d_out, int out_size, void* d_ws, size_t ws_size,
                              hipStream_t stream) {
  const float* x   = (const float*)d_in[0];
  const float* ew1 = (const float*)d_in[1];
  const float* eb1 = (const float*)d_in[2];
  const float* ew2 = (const float*)d_in[3];
  const float* eb2 = (const float*)d_in[4];
  const float* ew3 = (const float*)d_in[5];
  const float* eb3 = (const float*)d_in[6];
  const float* dw1 = (const float*)d_in[7];
  const float* db1 = (const float*)d_in[8];
  const float* dw2 = (const float*)d_in[9];
  const float* db2 = (const float*)d_in[10];
  const float* dw3 = (const float*)d_in[11];
  const float* db3 = (const float*)d_in[12];
  const float* emb = (const float*)d_in[13];

  char* ws = (char*)d_ws;
  // region A (0..33.5MB): enc h1 f32 -> {e16f, maxesq, emb16, w*f} after enc2
  float* h1            = (float*)(ws);
  unsigned short* e16f = (unsigned short*)(ws);               // 1 MB
  float* maxesq        = (float*)(ws + 2097152ull);           // 256 B
  unsigned short* emb16 = (unsigned short*)(ws + 4194304ull); // 1 MB
  unsigned short* w1f  = (unsigned short*)(ws + 5242880ull);  // 64 KB
  unsigned short* w2f  = (unsigned short*)(ws + 5308416ull);  // 16 KB
  unsigned short* w3f  = (unsigned short*)(ws + 5324800ull);  // 64 KB
  // region B (33.5..100.6MB): enc h2 f32 -> z16t -> {h2_16, h1_16} after dist
  float* h2            = (float*)(ws + 33554432ull);
  unsigned short* z16t = (unsigned short*)(ws + 33554432ull);   // 67 MB
  unsigned short* h2_16 = (unsigned short*)(ws + 33554432ull);  // 33.5 MB
  unsigned short* h1_16 = (unsigned short*)(ws + 67108864ull);  // 16.8 MB
  // persistent
  float* z_e    = (float*)(ws + 100663296ull);   // N x 256
  float* zsq    = (float*)(ws + 234881024ull);   // N
  float* esq    = (float*)(ws + 235405312ull);   // KE
  u64_t* keys   = (u64_t*)(ws + 235413504ull);   // N
  int* idx      = (int*)(ws + 236462080ull);     // N
  float* qparts = (float*)(ws + 236986368ull);   // N/4
  float* rparts = (float*)(ws + 237117440ull);   // 2048

  float* out = (float*)d_out;
  dim3 blk(256);

  // encoder: 512 -> 64 -> 128 -> 256  (f32 path unchanged -> bit-exact z_e;
  // enc3 additionally emits z16t from its epilogue registers)
  gemm64<0><<<dim3(NROWS / 64, 1), blk, 0, stream>>>(x, ew1, eb1, h1, NROWS, 64, 512,
      nullptr);
  gemm128<0, false><<<dim3(NROWS / 128, 1), blk, 0, stream>>>(h1, ew2, eb2, h2,
      128, 64, nullptr, nullptr, nullptr, nullptr);
  // h1 (region A) dead: decoder-side conversions (independent of z_e)
  cvt_rows16<<<dim3(KE * 256 / 8 / 256), blk, 0, stream>>>(emb, emb16);
  cvt_w16f<<<dim3(16), blk, 0, stream>>>(dw1, w1f, 128, 4096);
  cvt_w16f<<<dim3(4), blk, 0, stream>>>(dw2, w2f, 64, 1024);
  cvt_w16f<<<dim3(16), blk, 0, stream>>>(dw3, w3f, 512, 4096);
  gemm128<0, true><<<dim3(NROWS / 128, 2), blk, 0, stream>>>(h2, ew3, eb3, z_e,
      256, 128, nullptr, nullptr, nullptr, z16t);

  rowsq<<<dim3(NROWS / 4), blk, 0, stream>>>(z_e, zsq, NROWS);
  rowsq<<<dim3(KE / 4), blk, 0, stream>>>(emb, esq, KE);
  max_esq<<<dim3(1), blk, 0, stream>>>(esq, maxesq);
  init_keys<<<dim3(NROWS / 256), blk, 0, stream>>>(keys);

  cvt_e16f<<<dim3(KE * 256 / 8 / 256), blk, 0, stream>>>(emb, e16f);

  // bound + deferred exact rescore (bit-identical selection) — r15 kernel
  dist_g256<<<dim3(NROWS / 256), blk, 0, stream>>>(z16t, e16f, z_e, emb, zsq, esq,
      maxesq, keys);

  gather_quant<<<dim3(NROWS / 4), blk, 0, stream>>>(keys, emb, z_e, out, idx, qparts);

  // decoder: bf16 MFMA (loss-only path, 2% threshold; z16t dead -> h*_16)
  dec_mfma<256, 128, 128, true, false><<<dim3(NROWS / 128), blk, 0, stream>>>(
      emb16, w1f, db1, h2_16, nullptr, nullptr, idx);
  dec_mfma<128, 64, 64, false, false><<<dim3(NROWS / 128), blk, 0, stream>>>(
      h2_16, w2f, db2, h1_16, nullptr, nullptr, nullptr);
  dec_mfma<64, 256, 512, false, true><<<dim3((NROWS / 128) * 2), blk, 0, stream>>>(
      h1_16, w3f, db3, nullptr, x, rparts, nullptr);

  final_loss<<<dim3(1), blk, 0, stream>>>(qparts, NROWS / 4, rparts, 2048, out);
}

// Round 19
// 1197.655 us; speedup vs baseline: 1.0446x; 1.0118x over previous
//
#include <hip/hip_runtime.h>

#define NROWS 131072
#define KE 2048
#define CAND_CAP 8192

typedef unsigned long long u64_t;
typedef unsigned int u32;
typedef __attribute__((ext_vector_type(8))) short bf16x8;
typedef __attribute__((ext_vector_type(4))) float f32x4;

__device__ __forceinline__ unsigned f32_key(float f) {
  unsigned u = __float_as_uint(f);
  return (u & 0x80000000u) ? ~u : (u | 0x80000000u);
}

__device__ __forceinline__ unsigned short bf16_rne(float f) {
  unsigned u = __float_as_uint(f);
  u += 0x7FFFu + ((u >> 16) & 1u);
  return (unsigned short)(u >> 16);
}

// ---------------------------------------------------------------------------
// 64x64 tile f32 GEMM (UNCHANGED — enc1). MODE 0 only.
// ---------------------------------------------------------------------------
template <int MODE>
__global__ __launch_bounds__(256) void gemm64(
    const float* __restrict__ A, const float* __restrict__ B,
    const float* __restrict__ bias, float* __restrict__ C,
    int M, int N, int K,
    const int* __restrict__ gidx) {
  __shared__ __align__(16) float As[16][68];
  __shared__ __align__(16) float Bs[16][68];

  const int tid = threadIdx.x;
  const int tx = tid & 15;
  const int ty = tid >> 4;
  const int arow = blockIdx.x * 64;
  const int bcol = blockIdx.y * 64;

  const int lr = tid >> 2;
  const int lc = (tid & 3) * 4;
  int ga = arow + lr;
  if (MODE == 1) ga = gidx[ga];
  const float* Ap = A + (size_t)ga * K + lc;

  const int bkr = tid >> 4;
  const int bc4 = (tid & 15) * 4;
  const float* Bp = B + (size_t)bkr * N + bcol + bc4;

  float acc[4][4] = {};

  for (int kt = 0; kt < K; kt += 16) {
    float4 av = *reinterpret_cast<const float4*>(Ap);
    As[lc + 0][lr] = av.x;
    As[lc + 1][lr] = av.y;
    As[lc + 2][lr] = av.z;
    As[lc + 3][lr] = av.w;
    float4 bv = *reinterpret_cast<const float4*>(Bp);
    *reinterpret_cast<float4*>(&Bs[bkr][bc4]) = bv;
    Bp += (size_t)16 * N;
    Ap += 16;
    __syncthreads();
#pragma unroll
    for (int k = 0; k < 16; ++k) {
      float4 a = *reinterpret_cast<const float4*>(&As[k][ty * 4]);
      float4 b = *reinterpret_cast<const float4*>(&Bs[k][tx * 4]);
      acc[0][0] += a.x * b.x; acc[0][1] += a.x * b.y; acc[0][2] += a.x * b.z; acc[0][3] += a.x * b.w;
      acc[1][0] += a.y * b.x; acc[1][1] += a.y * b.y; acc[1][2] += a.y * b.z; acc[1][3] += a.y * b.w;
      acc[2][0] += a.z * b.x; acc[2][1] += a.z * b.y; acc[2][2] += a.z * b.z; acc[2][3] += a.z * b.w;
      acc[3][0] += a.w * b.x; acc[3][1] += a.w * b.y; acc[3][2] += a.w * b.z; acc[3][3] += a.w * b.w;
    }
    __syncthreads();
  }

#pragma unroll
  for (int i = 0; i < 4; ++i) {
    const int row = arow + ty * 4 + i;
    float4 v;
    v.x = fmaxf(acc[i][0] + bias[bcol + tx * 4 + 0], 0.f);
    v.y = fmaxf(acc[i][1] + bias[bcol + tx * 4 + 1], 0.f);
    v.z = fmaxf(acc[i][2] + bias[bcol + tx * 4 + 2], 0.f);
    v.w = fmaxf(acc[i][3] + bias[bcol + tx * 4 + 3], 0.f);
    *reinterpret_cast<float4*>(&C[(size_t)row * N + bcol + tx * 4]) = v;
  }
}

// ---------------------------------------------------------------------------
// 128x128 tile f32 GEMM (UNCHANGED — enc2/enc3). Mode 0 only instantiated.
// ---------------------------------------------------------------------------
template <int MODE>
__global__ __launch_bounds__(256) void gemm128(
    const float* __restrict__ A, const float* __restrict__ B,
    const float* __restrict__ bias, float* __restrict__ C,
    int N, int K,
    const int* __restrict__ gidx,
    const float* __restrict__ X,
    float* __restrict__ parts) {
  __shared__ __align__(16) char smem[17408];
  float (*As)[132] = (float(*)[132])smem;
  float (*Bs)[132] = (float(*)[132])(smem + 8448);

  const int tid = threadIdx.x;
  const int tx = tid & 15;
  const int ty = tid >> 4;
  const int arow = blockIdx.x * 128;
  const int bcol = blockIdx.y * 128;

  const int r0 = tid >> 2;
  const int r1 = r0 + 64;
  const int lc = (tid & 3) * 4;
  int ga0 = arow + r0, ga1 = arow + r1;
  if (MODE == 1) { ga0 = gidx[ga0]; ga1 = gidx[ga1]; }
  const float* Ap0 = A + (size_t)ga0 * K + lc;
  const float* Ap1 = A + (size_t)ga1 * K + lc;

  const int bk0 = tid >> 5;
  const int bc0 = (tid & 31) * 4;
  const float* Bp0 = B + (size_t)bk0 * N + bcol + bc0;
  const float* Bp1 = B + (size_t)(bk0 + 8) * N + bcol + bc0;

  float acc[8][8] = {};

  for (int kt = 0; kt < K; kt += 16) {
    float4 a0 = *reinterpret_cast<const float4*>(Ap0);
    float4 a1 = *reinterpret_cast<const float4*>(Ap1);
    As[lc + 0][r0] = a0.x; As[lc + 1][r0] = a0.y; As[lc + 2][r0] = a0.z; As[lc + 3][r0] = a0.w;
    As[lc + 0][r1] = a1.x; As[lc + 1][r1] = a1.y; As[lc + 2][r1] = a1.z; As[lc + 3][r1] = a1.w;
    float4 b0 = *reinterpret_cast<const float4*>(Bp0);
    float4 b1 = *reinterpret_cast<const float4*>(Bp1);
    *reinterpret_cast<float4*>(&Bs[bk0][bc0]) = b0;
    *reinterpret_cast<float4*>(&Bs[bk0 + 8][bc0]) = b1;
    Bp0 += (size_t)16 * N; Bp1 += (size_t)16 * N;
    Ap0 += 16; Ap1 += 16;
    __syncthreads();
#pragma unroll
    for (int k = 0; k < 16; ++k) {
      float4 av0 = *reinterpret_cast<const float4*>(&As[k][ty * 4]);
      float4 av1 = *reinterpret_cast<const float4*>(&As[k][64 + ty * 4]);
      float4 bv0 = *reinterpret_cast<const float4*>(&Bs[k][tx * 4]);
      float4 bv1 = *reinterpret_cast<const float4*>(&Bs[k][64 + tx * 4]);
      const float a[8] = {av0.x, av0.y, av0.z, av0.w, av1.x, av1.y, av1.z, av1.w};
      const float b[8] = {bv0.x, bv0.y, bv0.z, bv0.w, bv1.x, bv1.y, bv1.z, bv1.w};
#pragma unroll
      for (int i = 0; i < 8; ++i)
#pragma unroll
        for (int j = 0; j < 8; ++j) acc[i][j] += a[i] * b[j];
    }
    __syncthreads();
  }

#pragma unroll
  for (int i = 0; i < 8; ++i) {
    const int row = arow + (i >> 2) * 64 + ty * 4 + (i & 3);
    const int c0 = bcol + tx * 4;
    const int c1 = bcol + 64 + tx * 4;
    float4 v0, v1;
    v0.x = fmaxf(acc[i][0] + bias[c0 + 0], 0.f);
    v0.y = fmaxf(acc[i][1] + bias[c0 + 1], 0.f);
    v0.z = fmaxf(acc[i][2] + bias[c0 + 2], 0.f);
    v0.w = fmaxf(acc[i][3] + bias[c0 + 3], 0.f);
    v1.x = fmaxf(acc[i][4] + bias[c1 + 0], 0.f);
    v1.y = fmaxf(acc[i][5] + bias[c1 + 1], 0.f);
    v1.z = fmaxf(acc[i][6] + bias[c1 + 2], 0.f);
    v1.w = fmaxf(acc[i][7] + bias[c1 + 3], 0.f);
    *reinterpret_cast<float4*>(&C[(size_t)row * N + c0]) = v0;
    *reinterpret_cast<float4*>(&C[(size_t)row * N + c1]) = v1;
  }
}

// z16t for 256-row blocks (separate pass — no aliasing with h2; r16 version)
__global__ __launch_bounds__(256) void cvt_z16t(const float* __restrict__ z_e,
                                                unsigned short* __restrict__ z16t) {
  const int c = blockIdx.x * 256 + threadIdx.x;
  const int lane = c & 63;
  const int kb = (c >> 6) & 7;
  const int fr = (c >> 9) & 3;
  const int w = (c >> 11) & 3;
  const int rowblk = c >> 13;
  const int row = rowblk * 256 + w * 64 + fr * 16 + (lane & 15);
  const int k0 = kb * 32 + (lane >> 4) * 8;
  const float* p = z_e + (size_t)row * 256 + k0;
  const float4 v0 = *reinterpret_cast<const float4*>(p);
  const float4 v1 = *reinterpret_cast<const float4*>(p + 4);
  const float f[8] = {v0.x, v0.y, v0.z, v0.w, v1.x, v1.y, v1.z, v1.w};
  unsigned short s[8];
#pragma unroll
  for (int j = 0; j < 8; ++j) s[j] = bf16_rne(f[j]);
  uint4 o;
  o.x = (u32)s[0] | ((u32)s[1] << 16);
  o.y = (u32)s[2] | ((u32)s[3] << 16);
  o.z = (u32)s[4] | ((u32)s[5] << 16);
  o.w = (u32)s[6] | ((u32)s[7] << 16);
  *reinterpret_cast<uint4*>(z16t + (size_t)c * 8) = o;
}

// e16f: FRAGMENT-MAJOR emb tiles (UNCHANGED)
__global__ __launch_bounds__(256) void cvt_e16f(const float* __restrict__ emb,
                                                unsigned short* __restrict__ e16f) {
  const int c = blockIdx.x * 256 + threadIdx.x;  // 65536 chunks
  const int l = c & 63;
  const int fc = (c >> 6) & 7;
  const int t = c >> 9;
  const int kb = t & 7;
  const int ct = t >> 3;
  const int col = ct * 128 + fc * 16 + (l & 15);
  const int k0 = kb * 32 + (l >> 4) * 8;
  const float* p = emb + (size_t)col * 256 + k0;
  const float4 v0 = *reinterpret_cast<const float4*>(p);
  const float4 v1 = *reinterpret_cast<const float4*>(p + 4);
  const float f[8] = {v0.x, v0.y, v0.z, v0.w, v1.x, v1.y, v1.z, v1.w};
  unsigned short s8[8];
#pragma unroll
  for (int j = 0; j < 8; ++j) s8[j] = bf16_rne(f[j]);
  uint4 o;
  o.x = (u32)s8[0] | ((u32)s8[1] << 16);
  o.y = (u32)s8[2] | ((u32)s8[3] << 16);
  o.z = (u32)s8[4] | ((u32)s8[5] << 16);
  o.w = (u32)s8[6] | ((u32)s8[7] << 16);
  *reinterpret_cast<uint4*>(e16f + (size_t)c * 8) = o;
}

// plain f32 -> bf16 row-major (emb16), 8 elems/thread
__global__ __launch_bounds__(256) void cvt_rows16(const float* __restrict__ src,
                                                  unsigned short* __restrict__ dst) {
  const int i = blockIdx.x * 256 + threadIdx.x;
  const float4 v0 = *reinterpret_cast<const float4*>(src + (size_t)i * 8);
  const float4 v1 = *reinterpret_cast<const float4*>(src + (size_t)i * 8 + 4);
  const float f[8] = {v0.x, v0.y, v0.z, v0.w, v1.x, v1.y, v1.z, v1.w};
  unsigned short s[8];
#pragma unroll
  for (int j = 0; j < 8; ++j) s[j] = bf16_rne(f[j]);
  uint4 o;
  o.x = (u32)s[0] | ((u32)s[1] << 16);
  o.y = (u32)s[2] | ((u32)s[3] << 16);
  o.z = (u32)s[4] | ((u32)s[5] << 16);
  o.w = (u32)s[6] | ((u32)s[7] << 16);
  *reinterpret_cast<uint4*>(dst + (size_t)i * 8) = o;
}

// weights -> fragment-major bf16 (UNCHANGED)
__global__ __launch_bounds__(256) void cvt_w16f(const float* __restrict__ W,
                                                unsigned short* __restrict__ Wf,
                                                int N, int total) {
  const int c = blockIdx.x * 256 + threadIdx.x;
  if (c >= total) return;
  const int l = c & 63;
  const int f = c >> 6;
  const int ng = N >> 4;
  const int cg = f % ng;
  const int kb = f / ng;
  const int col = cg * 16 + (l & 15);
  const int k0 = kb * 32 + ((l >> 4) & 3) * 8;
  unsigned short s[8];
#pragma unroll
  for (int j = 0; j < 8; ++j) s[j] = bf16_rne(W[(size_t)(k0 + j) * N + col]);
  uint4 o;
  o.x = (u32)s[0] | ((u32)s[1] << 16);
  o.y = (u32)s[2] | ((u32)s[3] << 16);
  o.z = (u32)s[4] | ((u32)s[5] << 16);
  o.w = (u32)s[6] | ((u32)s[7] << 16);
  *reinterpret_cast<uint4*>(Wf + (size_t)c * 8) = o;
}

// ---------------------------------------------------------------------------
// dist_g256 (r15 version verbatim — best-measured dist variant).
// ---------------------------------------------------------------------------
__global__ __launch_bounds__(256, 1) void dist_g256(
    const unsigned short* __restrict__ z16t, const unsigned short* __restrict__ e16f,
    const float* __restrict__ zf, const float* __restrict__ ef,
    const float* __restrict__ zsq, const float* __restrict__ esq,
    const float* __restrict__ maxesq, u64_t* __restrict__ keys) {
  __shared__ float esq_lds[2048];
  __shared__ float me1_lds[256];
  __shared__ float rowmin_lds[256];
  __shared__ unsigned cand[CAND_CAP];
  __shared__ unsigned cnt;

  const int tid = threadIdx.x;
  const int l = tid & 63;
  const int w = tid >> 6;
  const int l15 = tid & 15;
  const int lk = (tid >> 4) & 3;
  const int arow = blockIdx.x * 256;

  if (tid == 0) cnt = 0;
  {
    for (int i = tid; i < 2048; i += 256) esq_lds[i] = esq[i];
    me1_lds[tid] = 0.009765625f * sqrtf(zsq[arow + tid]);  // 1.25 * 2^-7
    rowmin_lds[tid] = 3.402823466e38f;
  }
  const float semax = sqrtf(maxesq[0]);

  bf16x8 a[4][8];
  {
    const char* zb = (const char*)z16t + (size_t)blockIdx.x * 131072 + w * 32768 + l * 16;
#pragma unroll
    for (int fr = 0; fr < 4; ++fr)
#pragma unroll
      for (int kb = 0; kb < 8; ++kb)
        a[fr][kb] = *reinterpret_cast<const bf16x8*>(zb + fr * 8192 + kb * 1024);
  }

  auto rescore = [&](unsigned e) {  // exact ascending-k chain (bit-exact)
    const int row = arow + (int)(e >> 11);
    const int col = (int)(e & 2047u);
    const float* zp = zf + (size_t)row * 256;
    const float* ep = ef + (size_t)col * 256;
    float p = 0.f;
#pragma unroll 8
    for (int k4 = 0; k4 < 256; k4 += 4) {
      const float4 zv = *reinterpret_cast<const float4*>(zp + k4);
      const float4 ev = *reinterpret_cast<const float4*>(ep + k4);
      p = fmaf(zv.x, ev.x, p);
      p = fmaf(zv.y, ev.y, p);
      p = fmaf(zv.z, ev.z, p);
      p = fmaf(zv.w, ev.w, p);
    }
    const float dsc = (zsq[row] - 2.f * p) + esq[col];
    const u64_t kk = ((u64_t)f32_key(dsc) << 32) | (unsigned)col;
    atomicMin(&keys[row], kk);
  };

  __syncthreads();

  const char* eb = (const char*)e16f + (size_t)l * 16;
  const int ct0 = (int)((blockIdx.x * 5u) & 15u);

  f32x4 acc[4][8];
#pragma unroll
  for (int fr = 0; fr < 4; ++fr)
#pragma unroll
    for (int fc = 0; fc < 8; ++fc) acc[fr][fc] = (f32x4){0.f, 0.f, 0.f, 0.f};

  bf16x8 bc[8], bn[8];
#pragma unroll
  for (int fc = 0; fc < 8; ++fc)
    bc[fc] = *reinterpret_cast<const bf16x8*>(eb + (size_t)(ct0 * 8) * 8192 + fc * 1024);

#pragma unroll 1
  for (int ctl = 0; ctl < 16; ++ctl) {
    const int ct = (ct0 + ctl) & 15;
#pragma unroll
    for (int kb = 0; kb < 8; ++kb) {
      const int nctl = (kb == 7) ? ctl + 1 : ctl;
      const int nkb = (kb == 7) ? 0 : kb + 1;
      if (nctl < 16) {
        const int nct = (ct0 + nctl) & 15;
        const char* tb = eb + (size_t)(nct * 8 + nkb) * 8192;
#pragma unroll
        for (int fc = 0; fc < 8; ++fc)
          bn[fc] = *reinterpret_cast<const bf16x8*>(tb + fc * 1024);
      }
#pragma unroll
      for (int fr = 0; fr < 4; ++fr)
#pragma unroll
        for (int fc = 0; fc < 8; ++fc)
          acc[fr][fc] = __builtin_amdgcn_mfma_f32_16x16x32_bf16(a[fr][kb], bc[fc], acc[fr][fc], 0, 0, 0);
#pragma unroll
      for (int fc = 0; fc < 8; ++fc) bc[fc] = bn[fc];
    }
    {
      float esqv[8], se[8];
#pragma unroll
      for (int fc = 0; fc < 8; ++fc) {
        esqv[fc] = esq_lds[ct * 128 + fc * 16 + l15];
        se[fc] = sqrtf(esqv[fc]);
      }
#pragma unroll
      for (int fr = 0; fr < 4; ++fr)
#pragma unroll
        for (int rg = 0; rg < 4; ++rg) {
          float s8[8];
          float lm = 3.402823466e38f;
#pragma unroll
          for (int fc = 0; fc < 8; ++fc) {
            s8[fc] = fmaf(-2.f, acc[fr][fc][rg], esqv[fc]);
            lm = fminf(lm, s8[fc]);
          }
#pragma unroll
          for (int m = 1; m < 16; m <<= 1) lm = fminf(lm, __shfl_xor(lm, m, 64));
          const int row = w * 64 + fr * 16 + lk * 4 + rg;
          const float rm = fminf(rowmin_lds[row], lm);
          if (l15 == 0) rowmin_lds[row] = rm;
          const float me1 = me1_lds[row];
#pragma unroll
          for (int fc = 0; fc < 8; ++fc) {
            const float thr = rm + me1 * (se[fc] + semax) + 1e-7f;
            if (s8[fc] <= thr) {
              const unsigned code =
                  ((unsigned)row << 11) | (unsigned)(ct * 128 + fc * 16 + l15);
              const unsigned idx = atomicAdd(&cnt, 1u);
              if (idx < CAND_CAP) cand[idx] = code;
              else rescore(code);
            }
          }
        }
#pragma unroll
      for (int fr = 0; fr < 4; ++fr)
#pragma unroll
        for (int fc = 0; fc < 8; ++fc) acc[fr][fc] = (f32x4){0.f, 0.f, 0.f, 0.f};
    }
  }

  __syncthreads();
  const unsigned nc = cnt < CAND_CAP ? cnt : CAND_CAP;
  for (unsigned i = tid; i < nc; i += 256) rescore(cand[i]);
}

// ---------------------------------------------------------------------------
// dec_mfma (UNCHANGED — validated). bf16 MFMA decoder layer.
// ---------------------------------------------------------------------------
template <int K, int NT, int NTOT, bool GATHER, bool LOSS>
__global__ __launch_bounds__(256, 1) void dec_mfma(
    const unsigned short* __restrict__ A16, const unsigned short* __restrict__ Wf,
    const float* __restrict__ bias, unsigned short* __restrict__ C16,
    const float* __restrict__ X, float* __restrict__ parts,
    const int* __restrict__ gidx) {
  constexpr int CH = K / 8;
  constexpr int KB = K / 32;
  constexpr int CG = NT / 16;
  constexpr int NB = NTOT / NT;
  __shared__ __align__(16) unsigned short Atile[128 * K];
  __shared__ int idx_l[128];
  __shared__ float rbuf[256];

  const int tid = threadIdx.x;
  const int l = tid & 63;
  const int w = tid >> 6;
  const int arow = (int)(blockIdx.x / NB) * 128;
  const int bcol = (int)(blockIdx.x % NB) * NT;

  if (GATHER) {
    if (tid < 128) idx_l[tid] = gidx[arow + tid];
    __syncthreads();
  }
  for (int q = tid; q < 128 * CH; q += 256) {
    const int r = q / CH;
    const int c = q % CH;
    const unsigned short* src = GATHER
        ? A16 + (size_t)idx_l[r] * K + c * 8
        : A16 + (size_t)(arow + r) * K + c * 8;
    const uint4 v = *reinterpret_cast<const uint4*>(src);
    *reinterpret_cast<uint4*>(&Atile[(r * CH + (c ^ (r & 7))) * 8]) = v;
  }

  bf16x8 wf[KB][CG];
#pragma unroll
  for (int kb = 0; kb < KB; ++kb)
#pragma unroll
    for (int cg = 0; cg < CG; ++cg)
      wf[kb][cg] = *reinterpret_cast<const bf16x8*>(
          Wf + ((size_t)(kb * (NTOT / 16) + bcol / 16 + cg) * 64 + l) * 8);

  __syncthreads();

  f32x4 acc[2][CG];
#pragma unroll
  for (int fr = 0; fr < 2; ++fr)
#pragma unroll
    for (int cg = 0; cg < CG; ++cg) acc[fr][cg] = (f32x4){0.f, 0.f, 0.f, 0.f};

#pragma unroll
  for (int kb = 0; kb < KB; ++kb) {
    bf16x8 af[2];
#pragma unroll
    for (int fr = 0; fr < 2; ++fr) {
      const int r = w * 32 + fr * 16 + (l & 15);
      const int c = (kb * 4 + ((l >> 4) & 3)) ^ (r & 7);
      af[fr] = *reinterpret_cast<const bf16x8*>(&Atile[(r * CH + c) * 8]);
    }
#pragma unroll
    for (int fr = 0; fr < 2; ++fr)
#pragma unroll
      for (int cg = 0; cg < CG; ++cg)
        acc[fr][cg] = __builtin_amdgcn_mfma_f32_16x16x32_bf16(af[fr], wf[kb][cg], acc[fr][cg], 0, 0, 0);
  }

  if (!LOSS) {
#pragma unroll
    for (int fr = 0; fr < 2; ++fr)
#pragma unroll
      for (int cg = 0; cg < CG; ++cg) {
        const int col = bcol + cg * 16 + (l & 15);
        const float bv = bias[col];
#pragma unroll
        for (int rg = 0; rg < 4; ++rg) {
          const int row = arow + w * 32 + fr * 16 + ((l >> 4) & 3) * 4 + rg;
          const float v = fmaxf(acc[fr][cg][rg] + bv, 0.f);
          C16[(size_t)row * NTOT + col] = bf16_rne(v);
        }
      }
  } else {
    float local = 0.f;
#pragma unroll
    for (int fr = 0; fr < 2; ++fr)
#pragma unroll
      for (int cg = 0; cg < CG; ++cg) {
        const int col = bcol + cg * 16 + (l & 15);
        const float bv = bias[col];
#pragma unroll
        for (int rg = 0; rg < 4; ++rg) {
          const int row = arow + w * 32 + fr * 16 + ((l >> 4) & 3) * 4 + rg;
          const float v = fmaxf(acc[fr][cg][rg] + bv, 0.f);
          const float d = v - X[(size_t)row * NTOT + col];
          local = fmaf(d, d, local);
        }
      }
    rbuf[tid] = local;
    __syncthreads();
    for (int off = 128; off > 0; off >>= 1) {
      if (tid < off) rbuf[tid] += rbuf[tid + off];
      __syncthreads();
    }
    if (tid == 0) parts[blockIdx.x] = rbuf[0];
  }
}

__global__ __launch_bounds__(256) void max_esq(const float* __restrict__ esq,
                                               float* __restrict__ outv) {
  __shared__ float red[256];
  float m = 0.f;
  for (int i = threadIdx.x; i < KE; i += 256) m = fmaxf(m, esq[i]);
  red[threadIdx.x] = m;
  __syncthreads();
  for (int off = 128; off > 0; off >>= 1) {
    if (threadIdx.x < off) red[threadIdx.x] = fmaxf(red[threadIdx.x], red[threadIdx.x + off]);
    __syncthreads();
  }
  if (threadIdx.x == 0) outv[0] = red[0];
}

// sum of squares per row (256 cols); block = 4 rows x 64 lanes
__global__ __launch_bounds__(256) void rowsq(const float* __restrict__ src,
                                             float* __restrict__ dst, int rows) {
  const int sub = threadIdx.x >> 6;
  const int lane = threadIdx.x & 63;
  const int r = blockIdx.x * 4 + sub;
  if (r >= rows) return;
  const float* p = src + (size_t)r * 256;
  float s = 0.f;
#pragma unroll
  for (int j = 0; j < 4; ++j) {
    float v = p[lane + 64 * j];
    s += v * v;
  }
#pragma unroll
  for (int off = 32; off > 0; off >>= 1) s += __shfl_down(s, off, 64);
  if (lane == 0) dst[r] = s;
}

__global__ __launch_bounds__(256) void init_keys(u64_t* __restrict__ keys) {
  keys[(size_t)blockIdx.x * 256 + threadIdx.x] = ~0ull;
}

// per row: idx from key, write z_latent = z + (e - z), quant-loss partial sums
__global__ __launch_bounds__(256) void gather_quant(
    const u64_t* __restrict__ keys, const float* __restrict__ emb,
    const float* __restrict__ z_e, float* __restrict__ zlat,
    int* __restrict__ idx_out, float* __restrict__ qparts) {
  const int sub = threadIdx.x >> 6;
  const int lane = threadIdx.x & 63;
  const int r = blockIdx.x * 4 + sub;
  const int idx = (int)(keys[r] & 0xFFFFFFFFull);
  if (lane == 0) idx_out[r] = idx;
  float s = 0.f;
#pragma unroll
  for (int j = 0; j < 4; ++j) {
    const int d = lane + 64 * j;
    float e = emb[(size_t)idx * 256 + d];
    float z = z_e[(size_t)r * 256 + d];
    float df = e - z;
    s += df * df;
    zlat[(size_t)r * 256 + d] = z + df;  // fl(z_e + fl(z_q - z_e)) — exact ref order
  }
#pragma unroll
  for (int off = 32; off > 0; off >>= 1) s += __shfl_down(s, off, 64);
  __shared__ float red[4];
  if (lane == 0) red[sub] = s;
  __syncthreads();
  if (threadIdx.x == 0) qparts[blockIdx.x] = (red[0] + red[1]) + (red[2] + red[3]);
}

__global__ __launch_bounds__(256) void final_loss(
    const float* __restrict__ qparts, int nq,
    const float* __restrict__ rparts, int nr, float* __restrict__ out) {
  const int tid = threadIdx.x;
  double sq = 0.0, sr = 0.0;
  for (int i = tid; i < nq; i += 256) sq += (double)qparts[i];
  for (int i = tid; i < nr; i += 256) sr += (double)rparts[i];
  __shared__ double bq[256], br[256];
  bq[tid] = sq;
  br[tid] = sr;
  __syncthreads();
  for (int off = 128; off > 0; off >>= 1) {
    if (tid < off) {
      bq[tid] += bq[tid + off];
      br[tid] += br[tid + off];
    }
    __syncthreads();
  }
  if (tid == 0) {
    double qm = bq[0] / ((double)NROWS * 256.0);
    double rm = br[0] / ((double)NROWS * 512.0);
    out[(size_t)NROWS * 256] = (float)(rm + 1.25 * qm);  // recon + (1+BETA)*quant
  }
}

extern "C" void kernel_launch(void* const* d_in, const int* in_sizes, int n_in,
                              void* d_out, int out_size, void* d_ws, size_t ws_size,
                              hipStream_t stream) {
  const float* x   = (const float*)d_in[0];
  const float* ew1 = (const float*)d_in[1];
  const float* eb1 = (const float*)d_in[2];
  const float* ew2 = (const float*)d_in[3];
  const float* eb2 = (const float*)d_in[4];
  const float* ew3 = (const float*)d_in[5];
  const float* eb3 = (const float*)d_in[6];
  const float* dw1 = (const float*)d_in[7];
  const float* db1 = (const float*)d_in[8];
  const float* dw2 = (const float*)d_in[9];
  const float* db2 = (const float*)d_in[10];
  const float* dw3 = (const float*)d_in[11];
  const float* db3 = (const float*)d_in[12];
  const float* emb = (const float*)d_in[13];

  char* ws = (char*)d_ws;
  // region A (0..33.5MB): enc h1 f32 -> {e16f, maxesq, emb16, w*f} after enc2
  float* h1            = (float*)(ws);
  unsigned short* e16f = (unsigned short*)(ws);               // 1 MB
  float* maxesq        = (float*)(ws + 2097152ull);           // 256 B
  unsigned short* emb16 = (unsigned short*)(ws + 4194304ull); // 1 MB
  unsigned short* w1f  = (unsigned short*)(ws + 5242880ull);  // 64 KB
  unsigned short* w2f  = (unsigned short*)(ws + 5308416ull);  // 16 KB
  unsigned short* w3f  = (unsigned short*)(ws + 5324800ull);  // 64 KB
  // region B (33.5..100.6MB): enc h2 f32 -> z16t -> {h2_16, h1_16} after dist
  float* h2            = (float*)(ws + 33554432ull);
  unsigned short* z16t = (unsigned short*)(ws + 33554432ull);   // 67 MB
  unsigned short* h2_16 = (unsigned short*)(ws + 33554432ull);  // 33.5 MB
  unsigned short* h1_16 = (unsigned short*)(ws + 67108864ull);  // 16.8 MB
  // persistent
  float* z_e    = (float*)(ws + 100663296ull);   // N x 256
  float* zsq    = (float*)(ws + 234881024ull);   // N
  float* esq    = (float*)(ws + 235405312ull);   // KE
  u64_t* keys   = (u64_t*)(ws + 235413504ull);   // N
  int* idx      = (int*)(ws + 236462080ull);     // N
  float* qparts = (float*)(ws + 236986368ull);   // N/4
  float* rparts = (float*)(ws + 237117440ull);   // 2048

  float* out = (float*)d_out;
  dim3 blk(256);

  // encoder: 512 -> 64 -> 128 -> 256  (unchanged -> bit-exact z_e)
  gemm64<0><<<dim3(NROWS / 64, 1), blk, 0, stream>>>(x, ew1, eb1, h1, NROWS, 64, 512,
      nullptr);
  gemm128<0><<<dim3(NROWS / 128, 1), blk, 0, stream>>>(h1, ew2, eb2, h2,
      128, 64, nullptr, nullptr, nullptr);
  // h1 (region A) dead: decoder-side conversions (independent of z_e)
  cvt_rows16<<<dim3(KE * 256 / 8 / 256), blk, 0, stream>>>(emb, emb16);
  cvt_w16f<<<dim3(16), blk, 0, stream>>>(dw1, w1f, 128, 4096);
  cvt_w16f<<<dim3(4), blk, 0, stream>>>(dw2, w2f, 64, 1024);
  cvt_w16f<<<dim3(16), blk, 0, stream>>>(dw3, w3f, 512, 4096);
  gemm128<0><<<dim3(NROWS / 128, 2), blk, 0, stream>>>(h2, ew3, eb3, z_e,
      256, 128, nullptr, nullptr, nullptr);

  rowsq<<<dim3(NROWS / 4), blk, 0, stream>>>(z_e, zsq, NROWS);
  rowsq<<<dim3(KE / 4), blk, 0, stream>>>(emb, esq, KE);
  max_esq<<<dim3(1), blk, 0, stream>>>(esq, maxesq);
  init_keys<<<dim3(NROWS / 256), blk, 0, stream>>>(keys);

  // pre-tiled bf16 operand buffers (h2 region B dead after enc3; separate
  // cvt_z16t pass — kernel boundary provides the grid-wide sync that the
  // r18 fused variant lacked)
  cvt_z16t<<<dim3(NROWS * 256 / 8 / 256), blk, 0, stream>>>(z_e, z16t);
  cvt_e16f<<<dim3(KE * 256 / 8 / 256), blk, 0, stream>>>(emb, e16f);

  // bound + deferred exact rescore (bit-identical selection)
  dist_g256<<<dim3(NROWS / 256), blk, 0, stream>>>(z16t, e16f, z_e, emb, zsq, esq,
      maxesq, keys);

  gather_quant<<<dim3(NROWS / 4), blk, 0, stream>>>(keys, emb, z_e, out, idx, qparts);

  // decoder: bf16 MFMA (loss-only path, 2% threshold; z16t dead -> h*_16)
  dec_mfma<256, 128, 128, true, false><<<dim3(NROWS / 128), blk, 0, stream>>>(
      emb16, w1f, db1, h2_16, nullptr, nullptr, idx);
  dec_mfma<128, 64, 64, false, false><<<dim3(NROWS / 128), blk, 0, stream>>>(
      h2_16, w2f, db2, h1_16, nullptr, nullptr, nullptr);
  dec_mfma<64, 256, 512, false, true><<<dim3((NROWS / 128) * 2), blk, 0, stream>>>(
      h1_16, w3f, db3, nullptr, x, rparts, nullptr);

  final_loss<<<dim3(1), blk, 0, stream>>>(qparts, NROWS / 4, rparts, 2048, out);
}

// Round 20
// 1175.548 us; speedup vs baseline: 1.0643x; 1.0188x over previous
//
#include <hip/hip_runtime.h>

#define NROWS 131072
#define KE 2048
#define CAND_CAP 8192

typedef unsigned long long u64_t;
typedef unsigned int u32;
typedef __attribute__((ext_vector_type(8))) short bf16x8;
typedef __attribute__((ext_vector_type(4))) float f32x4;

__device__ __forceinline__ unsigned f32_key(float f) {
  unsigned u = __float_as_uint(f);
  return (u & 0x80000000u) ? ~u : (u | 0x80000000u);
}

__device__ __forceinline__ unsigned short bf16_rne(float f) {
  unsigned u = __float_as_uint(f);
  u += 0x7FFFu + ((u >> 16) & 1u);
  return (unsigned short)(u >> 16);
}

// ---------------------------------------------------------------------------
// 64x64 tile f32 GEMM (UNCHANGED — enc1). MODE 0 only.
// ---------------------------------------------------------------------------
template <int MODE>
__global__ __launch_bounds__(256) void gemm64(
    const float* __restrict__ A, const float* __restrict__ B,
    const float* __restrict__ bias, float* __restrict__ C,
    int M, int N, int K,
    const int* __restrict__ gidx) {
  __shared__ __align__(16) float As[16][68];
  __shared__ __align__(16) float Bs[16][68];

  const int tid = threadIdx.x;
  const int tx = tid & 15;
  const int ty = tid >> 4;
  const int arow = blockIdx.x * 64;
  const int bcol = blockIdx.y * 64;

  const int lr = tid >> 2;
  const int lc = (tid & 3) * 4;
  int ga = arow + lr;
  if (MODE == 1) ga = gidx[ga];
  const float* Ap = A + (size_t)ga * K + lc;

  const int bkr = tid >> 4;
  const int bc4 = (tid & 15) * 4;
  const float* Bp = B + (size_t)bkr * N + bcol + bc4;

  float acc[4][4] = {};

  for (int kt = 0; kt < K; kt += 16) {
    float4 av = *reinterpret_cast<const float4*>(Ap);
    As[lc + 0][lr] = av.x;
    As[lc + 1][lr] = av.y;
    As[lc + 2][lr] = av.z;
    As[lc + 3][lr] = av.w;
    float4 bv = *reinterpret_cast<const float4*>(Bp);
    *reinterpret_cast<float4*>(&Bs[bkr][bc4]) = bv;
    Bp += (size_t)16 * N;
    Ap += 16;
    __syncthreads();
#pragma unroll
    for (int k = 0; k < 16; ++k) {
      float4 a = *reinterpret_cast<const float4*>(&As[k][ty * 4]);
      float4 b = *reinterpret_cast<const float4*>(&Bs[k][tx * 4]);
      acc[0][0] += a.x * b.x; acc[0][1] += a.x * b.y; acc[0][2] += a.x * b.z; acc[0][3] += a.x * b.w;
      acc[1][0] += a.y * b.x; acc[1][1] += a.y * b.y; acc[1][2] += a.y * b.z; acc[1][3] += a.y * b.w;
      acc[2][0] += a.z * b.x; acc[2][1] += a.z * b.y; acc[2][2] += a.z * b.z; acc[2][3] += a.z * b.w;
      acc[3][0] += a.w * b.x; acc[3][1] += a.w * b.y; acc[3][2] += a.w * b.z; acc[3][3] += a.w * b.w;
    }
    __syncthreads();
  }

#pragma unroll
  for (int i = 0; i < 4; ++i) {
    const int row = arow + ty * 4 + i;
    float4 v;
    v.x = fmaxf(acc[i][0] + bias[bcol + tx * 4 + 0], 0.f);
    v.y = fmaxf(acc[i][1] + bias[bcol + tx * 4 + 1], 0.f);
    v.z = fmaxf(acc[i][2] + bias[bcol + tx * 4 + 2], 0.f);
    v.w = fmaxf(acc[i][3] + bias[bcol + tx * 4 + 3], 0.f);
    *reinterpret_cast<float4*>(&C[(size_t)row * N + bcol + tx * 4]) = v;
  }
}

// ---------------------------------------------------------------------------
// 128x128 tile f32 GEMM (UNCHANGED — enc2/enc3). Mode 0 only instantiated.
// ---------------------------------------------------------------------------
template <int MODE>
__global__ __launch_bounds__(256) void gemm128(
    const float* __restrict__ A, const float* __restrict__ B,
    const float* __restrict__ bias, float* __restrict__ C,
    int N, int K,
    const int* __restrict__ gidx,
    const float* __restrict__ X,
    float* __restrict__ parts) {
  __shared__ __align__(16) char smem[17408];
  float (*As)[132] = (float(*)[132])smem;
  float (*Bs)[132] = (float(*)[132])(smem + 8448);

  const int tid = threadIdx.x;
  const int tx = tid & 15;
  const int ty = tid >> 4;
  const int arow = blockIdx.x * 128;
  const int bcol = blockIdx.y * 128;

  const int r0 = tid >> 2;
  const int r1 = r0 + 64;
  const int lc = (tid & 3) * 4;
  int ga0 = arow + r0, ga1 = arow + r1;
  if (MODE == 1) { ga0 = gidx[ga0]; ga1 = gidx[ga1]; }
  const float* Ap0 = A + (size_t)ga0 * K + lc;
  const float* Ap1 = A + (size_t)ga1 * K + lc;

  const int bk0 = tid >> 5;
  const int bc0 = (tid & 31) * 4;
  const float* Bp0 = B + (size_t)bk0 * N + bcol + bc0;
  const float* Bp1 = B + (size_t)(bk0 + 8) * N + bcol + bc0;

  float acc[8][8] = {};

  for (int kt = 0; kt < K; kt += 16) {
    float4 a0 = *reinterpret_cast<const float4*>(Ap0);
    float4 a1 = *reinterpret_cast<const float4*>(Ap1);
    As[lc + 0][r0] = a0.x; As[lc + 1][r0] = a0.y; As[lc + 2][r0] = a0.z; As[lc + 3][r0] = a0.w;
    As[lc + 0][r1] = a1.x; As[lc + 1][r1] = a1.y; As[lc + 2][r1] = a1.z; As[lc + 3][r1] = a1.w;
    float4 b0 = *reinterpret_cast<const float4*>(Bp0);
    float4 b1 = *reinterpret_cast<const float4*>(Bp1);
    *reinterpret_cast<float4*>(&Bs[bk0][bc0]) = b0;
    *reinterpret_cast<float4*>(&Bs[bk0 + 8][bc0]) = b1;
    Bp0 += (size_t)16 * N; Bp1 += (size_t)16 * N;
    Ap0 += 16; Ap1 += 16;
    __syncthreads();
#pragma unroll
    for (int k = 0; k < 16; ++k) {
      float4 av0 = *reinterpret_cast<const float4*>(&As[k][ty * 4]);
      float4 av1 = *reinterpret_cast<const float4*>(&As[k][64 + ty * 4]);
      float4 bv0 = *reinterpret_cast<const float4*>(&Bs[k][tx * 4]);
      float4 bv1 = *reinterpret_cast<const float4*>(&Bs[k][64 + tx * 4]);
      const float a[8] = {av0.x, av0.y, av0.z, av0.w, av1.x, av1.y, av1.z, av1.w};
      const float b[8] = {bv0.x, bv0.y, bv0.z, bv0.w, bv1.x, bv1.y, bv1.z, bv1.w};
#pragma unroll
      for (int i = 0; i < 8; ++i)
#pragma unroll
        for (int j = 0; j < 8; ++j) acc[i][j] += a[i] * b[j];
    }
    __syncthreads();
  }

#pragma unroll
  for (int i = 0; i < 8; ++i) {
    const int row = arow + (i >> 2) * 64 + ty * 4 + (i & 3);
    const int c0 = bcol + tx * 4;
    const int c1 = bcol + 64 + tx * 4;
    float4 v0, v1;
    v0.x = fmaxf(acc[i][0] + bias[c0 + 0], 0.f);
    v0.y = fmaxf(acc[i][1] + bias[c0 + 1], 0.f);
    v0.z = fmaxf(acc[i][2] + bias[c0 + 2], 0.f);
    v0.w = fmaxf(acc[i][3] + bias[c0 + 3], 0.f);
    v1.x = fmaxf(acc[i][4] + bias[c1 + 0], 0.f);
    v1.y = fmaxf(acc[i][5] + bias[c1 + 1], 0.f);
    v1.z = fmaxf(acc[i][6] + bias[c1 + 2], 0.f);
    v1.w = fmaxf(acc[i][7] + bias[c1 + 3], 0.f);
    *reinterpret_cast<float4*>(&C[(size_t)row * N + c0]) = v0;
    *reinterpret_cast<float4*>(&C[(size_t)row * N + c1]) = v1;
  }
}

// z16t for 256-row blocks (separate pass — no aliasing with h2)
__global__ __launch_bounds__(256) void cvt_z16t(const float* __restrict__ z_e,
                                                unsigned short* __restrict__ z16t) {
  const int c = blockIdx.x * 256 + threadIdx.x;
  const int lane = c & 63;
  const int kb = (c >> 6) & 7;
  const int fr = (c >> 9) & 3;
  const int w = (c >> 11) & 3;
  const int rowblk = c >> 13;
  const int row = rowblk * 256 + w * 64 + fr * 16 + (lane & 15);
  const int k0 = kb * 32 + (lane >> 4) * 8;
  const float* p = z_e + (size_t)row * 256 + k0;
  const float4 v0 = *reinterpret_cast<const float4*>(p);
  const float4 v1 = *reinterpret_cast<const float4*>(p + 4);
  const float f[8] = {v0.x, v0.y, v0.z, v0.w, v1.x, v1.y, v1.z, v1.w};
  unsigned short s[8];
#pragma unroll
  for (int j = 0; j < 8; ++j) s[j] = bf16_rne(f[j]);
  uint4 o;
  o.x = (u32)s[0] | ((u32)s[1] << 16);
  o.y = (u32)s[2] | ((u32)s[3] << 16);
  o.z = (u32)s[4] | ((u32)s[5] << 16);
  o.w = (u32)s[6] | ((u32)s[7] << 16);
  *reinterpret_cast<uint4*>(z16t + (size_t)c * 8) = o;
}

// e16f: FRAGMENT-MAJOR emb tiles (UNCHANGED)
__global__ __launch_bounds__(256) void cvt_e16f(const float* __restrict__ emb,
                                                unsigned short* __restrict__ e16f) {
  const int c = blockIdx.x * 256 + threadIdx.x;  // 65536 chunks
  const int l = c & 63;
  const int fc = (c >> 6) & 7;
  const int t = c >> 9;
  const int kb = t & 7;
  const int ct = t >> 3;
  const int col = ct * 128 + fc * 16 + (l & 15);
  const int k0 = kb * 32 + (l >> 4) * 8;
  const float* p = emb + (size_t)col * 256 + k0;
  const float4 v0 = *reinterpret_cast<const float4*>(p);
  const float4 v1 = *reinterpret_cast<const float4*>(p + 4);
  const float f[8] = {v0.x, v0.y, v0.z, v0.w, v1.x, v1.y, v1.z, v1.w};
  unsigned short s8[8];
#pragma unroll
  for (int j = 0; j < 8; ++j) s8[j] = bf16_rne(f[j]);
  uint4 o;
  o.x = (u32)s8[0] | ((u32)s8[1] << 16);
  o.y = (u32)s8[2] | ((u32)s8[3] << 16);
  o.z = (u32)s8[4] | ((u32)s8[5] << 16);
  o.w = (u32)s8[6] | ((u32)s8[7] << 16);
  *reinterpret_cast<uint4*>(e16f + (size_t)c * 8) = o;
}

// plain f32 -> bf16 row-major (emb16), 8 elems/thread
__global__ __launch_bounds__(256) void cvt_rows16(const float* __restrict__ src,
                                                  unsigned short* __restrict__ dst) {
  const int i = blockIdx.x * 256 + threadIdx.x;
  const float4 v0 = *reinterpret_cast<const float4*>(src + (size_t)i * 8);
  const float4 v1 = *reinterpret_cast<const float4*>(src + (size_t)i * 8 + 4);
  const float f[8] = {v0.x, v0.y, v0.z, v0.w, v1.x, v1.y, v1.z, v1.w};
  unsigned short s[8];
#pragma unroll
  for (int j = 0; j < 8; ++j) s[j] = bf16_rne(f[j]);
  uint4 o;
  o.x = (u32)s[0] | ((u32)s[1] << 16);
  o.y = (u32)s[2] | ((u32)s[3] << 16);
  o.z = (u32)s[4] | ((u32)s[5] << 16);
  o.w = (u32)s[6] | ((u32)s[7] << 16);
  *reinterpret_cast<uint4*>(dst + (size_t)i * 8) = o;
}

// weights -> fragment-major bf16 (UNCHANGED)
__global__ __launch_bounds__(256) void cvt_w16f(const float* __restrict__ W,
                                                unsigned short* __restrict__ Wf,
                                                int N, int total) {
  const int c = blockIdx.x * 256 + threadIdx.x;
  if (c >= total) return;
  const int l = c & 63;
  const int f = c >> 6;
  const int ng = N >> 4;
  const int cg = f % ng;
  const int kb = f / ng;
  const int col = cg * 16 + (l & 15);
  const int k0 = kb * 32 + ((l >> 4) & 3) * 8;
  unsigned short s[8];
#pragma unroll
  for (int j = 0; j < 8; ++j) s[j] = bf16_rne(W[(size_t)(k0 + j) * N + col]);
  uint4 o;
  o.x = (u32)s[0] | ((u32)s[1] << 16);
  o.y = (u32)s[2] | ((u32)s[3] << 16);
  o.z = (u32)s[4] | ((u32)s[5] << 16);
  o.w = (u32)s[6] | ((u32)s[7] << 16);
  *reinterpret_cast<uint4*>(Wf + (size_t)c * 8) = o;
}

// ---------------------------------------------------------------------------
// dist_g256 (r15 logic + r20 edits):
// (1) PER-WAVE ct stagger: ct0 = (bid*5 + w*4) & 15 — waves on a CU issue
//     their 8x1KB load bursts 4 cts apart, so one wave's MFMA phase overlaps
//     another's load latency (intra-CU desynchronization). ct order is
//     correctness-irrelevant: rowmin rows are wave-partitioned, cand/cnt
//     are atomics, running-min proof is order-independent.
// (2) keys init folded into prologue (rows are block-exclusive; all
//     atomicMin's happen after the prologue barrier).
// ---------------------------------------------------------------------------
__global__ __launch_bounds__(256, 1) void dist_g256(
    const unsigned short* __restrict__ z16t, const unsigned short* __restrict__ e16f,
    const float* __restrict__ zf, const float* __restrict__ ef,
    const float* __restrict__ zsq, const float* __restrict__ esq,
    const float* __restrict__ maxesq, u64_t* __restrict__ keys) {
  __shared__ float esq_lds[2048];
  __shared__ float me1_lds[256];
  __shared__ float rowmin_lds[256];
  __shared__ unsigned cand[CAND_CAP];
  __shared__ unsigned cnt;

  const int tid = threadIdx.x;
  const int l = tid & 63;
  const int w = tid >> 6;
  const int l15 = tid & 15;
  const int lk = (tid >> 4) & 3;
  const int arow = blockIdx.x * 256;

  if (tid == 0) cnt = 0;
  {
    for (int i = tid; i < 2048; i += 256) esq_lds[i] = esq[i];
    me1_lds[tid] = 0.009765625f * sqrtf(zsq[arow + tid]);  // 1.25 * 2^-7
    rowmin_lds[tid] = 3.402823466e38f;
    keys[arow + tid] = ~0ull;  // block-exclusive rows; init before barrier
  }
  const float semax = sqrtf(maxesq[0]);

  bf16x8 a[4][8];
  {
    const char* zb = (const char*)z16t + (size_t)blockIdx.x * 131072 + w * 32768 + l * 16;
#pragma unroll
    for (int fr = 0; fr < 4; ++fr)
#pragma unroll
      for (int kb = 0; kb < 8; ++kb)
        a[fr][kb] = *reinterpret_cast<const bf16x8*>(zb + fr * 8192 + kb * 1024);
  }

  auto rescore = [&](unsigned e) {  // exact ascending-k chain (bit-exact)
    const int row = arow + (int)(e >> 11);
    const int col = (int)(e & 2047u);
    const float* zp = zf + (size_t)row * 256;
    const float* ep = ef + (size_t)col * 256;
    float p = 0.f;
#pragma unroll 8
    for (int k4 = 0; k4 < 256; k4 += 4) {
      const float4 zv = *reinterpret_cast<const float4*>(zp + k4);
      const float4 ev = *reinterpret_cast<const float4*>(ep + k4);
      p = fmaf(zv.x, ev.x, p);
      p = fmaf(zv.y, ev.y, p);
      p = fmaf(zv.z, ev.z, p);
      p = fmaf(zv.w, ev.w, p);
    }
    const float dsc = (zsq[row] - 2.f * p) + esq[col];
    const u64_t kk = ((u64_t)f32_key(dsc) << 32) | (unsigned)col;
    atomicMin(&keys[row], kk);
  };

  __syncthreads();

  const char* eb = (const char*)e16f + (size_t)l * 16;
  // per-wave staggered walk: blocks AND waves desynchronized
  const int ct0 = (int)((blockIdx.x * 5u + (unsigned)w * 4u) & 15u);

  f32x4 acc[4][8];
#pragma unroll
  for (int fr = 0; fr < 4; ++fr)
#pragma unroll
    for (int fc = 0; fc < 8; ++fc) acc[fr][fc] = (f32x4){0.f, 0.f, 0.f, 0.f};

  bf16x8 bc[8], bn[8];
#pragma unroll
  for (int fc = 0; fc < 8; ++fc)
    bc[fc] = *reinterpret_cast<const bf16x8*>(eb + (size_t)(ct0 * 8) * 8192 + fc * 1024);

#pragma unroll 1
  for (int ctl = 0; ctl < 16; ++ctl) {
    const int ct = (ct0 + ctl) & 15;
#pragma unroll
    for (int kb = 0; kb < 8; ++kb) {
      const int nctl = (kb == 7) ? ctl + 1 : ctl;
      const int nkb = (kb == 7) ? 0 : kb + 1;
      if (nctl < 16) {
        const int nct = (ct0 + nctl) & 15;
        const char* tb = eb + (size_t)(nct * 8 + nkb) * 8192;
#pragma unroll
        for (int fc = 0; fc < 8; ++fc)
          bn[fc] = *reinterpret_cast<const bf16x8*>(tb + fc * 1024);
      }
#pragma unroll
      for (int fr = 0; fr < 4; ++fr)
#pragma unroll
        for (int fc = 0; fc < 8; ++fc)
          acc[fr][fc] = __builtin_amdgcn_mfma_f32_16x16x32_bf16(a[fr][kb], bc[fc], acc[fr][fc], 0, 0, 0);
#pragma unroll
      for (int fc = 0; fc < 8; ++fc) bc[fc] = bn[fc];
    }
    {
      float esqv[8], se[8];
#pragma unroll
      for (int fc = 0; fc < 8; ++fc) {
        esqv[fc] = esq_lds[ct * 128 + fc * 16 + l15];
        se[fc] = sqrtf(esqv[fc]);
      }
#pragma unroll
      for (int fr = 0; fr < 4; ++fr)
#pragma unroll
        for (int rg = 0; rg < 4; ++rg) {
          float s8[8];
          float lm = 3.402823466e38f;
#pragma unroll
          for (int fc = 0; fc < 8; ++fc) {
            s8[fc] = fmaf(-2.f, acc[fr][fc][rg], esqv[fc]);
            lm = fminf(lm, s8[fc]);
          }
#pragma unroll
          for (int m = 1; m < 16; m <<= 1) lm = fminf(lm, __shfl_xor(lm, m, 64));
          const int row = w * 64 + fr * 16 + lk * 4 + rg;
          const float rm = fminf(rowmin_lds[row], lm);
          if (l15 == 0) rowmin_lds[row] = rm;
          const float me1 = me1_lds[row];
#pragma unroll
          for (int fc = 0; fc < 8; ++fc) {
            const float thr = rm + me1 * (se[fc] + semax) + 1e-7f;
            if (s8[fc] <= thr) {
              const unsigned code =
                  ((unsigned)row << 11) | (unsigned)(ct * 128 + fc * 16 + l15);
              const unsigned idx = atomicAdd(&cnt, 1u);
              if (idx < CAND_CAP) cand[idx] = code;
              else rescore(code);
            }
          }
        }
#pragma unroll
      for (int fr = 0; fr < 4; ++fr)
#pragma unroll
        for (int fc = 0; fc < 8; ++fc) acc[fr][fc] = (f32x4){0.f, 0.f, 0.f, 0.f};
    }
  }

  __syncthreads();
  const unsigned nc = cnt < CAND_CAP ? cnt : CAND_CAP;
  for (unsigned i = tid; i < nc; i += 256) rescore(cand[i]);
}

// ---------------------------------------------------------------------------
// dec_mfma (UNCHANGED — validated). bf16 MFMA decoder layer.
// ---------------------------------------------------------------------------
template <int K, int NT, int NTOT, bool GATHER, bool LOSS>
__global__ __launch_bounds__(256, 1) void dec_mfma(
    const unsigned short* __restrict__ A16, const unsigned short* __restrict__ Wf,
    const float* __restrict__ bias, unsigned short* __restrict__ C16,
    const float* __restrict__ X, float* __restrict__ parts,
    const int* __restrict__ gidx) {
  constexpr int CH = K / 8;
  constexpr int KB = K / 32;
  constexpr int CG = NT / 16;
  constexpr int NB = NTOT / NT;
  __shared__ __align__(16) unsigned short Atile[128 * K];
  __shared__ int idx_l[128];
  __shared__ float rbuf[256];

  const int tid = threadIdx.x;
  const int l = tid & 63;
  const int w = tid >> 6;
  const int arow = (int)(blockIdx.x / NB) * 128;
  const int bcol = (int)(blockIdx.x % NB) * NT;

  if (GATHER) {
    if (tid < 128) idx_l[tid] = gidx[arow + tid];
    __syncthreads();
  }
  for (int q = tid; q < 128 * CH; q += 256) {
    const int r = q / CH;
    const int c = q % CH;
    const unsigned short* src = GATHER
        ? A16 + (size_t)idx_l[r] * K + c * 8
        : A16 + (size_t)(arow + r) * K + c * 8;
    const uint4 v = *reinterpret_cast<const uint4*>(src);
    *reinterpret_cast<uint4*>(&Atile[(r * CH + (c ^ (r & 7))) * 8]) = v;
  }

  bf16x8 wf[KB][CG];
#pragma unroll
  for (int kb = 0; kb < KB; ++kb)
#pragma unroll
    for (int cg = 0; cg < CG; ++cg)
      wf[kb][cg] = *reinterpret_cast<const bf16x8*>(
          Wf + ((size_t)(kb * (NTOT / 16) + bcol / 16 + cg) * 64 + l) * 8);

  __syncthreads();

  f32x4 acc[2][CG];
#pragma unroll
  for (int fr = 0; fr < 2; ++fr)
#pragma unroll
    for (int cg = 0; cg < CG; ++cg) acc[fr][cg] = (f32x4){0.f, 0.f, 0.f, 0.f};

#pragma unroll
  for (int kb = 0; kb < KB; ++kb) {
    bf16x8 af[2];
#pragma unroll
    for (int fr = 0; fr < 2; ++fr) {
      const int r = w * 32 + fr * 16 + (l & 15);
      const int c = (kb * 4 + ((l >> 4) & 3)) ^ (r & 7);
      af[fr] = *reinterpret_cast<const bf16x8*>(&Atile[(r * CH + c) * 8]);
    }
#pragma unroll
    for (int fr = 0; fr < 2; ++fr)
#pragma unroll
      for (int cg = 0; cg < CG; ++cg)
        acc[fr][cg] = __builtin_amdgcn_mfma_f32_16x16x32_bf16(af[fr], wf[kb][cg], acc[fr][cg], 0, 0, 0);
  }

  if (!LOSS) {
#pragma unroll
    for (int fr = 0; fr < 2; ++fr)
#pragma unroll
      for (int cg = 0; cg < CG; ++cg) {
        const int col = bcol + cg * 16 + (l & 15);
        const float bv = bias[col];
#pragma unroll
        for (int rg = 0; rg < 4; ++rg) {
          const int row = arow + w * 32 + fr * 16 + ((l >> 4) & 3) * 4 + rg;
          const float v = fmaxf(acc[fr][cg][rg] + bv, 0.f);
          C16[(size_t)row * NTOT + col] = bf16_rne(v);
        }
      }
  } else {
    float local = 0.f;
#pragma unroll
    for (int fr = 0; fr < 2; ++fr)
#pragma unroll
      for (int cg = 0; cg < CG; ++cg) {
        const int col = bcol + cg * 16 + (l & 15);
        const float bv = bias[col];
#pragma unroll
        for (int rg = 0; rg < 4; ++rg) {
          const int row = arow + w * 32 + fr * 16 + ((l >> 4) & 3) * 4 + rg;
          const float v = fmaxf(acc[fr][cg][rg] + bv, 0.f);
          const float d = v - X[(size_t)row * NTOT + col];
          local = fmaf(d, d, local);
        }
      }
    rbuf[tid] = local;
    __syncthreads();
    for (int off = 128; off > 0; off >>= 1) {
      if (tid < off) rbuf[tid] += rbuf[tid + off];
      __syncthreads();
    }
    if (tid == 0) parts[blockIdx.x] = rbuf[0];
  }
}

__global__ __launch_bounds__(256) void max_esq(const float* __restrict__ esq,
                                               float* __restrict__ outv) {
  __shared__ float red[256];
  float m = 0.f;
  for (int i = threadIdx.x; i < KE; i += 256) m = fmaxf(m, esq[i]);
  red[threadIdx.x] = m;
  __syncthreads();
  for (int off = 128; off > 0; off >>= 1) {
    if (threadIdx.x < off) red[threadIdx.x] = fmaxf(red[threadIdx.x], red[threadIdx.x + off]);
    __syncthreads();
  }
  if (threadIdx.x == 0) outv[0] = red[0];
}

// sum of squares per row (256 cols); block = 4 rows x 64 lanes
__global__ __launch_bounds__(256) void rowsq(const float* __restrict__ src,
                                             float* __restrict__ dst, int rows) {
  const int sub = threadIdx.x >> 6;
  const int lane = threadIdx.x & 63;
  const int r = blockIdx.x * 4 + sub;
  if (r >= rows) return;
  const float* p = src + (size_t)r * 256;
  float s = 0.f;
#pragma unroll
  for (int j = 0; j < 4; ++j) {
    float v = p[lane + 64 * j];
    s += v * v;
  }
#pragma unroll
  for (int off = 32; off > 0; off >>= 1) s += __shfl_down(s, off, 64);
  if (lane == 0) dst[r] = s;
}

// per row: idx from key, write z_latent = z + (e - z), quant-loss partial sums
__global__ __launch_bounds__(256) void gather_quant(
    const u64_t* __restrict__ keys, const float* __restrict__ emb,
    const float* __restrict__ z_e, float* __restrict__ zlat,
    int* __restrict__ idx_out, float* __restrict__ qparts) {
  const int sub = threadIdx.x >> 6;
  const int lane = threadIdx.x & 63;
  const int r = blockIdx.x * 4 + sub;
  const int idx = (int)(keys[r] & 0xFFFFFFFFull);
  if (lane == 0) idx_out[r] = idx;
  float s = 0.f;
#pragma unroll
  for (int j = 0; j < 4; ++j) {
    const int d = lane + 64 * j;
    float e = emb[(size_t)idx * 256 + d];
    float z = z_e[(size_t)r * 256 + d];
    float df = e - z;
    s += df * df;
    zlat[(size_t)r * 256 + d] = z + df;  // fl(z_e + fl(z_q - z_e)) — exact ref order
  }
#pragma unroll
  for (int off = 32; off > 0; off >>= 1) s += __shfl_down(s, off, 64);
  __shared__ float red[4];
  if (lane == 0) red[sub] = s;
  __syncthreads();
  if (threadIdx.x == 0) qparts[blockIdx.x] = (red[0] + red[1]) + (red[2] + red[3]);
}

__global__ __launch_bounds__(256) void final_loss(
    const float* __restrict__ qparts, int nq,
    const float* __restrict__ rparts, int nr, float* __restrict__ out) {
  const int tid = threadIdx.x;
  double sq = 0.0, sr = 0.0;
  for (int i = tid; i < nq; i += 256) sq += (double)qparts[i];
  for (int i = tid; i < nr; i += 256) sr += (double)rparts[i];
  __shared__ double bq[256], br[256];
  bq[tid] = sq;
  br[tid] = sr;
  __syncthreads();
  for (int off = 128; off > 0; off >>= 1) {
    if (tid < off) {
      bq[tid] += bq[tid + off];
      br[tid] += br[tid + off];
    }
    __syncthreads();
  }
  if (tid == 0) {
    double qm = bq[0] / ((double)NROWS * 256.0);
    double rm = br[0] / ((double)NROWS * 512.0);
    out[(size_t)NROWS * 256] = (float)(rm + 1.25 * qm);  // recon + (1+BETA)*quant
  }
}

extern "C" void kernel_launch(void* const* d_in, const int* in_sizes, int n_in,
                              void* d_out, int out_size, void* d_ws, size_t ws_size,
                              hipStream_t stream) {
  const float* x   = (const float*)d_in[0];
  const float* ew1 = (const float*)d_in[1];
  const float* eb1 = (const float*)d_in[2];
  const float* ew2 = (const float*)d_in[3];
  const float* eb2 = (const float*)d_in[4];
  const float* ew3 = (const float*)d_in[5];
  const float* eb3 = (const float*)d_in[6];
  const float* dw1 = (const float*)d_in[7];
  const float* db1 = (const float*)d_in[8];
  const float* dw2 = (const float*)d_in[9];
  const float* db2 = (const float*)d_in[10];
  const float* dw3 = (const float*)d_in[11];
  const float* db3 = (const float*)d_in[12];
  const float* emb = (const float*)d_in[13];

  char* ws = (char*)d_ws;
  // region A (0..33.5MB): enc h1 f32 -> {e16f, maxesq, emb16, w*f} after enc2
  float* h1            = (float*)(ws);
  unsigned short* e16f = (unsigned short*)(ws);               // 1 MB
  float* maxesq        = (float*)(ws + 2097152ull);           // 256 B
  unsigned short* emb16 = (unsigned short*)(ws + 4194304ull); // 1 MB
  unsigned short* w1f  = (unsigned short*)(ws + 5242880ull);  // 64 KB
  unsigned short* w2f  = (unsigned short*)(ws + 5308416ull);  // 16 KB
  unsigned short* w3f  = (unsigned short*)(ws + 5324800ull);  // 64 KB
  // region B (33.5..100.6MB): enc h2 f32 -> z16t -> {h2_16, h1_16} after dist
  float* h2            = (float*)(ws + 33554432ull);
  unsigned short* z16t = (unsigned short*)(ws + 33554432ull);   // 67 MB
  unsigned short* h2_16 = (unsigned short*)(ws + 33554432ull);  // 33.5 MB
  unsigned short* h1_16 = (unsigned short*)(ws + 67108864ull);  // 16.8 MB
  // persistent
  float* z_e    = (float*)(ws + 100663296ull);   // N x 256
  float* zsq    = (float*)(ws + 234881024ull);   // N
  float* esq    = (float*)(ws + 235405312ull);   // KE
  u64_t* keys   = (u64_t*)(ws + 235413504ull);   // N
  int* idx      = (int*)(ws + 236462080ull);     // N
  float* qparts = (float*)(ws + 236986368ull);   // N/4
  float* rparts = (float*)(ws + 237117440ull);   // 2048

  float* out = (float*)d_out;
  dim3 blk(256);

  // encoder: 512 -> 64 -> 128 -> 256  (unchanged -> bit-exact z_e)
  gemm64<0><<<dim3(NROWS / 64, 1), blk, 0, stream>>>(x, ew1, eb1, h1, NROWS, 64, 512,
      nullptr);
  gemm128<0><<<dim3(NROWS / 128, 1), blk, 0, stream>>>(h1, ew2, eb2, h2,
      128, 64, nullptr, nullptr, nullptr);
  // h1 (region A) dead: decoder-side conversions (independent of z_e)
  cvt_rows16<<<dim3(KE * 256 / 8 / 256), blk, 0, stream>>>(emb, emb16);
  cvt_w16f<<<dim3(16), blk, 0, stream>>>(dw1, w1f, 128, 4096);
  cvt_w16f<<<dim3(4), blk, 0, stream>>>(dw2, w2f, 64, 1024);
  cvt_w16f<<<dim3(16), blk, 0, stream>>>(dw3, w3f, 512, 4096);
  gemm128<0><<<dim3(NROWS / 128, 2), blk, 0, stream>>>(h2, ew3, eb3, z_e,
      256, 128, nullptr, nullptr, nullptr);

  rowsq<<<dim3(NROWS / 4), blk, 0, stream>>>(z_e, zsq, NROWS);
  rowsq<<<dim3(KE / 4), blk, 0, stream>>>(emb, esq, KE);
  max_esq<<<dim3(1), blk, 0, stream>>>(esq, maxesq);

  cvt_z16t<<<dim3(NROWS * 256 / 8 / 256), blk, 0, stream>>>(z_e, z16t);
  cvt_e16f<<<dim3(KE * 256 / 8 / 256), blk, 0, stream>>>(emb, e16f);

  // bound + deferred exact rescore (bit-identical selection); keys init folded
  dist_g256<<<dim3(NROWS / 256), blk, 0, stream>>>(z16t, e16f, z_e, emb, zsq, esq,
      maxesq, keys);

  gather_quant<<<dim3(NROWS / 4), blk, 0, stream>>>(keys, emb, z_e, out, idx, qparts);

  // decoder: bf16 MFMA (loss-only path, 2% threshold; z16t dead -> h*_16)
  dec_mfma<256, 128, 128, true, false><<<dim3(NROWS / 128), blk, 0, stream>>>(
      emb16, w1f, db1, h2_16, nullptr, nullptr, idx);
  dec_mfma<128, 64, 64, false, false><<<dim3(NROWS / 128), blk, 0, stream>>>(
      h2_16, w2f, db2, h1_16, nullptr, nullptr, nullptr);
  dec_mfma<64, 256, 512, false, true><<<dim3((NROWS / 128) * 2), blk, 0, stream>>>(
      h1_16, w3f, db3, nullptr, x, rparts, nullptr);

  final_loss<<<dim3(1), blk, 0, stream>>>(qparts, NROWS / 4, rparts, 2048, out);
}

// Round 21
// 1152.657 us; speedup vs baseline: 1.0854x; 1.0199x over previous
//
#include <hip/hip_runtime.h>

#define NROWS 131072
#define KE 2048
#define CAND_CAP 8192

typedef unsigned long long u64_t;
typedef unsigned int u32;
typedef __attribute__((ext_vector_type(8))) short bf16x8;
typedef __attribute__((ext_vector_type(4))) float f32x4;

__device__ __forceinline__ unsigned f32_key(float f) {
  unsigned u = __float_as_uint(f);
  return (u & 0x80000000u) ? ~u : (u | 0x80000000u);
}

__device__ __forceinline__ unsigned short bf16_rne(float f) {
  unsigned u = __float_as_uint(f);
  u += 0x7FFFu + ((u >> 16) & 1u);
  return (unsigned short)(u >> 16);
}

// ---------------------------------------------------------------------------
// enc1_128x64: 128 rows x 64 cols f32 GEMM for enc L1 (K=512, N=64).
// r5-verified geometry: 256 threads, per-thread 8 rows x 4 cols; A staged
// transposed (broadcast reads), B row-layout (16B-stride reads, 2-way free).
// Per-output-element accumulation is the SAME ascending-k fmac chain as the
// previous gemm64 -> bit-exact z_e path preserved by construction.
// ---------------------------------------------------------------------------
__global__ __launch_bounds__(256) void enc1_128x64(
    const float* __restrict__ A, const float* __restrict__ B,
    const float* __restrict__ bias, float* __restrict__ C) {
  __shared__ __align__(16) float As[16][132];
  __shared__ __align__(16) float Bs[16][68];

  const int tid = threadIdx.x;
  const int tx = tid & 15;
  const int ty = tid >> 4;
  const int arow = blockIdx.x * 128;

  const int r0 = tid >> 2;        // 0..63
  const int lc = (tid & 3) * 4;   // 0,4,8,12
  const float* Ap0 = A + (size_t)(arow + r0) * 512 + lc;
  const float* Ap1 = A + (size_t)(arow + r0 + 64) * 512 + lc;

  const int bkr = tid >> 4;       // 0..15
  const int bc4 = (tid & 15) * 4; // 0..60
  const float* Bp = B + (size_t)bkr * 64 + bc4;

  float acc[8][4] = {};

  for (int kt = 0; kt < 512; kt += 16) {
    float4 a0 = *reinterpret_cast<const float4*>(Ap0);
    float4 a1 = *reinterpret_cast<const float4*>(Ap1);
    float4 bv = *reinterpret_cast<const float4*>(Bp);
    As[lc + 0][r0] = a0.x; As[lc + 1][r0] = a0.y; As[lc + 2][r0] = a0.z; As[lc + 3][r0] = a0.w;
    As[lc + 0][r0 + 64] = a1.x; As[lc + 1][r0 + 64] = a1.y;
    As[lc + 2][r0 + 64] = a1.z; As[lc + 3][r0 + 64] = a1.w;
    *reinterpret_cast<float4*>(&Bs[bkr][bc4]) = bv;
    Ap0 += 16; Ap1 += 16; Bp += (size_t)16 * 64;
    __syncthreads();
#pragma unroll
    for (int k = 0; k < 16; ++k) {
      float4 av0 = *reinterpret_cast<const float4*>(&As[k][ty * 4]);
      float4 av1 = *reinterpret_cast<const float4*>(&As[k][64 + ty * 4]);
      float4 b = *reinterpret_cast<const float4*>(&Bs[k][tx * 4]);
      const float a[8] = {av0.x, av0.y, av0.z, av0.w, av1.x, av1.y, av1.z, av1.w};
#pragma unroll
      for (int i = 0; i < 8; ++i) {
        acc[i][0] += a[i] * b.x;
        acc[i][1] += a[i] * b.y;
        acc[i][2] += a[i] * b.z;
        acc[i][3] += a[i] * b.w;
      }
    }
    __syncthreads();
  }

#pragma unroll
  for (int i = 0; i < 8; ++i) {
    const int row = arow + (i >> 2) * 64 + ty * 4 + (i & 3);
    const int c0 = tx * 4;
    float4 v;
    v.x = fmaxf(acc[i][0] + bias[c0 + 0], 0.f);
    v.y = fmaxf(acc[i][1] + bias[c0 + 1], 0.f);
    v.z = fmaxf(acc[i][2] + bias[c0 + 2], 0.f);
    v.w = fmaxf(acc[i][3] + bias[c0 + 3], 0.f);
    *reinterpret_cast<float4*>(&C[(size_t)row * 64 + c0]) = v;
  }
}

// ---------------------------------------------------------------------------
// 128x128 tile f32 GEMM (UNCHANGED — enc2/enc3). Mode 0 only instantiated.
// ---------------------------------------------------------------------------
template <int MODE>
__global__ __launch_bounds__(256) void gemm128(
    const float* __restrict__ A, const float* __restrict__ B,
    const float* __restrict__ bias, float* __restrict__ C,
    int N, int K,
    const int* __restrict__ gidx,
    const float* __restrict__ X,
    float* __restrict__ parts) {
  __shared__ __align__(16) char smem[17408];
  float (*As)[132] = (float(*)[132])smem;
  float (*Bs)[132] = (float(*)[132])(smem + 8448);

  const int tid = threadIdx.x;
  const int tx = tid & 15;
  const int ty = tid >> 4;
  const int arow = blockIdx.x * 128;
  const int bcol = blockIdx.y * 128;

  const int r0 = tid >> 2;
  const int r1 = r0 + 64;
  const int lc = (tid & 3) * 4;
  int ga0 = arow + r0, ga1 = arow + r1;
  if (MODE == 1) { ga0 = gidx[ga0]; ga1 = gidx[ga1]; }
  const float* Ap0 = A + (size_t)ga0 * K + lc;
  const float* Ap1 = A + (size_t)ga1 * K + lc;

  const int bk0 = tid >> 5;
  const int bc0 = (tid & 31) * 4;
  const float* Bp0 = B + (size_t)bk0 * N + bcol + bc0;
  const float* Bp1 = B + (size_t)(bk0 + 8) * N + bcol + bc0;

  float acc[8][8] = {};

  for (int kt = 0; kt < K; kt += 16) {
    float4 a0 = *reinterpret_cast<const float4*>(Ap0);
    float4 a1 = *reinterpret_cast<const float4*>(Ap1);
    As[lc + 0][r0] = a0.x; As[lc + 1][r0] = a0.y; As[lc + 2][r0] = a0.z; As[lc + 3][r0] = a0.w;
    As[lc + 0][r1] = a1.x; As[lc + 1][r1] = a1.y; As[lc + 2][r1] = a1.z; As[lc + 3][r1] = a1.w;
    float4 b0 = *reinterpret_cast<const float4*>(Bp0);
    float4 b1 = *reinterpret_cast<const float4*>(Bp1);
    *reinterpret_cast<float4*>(&Bs[bk0][bc0]) = b0;
    *reinterpret_cast<float4*>(&Bs[bk0 + 8][bc0]) = b1;
    Bp0 += (size_t)16 * N; Bp1 += (size_t)16 * N;
    Ap0 += 16; Ap1 += 16;
    __syncthreads();
#pragma unroll
    for (int k = 0; k < 16; ++k) {
      float4 av0 = *reinterpret_cast<const float4*>(&As[k][ty * 4]);
      float4 av1 = *reinterpret_cast<const float4*>(&As[k][64 + ty * 4]);
      float4 bv0 = *reinterpret_cast<const float4*>(&Bs[k][tx * 4]);
      float4 bv1 = *reinterpret_cast<const float4*>(&Bs[k][64 + tx * 4]);
      const float a[8] = {av0.x, av0.y, av0.z, av0.w, av1.x, av1.y, av1.z, av1.w};
      const float b[8] = {bv0.x, bv0.y, bv0.z, bv0.w, bv1.x, bv1.y, bv1.z, bv1.w};
#pragma unroll
      for (int i = 0; i < 8; ++i)
#pragma unroll
        for (int j = 0; j < 8; ++j) acc[i][j] += a[i] * b[j];
    }
    __syncthreads();
  }

#pragma unroll
  for (int i = 0; i < 8; ++i) {
    const int row = arow + (i >> 2) * 64 + ty * 4 + (i & 3);
    const int c0 = bcol + tx * 4;
    const int c1 = bcol + 64 + tx * 4;
    float4 v0, v1;
    v0.x = fmaxf(acc[i][0] + bias[c0 + 0], 0.f);
    v0.y = fmaxf(acc[i][1] + bias[c0 + 1], 0.f);
    v0.z = fmaxf(acc[i][2] + bias[c0 + 2], 0.f);
    v0.w = fmaxf(acc[i][3] + bias[c0 + 3], 0.f);
    v1.x = fmaxf(acc[i][4] + bias[c1 + 0], 0.f);
    v1.y = fmaxf(acc[i][5] + bias[c1 + 1], 0.f);
    v1.z = fmaxf(acc[i][6] + bias[c1 + 2], 0.f);
    v1.w = fmaxf(acc[i][7] + bias[c1 + 3], 0.f);
    *reinterpret_cast<float4*>(&C[(size_t)row * N + c0]) = v0;
    *reinterpret_cast<float4*>(&C[(size_t)row * N + c1]) = v1;
  }
}

// z16t for 256-row blocks (separate pass — no aliasing with h2)
__global__ __launch_bounds__(256) void cvt_z16t(const float* __restrict__ z_e,
                                                unsigned short* __restrict__ z16t) {
  const int c = blockIdx.x * 256 + threadIdx.x;
  const int lane = c & 63;
  const int kb = (c >> 6) & 7;
  const int fr = (c >> 9) & 3;
  const int w = (c >> 11) & 3;
  const int rowblk = c >> 13;
  const int row = rowblk * 256 + w * 64 + fr * 16 + (lane & 15);
  const int k0 = kb * 32 + (lane >> 4) * 8;
  const float* p = z_e + (size_t)row * 256 + k0;
  const float4 v0 = *reinterpret_cast<const float4*>(p);
  const float4 v1 = *reinterpret_cast<const float4*>(p + 4);
  const float f[8] = {v0.x, v0.y, v0.z, v0.w, v1.x, v1.y, v1.z, v1.w};
  unsigned short s[8];
#pragma unroll
  for (int j = 0; j < 8; ++j) s[j] = bf16_rne(f[j]);
  uint4 o;
  o.x = (u32)s[0] | ((u32)s[1] << 16);
  o.y = (u32)s[2] | ((u32)s[3] << 16);
  o.z = (u32)s[4] | ((u32)s[5] << 16);
  o.w = (u32)s[6] | ((u32)s[7] << 16);
  *reinterpret_cast<uint4*>(z16t + (size_t)c * 8) = o;
}

// merged emb conversions: per thread, one row-major chunk (emb16) AND one
// fragment-major chunk (e16f). Independent outputs, same const input.
__global__ __launch_bounds__(256) void cvt_emb_all(const float* __restrict__ emb,
                                                   unsigned short* __restrict__ emb16,
                                                   unsigned short* __restrict__ e16f) {
  const int c = blockIdx.x * 256 + threadIdx.x;  // 65536 chunks
  // part 1: row-major bf16 (emb16)
  {
    const float4 v0 = *reinterpret_cast<const float4*>(emb + (size_t)c * 8);
    const float4 v1 = *reinterpret_cast<const float4*>(emb + (size_t)c * 8 + 4);
    const float f[8] = {v0.x, v0.y, v0.z, v0.w, v1.x, v1.y, v1.z, v1.w};
    unsigned short s[8];
#pragma unroll
    for (int j = 0; j < 8; ++j) s[j] = bf16_rne(f[j]);
    uint4 o;
    o.x = (u32)s[0] | ((u32)s[1] << 16);
    o.y = (u32)s[2] | ((u32)s[3] << 16);
    o.z = (u32)s[4] | ((u32)s[5] << 16);
    o.w = (u32)s[6] | ((u32)s[7] << 16);
    *reinterpret_cast<uint4*>(emb16 + (size_t)c * 8) = o;
  }
  // part 2: fragment-major tiles (e16f)
  {
    const int l = c & 63;
    const int fc = (c >> 6) & 7;
    const int t = c >> 9;
    const int kb = t & 7;
    const int ct = t >> 3;
    const int col = ct * 128 + fc * 16 + (l & 15);
    const int k0 = kb * 32 + (l >> 4) * 8;
    const float* p = emb + (size_t)col * 256 + k0;
    const float4 v0 = *reinterpret_cast<const float4*>(p);
    const float4 v1 = *reinterpret_cast<const float4*>(p + 4);
    const float f[8] = {v0.x, v0.y, v0.z, v0.w, v1.x, v1.y, v1.z, v1.w};
    unsigned short s8[8];
#pragma unroll
    for (int j = 0; j < 8; ++j) s8[j] = bf16_rne(f[j]);
    uint4 o;
    o.x = (u32)s8[0] | ((u32)s8[1] << 16);
    o.y = (u32)s8[2] | ((u32)s8[3] << 16);
    o.z = (u32)s8[4] | ((u32)s8[5] << 16);
    o.w = (u32)s8[6] | ((u32)s8[7] << 16);
    *reinterpret_cast<uint4*>(e16f + (size_t)c * 8) = o;
  }
}

// weights -> fragment-major bf16 (UNCHANGED)
__global__ __launch_bounds__(256) void cvt_w16f(const float* __restrict__ W,
                                                unsigned short* __restrict__ Wf,
                                                int N, int total) {
  const int c = blockIdx.x * 256 + threadIdx.x;
  if (c >= total) return;
  const int l = c & 63;
  const int f = c >> 6;
  const int ng = N >> 4;
  const int cg = f % ng;
  const int kb = f / ng;
  const int col = cg * 16 + (l & 15);
  const int k0 = kb * 32 + ((l >> 4) & 3) * 8;
  unsigned short s[8];
#pragma unroll
  for (int j = 0; j < 8; ++j) s[j] = bf16_rne(W[(size_t)(k0 + j) * N + col]);
  uint4 o;
  o.x = (u32)s[0] | ((u32)s[1] << 16);
  o.y = (u32)s[2] | ((u32)s[3] << 16);
  o.z = (u32)s[4] | ((u32)s[5] << 16);
  o.w = (u32)s[6] | ((u32)s[7] << 16);
  *reinterpret_cast<uint4*>(Wf + (size_t)c * 8) = o;
}

// ---------------------------------------------------------------------------
// dist_g256 (UNCHANGED from r20 — best-measured; wave-staggered, keys-folded).
// ---------------------------------------------------------------------------
__global__ __launch_bounds__(256, 1) void dist_g256(
    const unsigned short* __restrict__ z16t, const unsigned short* __restrict__ e16f,
    const float* __restrict__ zf, const float* __restrict__ ef,
    const float* __restrict__ zsq, const float* __restrict__ esq,
    const float* __restrict__ maxesq, u64_t* __restrict__ keys) {
  __shared__ float esq_lds[2048];
  __shared__ float me1_lds[256];
  __shared__ float rowmin_lds[256];
  __shared__ unsigned cand[CAND_CAP];
  __shared__ unsigned cnt;

  const int tid = threadIdx.x;
  const int l = tid & 63;
  const int w = tid >> 6;
  const int l15 = tid & 15;
  const int lk = (tid >> 4) & 3;
  const int arow = blockIdx.x * 256;

  if (tid == 0) cnt = 0;
  {
    for (int i = tid; i < 2048; i += 256) esq_lds[i] = esq[i];
    me1_lds[tid] = 0.009765625f * sqrtf(zsq[arow + tid]);  // 1.25 * 2^-7
    rowmin_lds[tid] = 3.402823466e38f;
    keys[arow + tid] = ~0ull;  // block-exclusive rows; init before barrier
  }
  const float semax = sqrtf(maxesq[0]);

  bf16x8 a[4][8];
  {
    const char* zb = (const char*)z16t + (size_t)blockIdx.x * 131072 + w * 32768 + l * 16;
#pragma unroll
    for (int fr = 0; fr < 4; ++fr)
#pragma unroll
      for (int kb = 0; kb < 8; ++kb)
        a[fr][kb] = *reinterpret_cast<const bf16x8*>(zb + fr * 8192 + kb * 1024);
  }

  auto rescore = [&](unsigned e) {  // exact ascending-k chain (bit-exact)
    const int row = arow + (int)(e >> 11);
    const int col = (int)(e & 2047u);
    const float* zp = zf + (size_t)row * 256;
    const float* ep = ef + (size_t)col * 256;
    float p = 0.f;
#pragma unroll 8
    for (int k4 = 0; k4 < 256; k4 += 4) {
      const float4 zv = *reinterpret_cast<const float4*>(zp + k4);
      const float4 ev = *reinterpret_cast<const float4*>(ep + k4);
      p = fmaf(zv.x, ev.x, p);
      p = fmaf(zv.y, ev.y, p);
      p = fmaf(zv.z, ev.z, p);
      p = fmaf(zv.w, ev.w, p);
    }
    const float dsc = (zsq[row] - 2.f * p) + esq[col];
    const u64_t kk = ((u64_t)f32_key(dsc) << 32) | (unsigned)col;
    atomicMin(&keys[row], kk);
  };

  __syncthreads();

  const char* eb = (const char*)e16f + (size_t)l * 16;
  // per-wave staggered walk: blocks AND waves desynchronized
  const int ct0 = (int)((blockIdx.x * 5u + (unsigned)w * 4u) & 15u);

  f32x4 acc[4][8];
#pragma unroll
  for (int fr = 0; fr < 4; ++fr)
#pragma unroll
    for (int fc = 0; fc < 8; ++fc) acc[fr][fc] = (f32x4){0.f, 0.f, 0.f, 0.f};

  bf16x8 bc[8], bn[8];
#pragma unroll
  for (int fc = 0; fc < 8; ++fc)
    bc[fc] = *reinterpret_cast<const bf16x8*>(eb + (size_t)(ct0 * 8) * 8192 + fc * 1024);

#pragma unroll 1
  for (int ctl = 0; ctl < 16; ++ctl) {
    const int ct = (ct0 + ctl) & 15;
#pragma unroll
    for (int kb = 0; kb < 8; ++kb) {
      const int nctl = (kb == 7) ? ctl + 1 : ctl;
      const int nkb = (kb == 7) ? 0 : kb + 1;
      if (nctl < 16) {
        const int nct = (ct0 + nctl) & 15;
        const char* tb = eb + (size_t)(nct * 8 + nkb) * 8192;
#pragma unroll
        for (int fc = 0; fc < 8; ++fc)
          bn[fc] = *reinterpret_cast<const bf16x8*>(tb + fc * 1024);
      }
#pragma unroll
      for (int fr = 0; fr < 4; ++fr)
#pragma unroll
        for (int fc = 0; fc < 8; ++fc)
          acc[fr][fc] = __builtin_amdgcn_mfma_f32_16x16x32_bf16(a[fr][kb], bc[fc], acc[fr][fc], 0, 0, 0);
#pragma unroll
      for (int fc = 0; fc < 8; ++fc) bc[fc] = bn[fc];
    }
    {
      float esqv[8], se[8];
#pragma unroll
      for (int fc = 0; fc < 8; ++fc) {
        esqv[fc] = esq_lds[ct * 128 + fc * 16 + l15];
        se[fc] = sqrtf(esqv[fc]);
      }
#pragma unroll
      for (int fr = 0; fr < 4; ++fr)
#pragma unroll
        for (int rg = 0; rg < 4; ++rg) {
          float s8[8];
          float lm = 3.402823466e38f;
#pragma unroll
          for (int fc = 0; fc < 8; ++fc) {
            s8[fc] = fmaf(-2.f, acc[fr][fc][rg], esqv[fc]);
            lm = fminf(lm, s8[fc]);
          }
#pragma unroll
          for (int m = 1; m < 16; m <<= 1) lm = fminf(lm, __shfl_xor(lm, m, 64));
          const int row = w * 64 + fr * 16 + lk * 4 + rg;
          const float rm = fminf(rowmin_lds[row], lm);
          if (l15 == 0) rowmin_lds[row] = rm;
          const float me1 = me1_lds[row];
#pragma unroll
          for (int fc = 0; fc < 8; ++fc) {
            const float thr = rm + me1 * (se[fc] + semax) + 1e-7f;
            if (s8[fc] <= thr) {
              const unsigned code =
                  ((unsigned)row << 11) | (unsigned)(ct * 128 + fc * 16 + l15);
              const unsigned idx = atomicAdd(&cnt, 1u);
              if (idx < CAND_CAP) cand[idx] = code;
              else rescore(code);
            }
          }
        }
#pragma unroll
      for (int fr = 0; fr < 4; ++fr)
#pragma unroll
        for (int fc = 0; fc < 8; ++fc) acc[fr][fc] = (f32x4){0.f, 0.f, 0.f, 0.f};
    }
  }

  __syncthreads();
  const unsigned nc = cnt < CAND_CAP ? cnt : CAND_CAP;
  for (unsigned i = tid; i < nc; i += 256) rescore(cand[i]);
}

// ---------------------------------------------------------------------------
// dec_mfma (UNCHANGED — validated). bf16 MFMA decoder layer.
// ---------------------------------------------------------------------------
template <int K, int NT, int NTOT, bool GATHER, bool LOSS>
__global__ __launch_bounds__(256, 1) void dec_mfma(
    const unsigned short* __restrict__ A16, const unsigned short* __restrict__ Wf,
    const float* __restrict__ bias, unsigned short* __restrict__ C16,
    const float* __restrict__ X, float* __restrict__ parts,
    const int* __restrict__ gidx) {
  constexpr int CH = K / 8;
  constexpr int KB = K / 32;
  constexpr int CG = NT / 16;
  constexpr int NB = NTOT / NT;
  __shared__ __align__(16) unsigned short Atile[128 * K];
  __shared__ int idx_l[128];
  __shared__ float rbuf[256];

  const int tid = threadIdx.x;
  const int l = tid & 63;
  const int w = tid >> 6;
  const int arow = (int)(blockIdx.x / NB) * 128;
  const int bcol = (int)(blockIdx.x % NB) * NT;

  if (GATHER) {
    if (tid < 128) idx_l[tid] = gidx[arow + tid];
    __syncthreads();
  }
  for (int q = tid; q < 128 * CH; q += 256) {
    const int r = q / CH;
    const int c = q % CH;
    const unsigned short* src = GATHER
        ? A16 + (size_t)idx_l[r] * K + c * 8
        : A16 + (size_t)(arow + r) * K + c * 8;
    const uint4 v = *reinterpret_cast<const uint4*>(src);
    *reinterpret_cast<uint4*>(&Atile[(r * CH + (c ^ (r & 7))) * 8]) = v;
  }

  bf16x8 wf[KB][CG];
#pragma unroll
  for (int kb = 0; kb < KB; ++kb)
#pragma unroll
    for (int cg = 0; cg < CG; ++cg)
      wf[kb][cg] = *reinterpret_cast<const bf16x8*>(
          Wf + ((size_t)(kb * (NTOT / 16) + bcol / 16 + cg) * 64 + l) * 8);

  __syncthreads();

  f32x4 acc[2][CG];
#pragma unroll
  for (int fr = 0; fr < 2; ++fr)
#pragma unroll
    for (int cg = 0; cg < CG; ++cg) acc[fr][cg] = (f32x4){0.f, 0.f, 0.f, 0.f};

#pragma unroll
  for (int kb = 0; kb < KB; ++kb) {
    bf16x8 af[2];
#pragma unroll
    for (int fr = 0; fr < 2; ++fr) {
      const int r = w * 32 + fr * 16 + (l & 15);
      const int c = (kb * 4 + ((l >> 4) & 3)) ^ (r & 7);
      af[fr] = *reinterpret_cast<const bf16x8*>(&Atile[(r * CH + c) * 8]);
    }
#pragma unroll
    for (int fr = 0; fr < 2; ++fr)
#pragma unroll
      for (int cg = 0; cg < CG; ++cg)
        acc[fr][cg] = __builtin_amdgcn_mfma_f32_16x16x32_bf16(af[fr], wf[kb][cg], acc[fr][cg], 0, 0, 0);
  }

  if (!LOSS) {
#pragma unroll
    for (int fr = 0; fr < 2; ++fr)
#pragma unroll
      for (int cg = 0; cg < CG; ++cg) {
        const int col = bcol + cg * 16 + (l & 15);
        const float bv = bias[col];
#pragma unroll
        for (int rg = 0; rg < 4; ++rg) {
          const int row = arow + w * 32 + fr * 16 + ((l >> 4) & 3) * 4 + rg;
          const float v = fmaxf(acc[fr][cg][rg] + bv, 0.f);
          C16[(size_t)row * NTOT + col] = bf16_rne(v);
        }
      }
  } else {
    float local = 0.f;
#pragma unroll
    for (int fr = 0; fr < 2; ++fr)
#pragma unroll
      for (int cg = 0; cg < CG; ++cg) {
        const int col = bcol + cg * 16 + (l & 15);
        const float bv = bias[col];
#pragma unroll
        for (int rg = 0; rg < 4; ++rg) {
          const int row = arow + w * 32 + fr * 16 + ((l >> 4) & 3) * 4 + rg;
          const float v = fmaxf(acc[fr][cg][rg] + bv, 0.f);
          const float d = v - X[(size_t)row * NTOT + col];
          local = fmaf(d, d, local);
        }
      }
    rbuf[tid] = local;
    __syncthreads();
    for (int off = 128; off > 0; off >>= 1) {
      if (tid < off) rbuf[tid] += rbuf[tid + off];
      __syncthreads();
    }
    if (tid == 0) parts[blockIdx.x] = rbuf[0];
  }
}

__global__ __launch_bounds__(256) void max_esq(const float* __restrict__ esq,
                                               float* __restrict__ outv) {
  __shared__ float red[256];
  float m = 0.f;
  for (int i = threadIdx.x; i < KE; i += 256) m = fmaxf(m, esq[i]);
  red[threadIdx.x] = m;
  __syncthreads();
  for (int off = 128; off > 0; off >>= 1) {
    if (threadIdx.x < off) red[threadIdx.x] = fmaxf(red[threadIdx.x], red[threadIdx.x + off]);
    __syncthreads();
  }
  if (threadIdx.x == 0) outv[0] = red[0];
}

// sum of squares per row (256 cols); block = 4 rows x 64 lanes
__global__ __launch_bounds__(256) void rowsq(const float* __restrict__ src,
                                             float* __restrict__ dst, int rows) {
  const int sub = threadIdx.x >> 6;
  const int lane = threadIdx.x & 63;
  const int r = blockIdx.x * 4 + sub;
  if (r >= rows) return;
  const float* p = src + (size_t)r * 256;
  float s = 0.f;
#pragma unroll
  for (int j = 0; j < 4; ++j) {
    float v = p[lane + 64 * j];
    s += v * v;
  }
#pragma unroll
  for (int off = 32; off > 0; off >>= 1) s += __shfl_down(s, off, 64);
  if (lane == 0) dst[r] = s;
}

// per row: idx from key, write z_latent = z + (e - z), quant-loss partial sums
__global__ __launch_bounds__(256) void gather_quant(
    const u64_t* __restrict__ keys, const float* __restrict__ emb,
    const float* __restrict__ z_e, float* __restrict__ zlat,
    int* __restrict__ idx_out, float* __restrict__ qparts) {
  const int sub = threadIdx.x >> 6;
  const int lane = threadIdx.x & 63;
  const int r = blockIdx.x * 4 + sub;
  const int idx = (int)(keys[r] & 0xFFFFFFFFull);
  if (lane == 0) idx_out[r] = idx;
  float s = 0.f;
#pragma unroll
  for (int j = 0; j < 4; ++j) {
    const int d = lane + 64 * j;
    float e = emb[(size_t)idx * 256 + d];
    float z = z_e[(size_t)r * 256 + d];
    float df = e - z;
    s += df * df;
    zlat[(size_t)r * 256 + d] = z + df;  // fl(z_e + fl(z_q - z_e)) — exact ref order
  }
#pragma unroll
  for (int off = 32; off > 0; off >>= 1) s += __shfl_down(s, off, 64);
  __shared__ float red[4];
  if (lane == 0) red[sub] = s;
  __syncthreads();
  if (threadIdx.x == 0) qparts[blockIdx.x] = (red[0] + red[1]) + (red[2] + red[3]);
}

__global__ __launch_bounds__(256) void final_loss(
    const float* __restrict__ qparts, int nq,
    const float* __restrict__ rparts, int nr, float* __restrict__ out) {
  const int tid = threadIdx.x;
  double sq = 0.0, sr = 0.0;
  for (int i = tid; i < nq; i += 256) sq += (double)qparts[i];
  for (int i = tid; i < nr; i += 256) sr += (double)rparts[i];
  __shared__ double bq[256], br[256];
  bq[tid] = sq;
  br[tid] = sr;
  __syncthreads();
  for (int off = 128; off > 0; off >>= 1) {
    if (tid < off) {
      bq[tid] += bq[tid + off];
      br[tid] += br[tid + off];
    }
    __syncthreads();
  }
  if (tid == 0) {
    double qm = bq[0] / ((double)NROWS * 256.0);
    double rm = br[0] / ((double)NROWS * 512.0);
    out[(size_t)NROWS * 256] = (float)(rm + 1.25 * qm);  // recon + (1+BETA)*quant
  }
}

extern "C" void kernel_launch(void* const* d_in, const int* in_sizes, int n_in,
                              void* d_out, int out_size, void* d_ws, size_t ws_size,
                              hipStream_t stream) {
  const float* x   = (const float*)d_in[0];
  const float* ew1 = (const float*)d_in[1];
  const float* eb1 = (const float*)d_in[2];
  const float* ew2 = (const float*)d_in[3];
  const float* eb2 = (const float*)d_in[4];
  const float* ew3 = (const float*)d_in[5];
  const float* eb3 = (const float*)d_in[6];
  const float* dw1 = (const float*)d_in[7];
  const float* db1 = (const float*)d_in[8];
  const float* dw2 = (const float*)d_in[9];
  const float* db2 = (const float*)d_in[10];
  const float* dw3 = (const float*)d_in[11];
  const float* db3 = (const float*)d_in[12];
  const float* emb = (const float*)d_in[13];

  char* ws = (char*)d_ws;
  // region A (0..33.5MB): enc h1 f32 -> {e16f, maxesq, emb16, w*f} after enc2
  float* h1            = (float*)(ws);
  unsigned short* e16f = (unsigned short*)(ws);               // 1 MB
  float* maxesq        = (float*)(ws + 2097152ull);           // 256 B
  unsigned short* emb16 = (unsigned short*)(ws + 4194304ull); // 1 MB
  unsigned short* w1f  = (unsigned short*)(ws + 5242880ull);  // 64 KB
  unsigned short* w2f  = (unsigned short*)(ws + 5308416ull);  // 16 KB
  unsigned short* w3f  = (unsigned short*)(ws + 5324800ull);  // 64 KB
  // region B (33.5..100.6MB): enc h2 f32 -> z16t -> {h2_16, h1_16} after dist
  float* h2            = (float*)(ws + 33554432ull);
  unsigned short* z16t = (unsigned short*)(ws + 33554432ull);   // 67 MB
  unsigned short* h2_16 = (unsigned short*)(ws + 33554432ull);  // 33.5 MB
  unsigned short* h1_16 = (unsigned short*)(ws + 67108864ull);  // 16.8 MB
  // persistent
  float* z_e    = (float*)(ws + 100663296ull);   // N x 256
  float* zsq    = (float*)(ws + 234881024ull);   // N
  float* esq    = (float*)(ws + 235405312ull);   // KE
  u64_t* keys   = (u64_t*)(ws + 235413504ull);   // N
  int* idx      = (int*)(ws + 236462080ull);     // N
  float* qparts = (float*)(ws + 236986368ull);   // N/4
  float* rparts = (float*)(ws + 237117440ull);   // 2048

  float* out = (float*)d_out;
  dim3 blk(256);

  // encoder: 512 -> 64 -> 128 -> 256 (enc1 retiled 128x64; per-element
  // ascending-k chain identical -> bit-exact z_e)
  enc1_128x64<<<dim3(NROWS / 128), blk, 0, stream>>>(x, ew1, eb1, h1);
  gemm128<0><<<dim3(NROWS / 128, 1), blk, 0, stream>>>(h1, ew2, eb2, h2,
      128, 64, nullptr, nullptr, nullptr);
  // h1 (region A) dead: decoder-side conversions (independent of z_e)
  cvt_emb_all<<<dim3(KE * 256 / 8 / 256), blk, 0, stream>>>(emb, emb16, e16f);
  cvt_w16f<<<dim3(16), blk, 0, stream>>>(dw1, w1f, 128, 4096);
  cvt_w16f<<<dim3(4), blk, 0, stream>>>(dw2, w2f, 64, 1024);
  cvt_w16f<<<dim3(16), blk, 0, stream>>>(dw3, w3f, 512, 4096);
  gemm128<0><<<dim3(NROWS / 128, 2), blk, 0, stream>>>(h2, ew3, eb3, z_e,
      256, 128, nullptr, nullptr, nullptr);

  rowsq<<<dim3(NROWS / 4), blk, 0, stream>>>(z_e, zsq, NROWS);
  rowsq<<<dim3(KE / 4), blk, 0, stream>>>(emb, esq, KE);
  max_esq<<<dim3(1), blk, 0, stream>>>(esq, maxesq);

  cvt_z16t<<<dim3(NROWS * 256 / 8 / 256), blk, 0, stream>>>(z_e, z16t);

  // bound + deferred exact rescore (bit-identical selection); keys init folded
  dist_g256<<<dim3(NROWS / 256), blk, 0, stream>>>(z16t, e16f, z_e, emb, zsq, esq,
      maxesq, keys);

  gather_quant<<<dim3(NROWS / 4), blk, 0, stream>>>(keys, emb, z_e, out, idx, qparts);

  // decoder: bf16 MFMA (loss-only path, 2% threshold; z16t dead -> h*_16)
  dec_mfma<256, 128, 128, true, false><<<dim3(NROWS / 128), blk, 0, stream>>>(
      emb16, w1f, db1, h2_16, nullptr, nullptr, idx);
  dec_mfma<128, 64, 64, false, false><<<dim3(NROWS / 128), blk, 0, stream>>>(
      h2_16, w2f, db2, h1_16, nullptr, nullptr, nullptr);
  dec_mfma<64, 256, 512, false, true><<<dim3((NROWS / 128) * 2), blk, 0, stream>>>(
      h1_16, w3f, db3, nullptr, x, rparts, nullptr);

  final_loss<<<dim3(1), blk, 0, stream>>>(qparts, NROWS / 4, rparts, 2048, out);
}

// Round 22
// 1137.873 us; speedup vs baseline: 1.0995x; 1.0130x over previous
//
#include <hip/hip_runtime.h>

#define NROWS 131072
#define KE 2048
#define CAND_CAP 8192

typedef unsigned long long u64_t;
typedef unsigned int u32;
typedef __attribute__((ext_vector_type(8))) short bf16x8;
typedef __attribute__((ext_vector_type(4))) float f32x4;

__device__ __forceinline__ unsigned f32_key(float f) {
  unsigned u = __float_as_uint(f);
  return (u & 0x80000000u) ? ~u : (u | 0x80000000u);
}

__device__ __forceinline__ unsigned short bf16_rne(float f) {
  unsigned u = __float_as_uint(f);
  u += 0x7FFFu + ((u >> 16) & 1u);
  return (unsigned short)(u >> 16);
}

// ---------------------------------------------------------------------------
// enc1_128x64 (UNCHANGED from r21 — validated).
// ---------------------------------------------------------------------------
__global__ __launch_bounds__(256) void enc1_128x64(
    const float* __restrict__ A, const float* __restrict__ B,
    const float* __restrict__ bias, float* __restrict__ C) {
  __shared__ __align__(16) float As[16][132];
  __shared__ __align__(16) float Bs[16][68];

  const int tid = threadIdx.x;
  const int tx = tid & 15;
  const int ty = tid >> 4;
  const int arow = blockIdx.x * 128;

  const int r0 = tid >> 2;
  const int lc = (tid & 3) * 4;
  const float* Ap0 = A + (size_t)(arow + r0) * 512 + lc;
  const float* Ap1 = A + (size_t)(arow + r0 + 64) * 512 + lc;

  const int bkr = tid >> 4;
  const int bc4 = (tid & 15) * 4;
  const float* Bp = B + (size_t)bkr * 64 + bc4;

  float acc[8][4] = {};

  for (int kt = 0; kt < 512; kt += 16) {
    float4 a0 = *reinterpret_cast<const float4*>(Ap0);
    float4 a1 = *reinterpret_cast<const float4*>(Ap1);
    float4 bv = *reinterpret_cast<const float4*>(Bp);
    As[lc + 0][r0] = a0.x; As[lc + 1][r0] = a0.y; As[lc + 2][r0] = a0.z; As[lc + 3][r0] = a0.w;
    As[lc + 0][r0 + 64] = a1.x; As[lc + 1][r0 + 64] = a1.y;
    As[lc + 2][r0 + 64] = a1.z; As[lc + 3][r0 + 64] = a1.w;
    *reinterpret_cast<float4*>(&Bs[bkr][bc4]) = bv;
    Ap0 += 16; Ap1 += 16; Bp += (size_t)16 * 64;
    __syncthreads();
#pragma unroll
    for (int k = 0; k < 16; ++k) {
      float4 av0 = *reinterpret_cast<const float4*>(&As[k][ty * 4]);
      float4 av1 = *reinterpret_cast<const float4*>(&As[k][64 + ty * 4]);
      float4 b = *reinterpret_cast<const float4*>(&Bs[k][tx * 4]);
      const float a[8] = {av0.x, av0.y, av0.z, av0.w, av1.x, av1.y, av1.z, av1.w};
#pragma unroll
      for (int i = 0; i < 8; ++i) {
        acc[i][0] += a[i] * b.x;
        acc[i][1] += a[i] * b.y;
        acc[i][2] += a[i] * b.z;
        acc[i][3] += a[i] * b.w;
      }
    }
    __syncthreads();
  }

#pragma unroll
  for (int i = 0; i < 8; ++i) {
    const int row = arow + (i >> 2) * 64 + ty * 4 + (i & 3);
    const int c0 = tx * 4;
    float4 v;
    v.x = fmaxf(acc[i][0] + bias[c0 + 0], 0.f);
    v.y = fmaxf(acc[i][1] + bias[c0 + 1], 0.f);
    v.z = fmaxf(acc[i][2] + bias[c0 + 2], 0.f);
    v.w = fmaxf(acc[i][3] + bias[c0 + 3], 0.f);
    *reinterpret_cast<float4*>(&C[(size_t)row * 64 + c0]) = v;
  }
}

// ---------------------------------------------------------------------------
// 128x128 tile f32 GEMM (UNCHANGED — enc2/enc3). Mode 0 only instantiated.
// ---------------------------------------------------------------------------
template <int MODE>
__global__ __launch_bounds__(256) void gemm128(
    const float* __restrict__ A, const float* __restrict__ B,
    const float* __restrict__ bias, float* __restrict__ C,
    int N, int K,
    const int* __restrict__ gidx,
    const float* __restrict__ X,
    float* __restrict__ parts) {
  __shared__ __align__(16) char smem[17408];
  float (*As)[132] = (float(*)[132])smem;
  float (*Bs)[132] = (float(*)[132])(smem + 8448);

  const int tid = threadIdx.x;
  const int tx = tid & 15;
  const int ty = tid >> 4;
  const int arow = blockIdx.x * 128;
  const int bcol = blockIdx.y * 128;

  const int r0 = tid >> 2;
  const int r1 = r0 + 64;
  const int lc = (tid & 3) * 4;
  int ga0 = arow + r0, ga1 = arow + r1;
  if (MODE == 1) { ga0 = gidx[ga0]; ga1 = gidx[ga1]; }
  const float* Ap0 = A + (size_t)ga0 * K + lc;
  const float* Ap1 = A + (size_t)ga1 * K + lc;

  const int bk0 = tid >> 5;
  const int bc0 = (tid & 31) * 4;
  const float* Bp0 = B + (size_t)bk0 * N + bcol + bc0;
  const float* Bp1 = B + (size_t)(bk0 + 8) * N + bcol + bc0;

  float acc[8][8] = {};

  for (int kt = 0; kt < K; kt += 16) {
    float4 a0 = *reinterpret_cast<const float4*>(Ap0);
    float4 a1 = *reinterpret_cast<const float4*>(Ap1);
    As[lc + 0][r0] = a0.x; As[lc + 1][r0] = a0.y; As[lc + 2][r0] = a0.z; As[lc + 3][r0] = a0.w;
    As[lc + 0][r1] = a1.x; As[lc + 1][r1] = a1.y; As[lc + 2][r1] = a1.z; As[lc + 3][r1] = a1.w;
    float4 b0 = *reinterpret_cast<const float4*>(Bp0);
    float4 b1 = *reinterpret_cast<const float4*>(Bp1);
    *reinterpret_cast<float4*>(&Bs[bk0][bc0]) = b0;
    *reinterpret_cast<float4*>(&Bs[bk0 + 8][bc0]) = b1;
    Bp0 += (size_t)16 * N; Bp1 += (size_t)16 * N;
    Ap0 += 16; Ap1 += 16;
    __syncthreads();
#pragma unroll
    for (int k = 0; k < 16; ++k) {
      float4 av0 = *reinterpret_cast<const float4*>(&As[k][ty * 4]);
      float4 av1 = *reinterpret_cast<const float4*>(&As[k][64 + ty * 4]);
      float4 bv0 = *reinterpret_cast<const float4*>(&Bs[k][tx * 4]);
      float4 bv1 = *reinterpret_cast<const float4*>(&Bs[k][64 + tx * 4]);
      const float a[8] = {av0.x, av0.y, av0.z, av0.w, av1.x, av1.y, av1.z, av1.w};
      const float b[8] = {bv0.x, bv0.y, bv0.z, bv0.w, bv1.x, bv1.y, bv1.z, bv1.w};
#pragma unroll
      for (int i = 0; i < 8; ++i)
#pragma unroll
        for (int j = 0; j < 8; ++j) acc[i][j] += a[i] * b[j];
    }
    __syncthreads();
  }

#pragma unroll
  for (int i = 0; i < 8; ++i) {
    const int row = arow + (i >> 2) * 64 + ty * 4 + (i & 3);
    const int c0 = bcol + tx * 4;
    const int c1 = bcol + 64 + tx * 4;
    float4 v0, v1;
    v0.x = fmaxf(acc[i][0] + bias[c0 + 0], 0.f);
    v0.y = fmaxf(acc[i][1] + bias[c0 + 1], 0.f);
    v0.z = fmaxf(acc[i][2] + bias[c0 + 2], 0.f);
    v0.w = fmaxf(acc[i][3] + bias[c0 + 3], 0.f);
    v1.x = fmaxf(acc[i][4] + bias[c1 + 0], 0.f);
    v1.y = fmaxf(acc[i][5] + bias[c1 + 1], 0.f);
    v1.z = fmaxf(acc[i][6] + bias[c1 + 2], 0.f);
    v1.w = fmaxf(acc[i][7] + bias[c1 + 3], 0.f);
    *reinterpret_cast<float4*>(&C[(size_t)row * N + c0]) = v0;
    *reinterpret_cast<float4*>(&C[(size_t)row * N + c1]) = v1;
  }
}

// ---------------------------------------------------------------------------
// rowsq_z16t: one pass over z_e producing BOTH zsq and z16t.
// Part 1 is byte-identical to the old rowsq (same reads p[lane+64j], same
// shuffle tree) -> zsq bit-identical (exact-rescore dependency).
// Part 2 (tid<128) emits z16t chunks with the identical chunk formula and
// RNE conversion as the old cvt_z16t -> z16t bit-identical. Disjoint outputs.
// Saves a full 134MB z_e re-read + one launch.
// ---------------------------------------------------------------------------
__global__ __launch_bounds__(256) void rowsq_z16t(const float* __restrict__ z_e,
                                                  float* __restrict__ zsq,
                                                  unsigned short* __restrict__ z16t) {
  const int tid = threadIdx.x;
  const int sub = tid >> 6;
  const int lane = tid & 63;
  const int r = blockIdx.x * 4 + sub;
  // part 1: row sum of squares (IDENTICAL to old rowsq)
  {
    const float* p = z_e + (size_t)r * 256;
    float s = 0.f;
#pragma unroll
    for (int j = 0; j < 4; ++j) {
      float v = p[lane + 64 * j];
      s += v * v;
    }
#pragma unroll
    for (int off = 32; off > 0; off >>= 1) s += __shfl_down(s, off, 64);
    if (lane == 0) zsq[r] = s;
  }
  // part 2: z16t chunks (identical formula/values to old cvt_z16t)
  if (tid < 128) {
    const int ri = tid >> 5;                 // 0..3
    const int cid = tid & 31;                // 0..31 chunks per row
    const int r2 = blockIdx.x * 4 + ri;
    const int kb = cid >> 2;                 // 0..7
    const int q = cid & 3;                   // 0..3
    const int k0 = kb * 32 + q * 8;
    const float* p = z_e + (size_t)r2 * 256 + k0;
    const float4 v0 = *reinterpret_cast<const float4*>(p);
    const float4 v1 = *reinterpret_cast<const float4*>(p + 4);
    const float f[8] = {v0.x, v0.y, v0.z, v0.w, v1.x, v1.y, v1.z, v1.w};
    unsigned short s8[8];
#pragma unroll
    for (int j = 0; j < 8; ++j) s8[j] = bf16_rne(f[j]);
    uint4 o;
    o.x = (u32)s8[0] | ((u32)s8[1] << 16);
    o.y = (u32)s8[2] | ((u32)s8[3] << 16);
    o.z = (u32)s8[4] | ((u32)s8[5] << 16);
    o.w = (u32)s8[6] | ((u32)s8[7] << 16);
    const size_t c = (size_t)(r2 >> 8) * 8192 + (size_t)((r2 >> 6) & 3) * 2048 +
                     (size_t)((r2 >> 4) & 3) * 512 + (size_t)kb * 64 +
                     (size_t)q * 16 + (size_t)(r2 & 15);
    *reinterpret_cast<uint4*>(z16t + c * 8) = o;
  }
}

// merged emb conversions (UNCHANGED from r21)
__global__ __launch_bounds__(256) void cvt_emb_all(const float* __restrict__ emb,
                                                   unsigned short* __restrict__ emb16,
                                                   unsigned short* __restrict__ e16f) {
  const int c = blockIdx.x * 256 + threadIdx.x;  // 65536 chunks
  {
    const float4 v0 = *reinterpret_cast<const float4*>(emb + (size_t)c * 8);
    const float4 v1 = *reinterpret_cast<const float4*>(emb + (size_t)c * 8 + 4);
    const float f[8] = {v0.x, v0.y, v0.z, v0.w, v1.x, v1.y, v1.z, v1.w};
    unsigned short s[8];
#pragma unroll
    for (int j = 0; j < 8; ++j) s[j] = bf16_rne(f[j]);
    uint4 o;
    o.x = (u32)s[0] | ((u32)s[1] << 16);
    o.y = (u32)s[2] | ((u32)s[3] << 16);
    o.z = (u32)s[4] | ((u32)s[5] << 16);
    o.w = (u32)s[6] | ((u32)s[7] << 16);
    *reinterpret_cast<uint4*>(emb16 + (size_t)c * 8) = o;
  }
  {
    const int l = c & 63;
    const int fc = (c >> 6) & 7;
    const int t = c >> 9;
    const int kb = t & 7;
    const int ct = t >> 3;
    const int col = ct * 128 + fc * 16 + (l & 15);
    const int k0 = kb * 32 + (l >> 4) * 8;
    const float* p = emb + (size_t)col * 256 + k0;
    const float4 v0 = *reinterpret_cast<const float4*>(p);
    const float4 v1 = *reinterpret_cast<const float4*>(p + 4);
    const float f[8] = {v0.x, v0.y, v0.z, v0.w, v1.x, v1.y, v1.z, v1.w};
    unsigned short s8[8];
#pragma unroll
    for (int j = 0; j < 8; ++j) s8[j] = bf16_rne(f[j]);
    uint4 o;
    o.x = (u32)s8[0] | ((u32)s8[1] << 16);
    o.y = (u32)s8[2] | ((u32)s8[3] << 16);
    o.z = (u32)s8[4] | ((u32)s8[5] << 16);
    o.w = (u32)s8[6] | ((u32)s8[7] << 16);
    *reinterpret_cast<uint4*>(e16f + (size_t)c * 8) = o;
  }
}

// weights -> fragment-major bf16 (UNCHANGED)
__global__ __launch_bounds__(256) void cvt_w16f(const float* __restrict__ W,
                                                unsigned short* __restrict__ Wf,
                                                int N, int total) {
  const int c = blockIdx.x * 256 + threadIdx.x;
  if (c >= total) return;
  const int l = c & 63;
  const int f = c >> 6;
  const int ng = N >> 4;
  const int cg = f % ng;
  const int kb = f / ng;
  const int col = cg * 16 + (l & 15);
  const int k0 = kb * 32 + ((l >> 4) & 3) * 8;
  unsigned short s[8];
#pragma unroll
  for (int j = 0; j < 8; ++j) s[j] = bf16_rne(W[(size_t)(k0 + j) * N + col]);
  uint4 o;
  o.x = (u32)s[0] | ((u32)s[1] << 16);
  o.y = (u32)s[2] | ((u32)s[3] << 16);
  o.z = (u32)s[4] | ((u32)s[5] << 16);
  o.w = (u32)s[6] | ((u32)s[7] << 16);
  *reinterpret_cast<uint4*>(Wf + (size_t)c * 8) = o;
}

// ---------------------------------------------------------------------------
// dist_g256 (UNCHANGED from r20/21 — best-measured; parked).
// ---------------------------------------------------------------------------
__global__ __launch_bounds__(256, 1) void dist_g256(
    const unsigned short* __restrict__ z16t, const unsigned short* __restrict__ e16f,
    const float* __restrict__ zf, const float* __restrict__ ef,
    const float* __restrict__ zsq, const float* __restrict__ esq,
    const float* __restrict__ maxesq, u64_t* __restrict__ keys) {
  __shared__ float esq_lds[2048];
  __shared__ float me1_lds[256];
  __shared__ float rowmin_lds[256];
  __shared__ unsigned cand[CAND_CAP];
  __shared__ unsigned cnt;

  const int tid = threadIdx.x;
  const int l = tid & 63;
  const int w = tid >> 6;
  const int l15 = tid & 15;
  const int lk = (tid >> 4) & 3;
  const int arow = blockIdx.x * 256;

  if (tid == 0) cnt = 0;
  {
    for (int i = tid; i < 2048; i += 256) esq_lds[i] = esq[i];
    me1_lds[tid] = 0.009765625f * sqrtf(zsq[arow + tid]);  // 1.25 * 2^-7
    rowmin_lds[tid] = 3.402823466e38f;
    keys[arow + tid] = ~0ull;  // block-exclusive rows; init before barrier
  }
  const float semax = sqrtf(maxesq[0]);

  bf16x8 a[4][8];
  {
    const char* zb = (const char*)z16t + (size_t)blockIdx.x * 131072 + w * 32768 + l * 16;
#pragma unroll
    for (int fr = 0; fr < 4; ++fr)
#pragma unroll
      for (int kb = 0; kb < 8; ++kb)
        a[fr][kb] = *reinterpret_cast<const bf16x8*>(zb + fr * 8192 + kb * 1024);
  }

  auto rescore = [&](unsigned e) {  // exact ascending-k chain (bit-exact)
    const int row = arow + (int)(e >> 11);
    const int col = (int)(e & 2047u);
    const float* zp = zf + (size_t)row * 256;
    const float* ep = ef + (size_t)col * 256;
    float p = 0.f;
#pragma unroll 8
    for (int k4 = 0; k4 < 256; k4 += 4) {
      const float4 zv = *reinterpret_cast<const float4*>(zp + k4);
      const float4 ev = *reinterpret_cast<const float4*>(ep + k4);
      p = fmaf(zv.x, ev.x, p);
      p = fmaf(zv.y, ev.y, p);
      p = fmaf(zv.z, ev.z, p);
      p = fmaf(zv.w, ev.w, p);
    }
    const float dsc = (zsq[row] - 2.f * p) + esq[col];
    const u64_t kk = ((u64_t)f32_key(dsc) << 32) | (unsigned)col;
    atomicMin(&keys[row], kk);
  };

  __syncthreads();

  const char* eb = (const char*)e16f + (size_t)l * 16;
  const int ct0 = (int)((blockIdx.x * 5u + (unsigned)w * 4u) & 15u);

  f32x4 acc[4][8];
#pragma unroll
  for (int fr = 0; fr < 4; ++fr)
#pragma unroll
    for (int fc = 0; fc < 8; ++fc) acc[fr][fc] = (f32x4){0.f, 0.f, 0.f, 0.f};

  bf16x8 bc[8], bn[8];
#pragma unroll
  for (int fc = 0; fc < 8; ++fc)
    bc[fc] = *reinterpret_cast<const bf16x8*>(eb + (size_t)(ct0 * 8) * 8192 + fc * 1024);

#pragma unroll 1
  for (int ctl = 0; ctl < 16; ++ctl) {
    const int ct = (ct0 + ctl) & 15;
#pragma unroll
    for (int kb = 0; kb < 8; ++kb) {
      const int nctl = (kb == 7) ? ctl + 1 : ctl;
      const int nkb = (kb == 7) ? 0 : kb + 1;
      if (nctl < 16) {
        const int nct = (ct0 + nctl) & 15;
        const char* tb = eb + (size_t)(nct * 8 + nkb) * 8192;
#pragma unroll
        for (int fc = 0; fc < 8; ++fc)
          bn[fc] = *reinterpret_cast<const bf16x8*>(tb + fc * 1024);
      }
#pragma unroll
      for (int fr = 0; fr < 4; ++fr)
#pragma unroll
        for (int fc = 0; fc < 8; ++fc)
          acc[fr][fc] = __builtin_amdgcn_mfma_f32_16x16x32_bf16(a[fr][kb], bc[fc], acc[fr][fc], 0, 0, 0);
#pragma unroll
      for (int fc = 0; fc < 8; ++fc) bc[fc] = bn[fc];
    }
    {
      float esqv[8], se[8];
#pragma unroll
      for (int fc = 0; fc < 8; ++fc) {
        esqv[fc] = esq_lds[ct * 128 + fc * 16 + l15];
        se[fc] = sqrtf(esqv[fc]);
      }
#pragma unroll
      for (int fr = 0; fr < 4; ++fr)
#pragma unroll
        for (int rg = 0; rg < 4; ++rg) {
          float s8[8];
          float lm = 3.402823466e38f;
#pragma unroll
          for (int fc = 0; fc < 8; ++fc) {
            s8[fc] = fmaf(-2.f, acc[fr][fc][rg], esqv[fc]);
            lm = fminf(lm, s8[fc]);
          }
#pragma unroll
          for (int m = 1; m < 16; m <<= 1) lm = fminf(lm, __shfl_xor(lm, m, 64));
          const int row = w * 64 + fr * 16 + lk * 4 + rg;
          const float rm = fminf(rowmin_lds[row], lm);
          if (l15 == 0) rowmin_lds[row] = rm;
          const float me1 = me1_lds[row];
#pragma unroll
          for (int fc = 0; fc < 8; ++fc) {
            const float thr = rm + me1 * (se[fc] + semax) + 1e-7f;
            if (s8[fc] <= thr) {
              const unsigned code =
                  ((unsigned)row << 11) | (unsigned)(ct * 128 + fc * 16 + l15);
              const unsigned idx = atomicAdd(&cnt, 1u);
              if (idx < CAND_CAP) cand[idx] = code;
              else rescore(code);
            }
          }
        }
#pragma unroll
      for (int fr = 0; fr < 4; ++fr)
#pragma unroll
        for (int fc = 0; fc < 8; ++fc) acc[fr][fc] = (f32x4){0.f, 0.f, 0.f, 0.f};
    }
  }

  __syncthreads();
  const unsigned nc = cnt < CAND_CAP ? cnt : CAND_CAP;
  for (unsigned i = tid; i < nc; i += 256) rescore(cand[i]);
}

// ---------------------------------------------------------------------------
// dec_mfma (UNCHANGED — validated). bf16 MFMA decoder layer.
// ---------------------------------------------------------------------------
template <int K, int NT, int NTOT, bool GATHER, bool LOSS>
__global__ __launch_bounds__(256, 1) void dec_mfma(
    const unsigned short* __restrict__ A16, const unsigned short* __restrict__ Wf,
    const float* __restrict__ bias, unsigned short* __restrict__ C16,
    const float* __restrict__ X, float* __restrict__ parts,
    const int* __restrict__ gidx) {
  constexpr int CH = K / 8;
  constexpr int KB = K / 32;
  constexpr int CG = NT / 16;
  constexpr int NB = NTOT / NT;
  __shared__ __align__(16) unsigned short Atile[128 * K];
  __shared__ int idx_l[128];
  __shared__ float rbuf[256];

  const int tid = threadIdx.x;
  const int l = tid & 63;
  const int w = tid >> 6;
  const int arow = (int)(blockIdx.x / NB) * 128;
  const int bcol = (int)(blockIdx.x % NB) * NT;

  if (GATHER) {
    if (tid < 128) idx_l[tid] = gidx[arow + tid];
    __syncthreads();
  }
  for (int q = tid; q < 128 * CH; q += 256) {
    const int r = q / CH;
    const int c = q % CH;
    const unsigned short* src = GATHER
        ? A16 + (size_t)idx_l[r] * K + c * 8
        : A16 + (size_t)(arow + r) * K + c * 8;
    const uint4 v = *reinterpret_cast<const uint4*>(src);
    *reinterpret_cast<uint4*>(&Atile[(r * CH + (c ^ (r & 7))) * 8]) = v;
  }

  bf16x8 wf[KB][CG];
#pragma unroll
  for (int kb = 0; kb < KB; ++kb)
#pragma unroll
    for (int cg = 0; cg < CG; ++cg)
      wf[kb][cg] = *reinterpret_cast<const bf16x8*>(
          Wf + ((size_t)(kb * (NTOT / 16) + bcol / 16 + cg) * 64 + l) * 8);

  __syncthreads();

  f32x4 acc[2][CG];
#pragma unroll
  for (int fr = 0; fr < 2; ++fr)
#pragma unroll
    for (int cg = 0; cg < CG; ++cg) acc[fr][cg] = (f32x4){0.f, 0.f, 0.f, 0.f};

#pragma unroll
  for (int kb = 0; kb < KB; ++kb) {
    bf16x8 af[2];
#pragma unroll
    for (int fr = 0; fr < 2; ++fr) {
      const int r = w * 32 + fr * 16 + (l & 15);
      const int c = (kb * 4 + ((l >> 4) & 3)) ^ (r & 7);
      af[fr] = *reinterpret_cast<const bf16x8*>(&Atile[(r * CH + c) * 8]);
    }
#pragma unroll
    for (int fr = 0; fr < 2; ++fr)
#pragma unroll
      for (int cg = 0; cg < CG; ++cg)
        acc[fr][cg] = __builtin_amdgcn_mfma_f32_16x16x32_bf16(af[fr], wf[kb][cg], acc[fr][cg], 0, 0, 0);
  }

  if (!LOSS) {
#pragma unroll
    for (int fr = 0; fr < 2; ++fr)
#pragma unroll
      for (int cg = 0; cg < CG; ++cg) {
        const int col = bcol + cg * 16 + (l & 15);
        const float bv = bias[col];
#pragma unroll
        for (int rg = 0; rg < 4; ++rg) {
          const int row = arow + w * 32 + fr * 16 + ((l >> 4) & 3) * 4 + rg;
          const float v = fmaxf(acc[fr][cg][rg] + bv, 0.f);
          C16[(size_t)row * NTOT + col] = bf16_rne(v);
        }
      }
  } else {
    float local = 0.f;
#pragma unroll
    for (int fr = 0; fr < 2; ++fr)
#pragma unroll
      for (int cg = 0; cg < CG; ++cg) {
        const int col = bcol + cg * 16 + (l & 15);
        const float bv = bias[col];
#pragma unroll
        for (int rg = 0; rg < 4; ++rg) {
          const int row = arow + w * 32 + fr * 16 + ((l >> 4) & 3) * 4 + rg;
          const float v = fmaxf(acc[fr][cg][rg] + bv, 0.f);
          const float d = v - X[(size_t)row * NTOT + col];
          local = fmaf(d, d, local);
        }
      }
    rbuf[tid] = local;
    __syncthreads();
    for (int off = 128; off > 0; off >>= 1) {
      if (tid < off) rbuf[tid] += rbuf[tid + off];
      __syncthreads();
    }
    if (tid == 0) parts[blockIdx.x] = rbuf[0];
  }
}

__global__ __launch_bounds__(256) void max_esq(const float* __restrict__ esq,
                                               float* __restrict__ outv) {
  __shared__ float red[256];
  float m = 0.f;
  for (int i = threadIdx.x; i < KE; i += 256) m = fmaxf(m, esq[i]);
  red[threadIdx.x] = m;
  __syncthreads();
  for (int off = 128; off > 0; off >>= 1) {
    if (threadIdx.x < off) red[threadIdx.x] = fmaxf(red[threadIdx.x], red[threadIdx.x + off]);
    __syncthreads();
  }
  if (threadIdx.x == 0) outv[0] = red[0];
}

// sum of squares per row (emb only now)
__global__ __launch_bounds__(256) void rowsq(const float* __restrict__ src,
                                             float* __restrict__ dst, int rows) {
  const int sub = threadIdx.x >> 6;
  const int lane = threadIdx.x & 63;
  const int r = blockIdx.x * 4 + sub;
  if (r >= rows) return;
  const float* p = src + (size_t)r * 256;
  float s = 0.f;
#pragma unroll
  for (int j = 0; j < 4; ++j) {
    float v = p[lane + 64 * j];
    s += v * v;
  }
#pragma unroll
  for (int off = 32; off > 0; off >>= 1) s += __shfl_down(s, off, 64);
  if (lane == 0) dst[r] = s;
}

// per row: idx from key, write z_latent = z + (e - z), quant-loss partial sums
__global__ __launch_bounds__(256) void gather_quant(
    const u64_t* __restrict__ keys, const float* __restrict__ emb,
    const float* __restrict__ z_e, float* __restrict__ zlat,
    int* __restrict__ idx_out, float* __restrict__ qparts) {
  const int sub = threadIdx.x >> 6;
  const int lane = threadIdx.x & 63;
  const int r = blockIdx.x * 4 + sub;
  const int idx = (int)(keys[r] & 0xFFFFFFFFull);
  if (lane == 0) idx_out[r] = idx;
  float s = 0.f;
#pragma unroll
  for (int j = 0; j < 4; ++j) {
    const int d = lane + 64 * j;
    float e = emb[(size_t)idx * 256 + d];
    float z = z_e[(size_t)r * 256 + d];
    float df = e - z;
    s += df * df;
    zlat[(size_t)r * 256 + d] = z + df;  // fl(z_e + fl(z_q - z_e)) — exact ref order
  }
#pragma unroll
  for (int off = 32; off > 0; off >>= 1) s += __shfl_down(s, off, 64);
  __shared__ float red[4];
  if (lane == 0) red[sub] = s;
  __syncthreads();
  if (threadIdx.x == 0) qparts[blockIdx.x] = (red[0] + red[1]) + (red[2] + red[3]);
}

__global__ __launch_bounds__(256) void final_loss(
    const float* __restrict__ qparts, int nq,
    const float* __restrict__ rparts, int nr, float* __restrict__ out) {
  const int tid = threadIdx.x;
  double sq = 0.0, sr = 0.0;
  for (int i = tid; i < nq; i += 256) sq += (double)qparts[i];
  for (int i = tid; i < nr; i += 256) sr += (double)rparts[i];
  __shared__ double bq[256], br[256];
  bq[tid] = sq;
  br[tid] = sr;
  __syncthreads();
  for (int off = 128; off > 0; off >>= 1) {
    if (tid < off) {
      bq[tid] += bq[tid + off];
      br[tid] += br[tid + off];
    }
    __syncthreads();
  }
  if (tid == 0) {
    double qm = bq[0] / ((double)NROWS * 256.0);
    double rm = br[0] / ((double)NROWS * 512.0);
    out[(size_t)NROWS * 256] = (float)(rm + 1.25 * qm);  // recon + (1+BETA)*quant
  }
}

extern "C" void kernel_launch(void* const* d_in, const int* in_sizes, int n_in,
                              void* d_out, int out_size, void* d_ws, size_t ws_size,
                              hipStream_t stream) {
  const float* x   = (const float*)d_in[0];
  const float* ew1 = (const float*)d_in[1];
  const float* eb1 = (const float*)d_in[2];
  const float* ew2 = (const float*)d_in[3];
  const float* eb2 = (const float*)d_in[4];
  const float* ew3 = (const float*)d_in[5];
  const float* eb3 = (const float*)d_in[6];
  const float* dw1 = (const float*)d_in[7];
  const float* db1 = (const float*)d_in[8];
  const float* dw2 = (const float*)d_in[9];
  const float* db2 = (const float*)d_in[10];
  const float* dw3 = (const float*)d_in[11];
  const float* db3 = (const float*)d_in[12];
  const float* emb = (const float*)d_in[13];

  char* ws = (char*)d_ws;
  // region A (0..33.5MB): enc h1 f32 -> {e16f, maxesq, emb16, w*f} after enc2
  float* h1            = (float*)(ws);
  unsigned short* e16f = (unsigned short*)(ws);               // 1 MB
  float* maxesq        = (float*)(ws + 2097152ull);           // 256 B
  unsigned short* emb16 = (unsigned short*)(ws + 4194304ull); // 1 MB
  unsigned short* w1f  = (unsigned short*)(ws + 5242880ull);  // 64 KB
  unsigned short* w2f  = (unsigned short*)(ws + 5308416ull);  // 16 KB
  unsigned short* w3f  = (unsigned short*)(ws + 5324800ull);  // 64 KB
  // region B (33.5..100.6MB): enc h2 f32 -> z16t -> {h2_16, h1_16} after dist
  float* h2            = (float*)(ws + 33554432ull);
  unsigned short* z16t = (unsigned short*)(ws + 33554432ull);   // 67 MB
  unsigned short* h2_16 = (unsigned short*)(ws + 33554432ull);  // 33.5 MB
  unsigned short* h1_16 = (unsigned short*)(ws + 67108864ull);  // 16.8 MB
  // persistent
  float* z_e    = (float*)(ws + 100663296ull);   // N x 256
  float* zsq    = (float*)(ws + 234881024ull);   // N
  float* esq    = (float*)(ws + 235405312ull);   // KE
  u64_t* keys   = (u64_t*)(ws + 235413504ull);   // N
  int* idx      = (int*)(ws + 236462080ull);     // N
  float* qparts = (float*)(ws + 236986368ull);   // N/4
  float* rparts = (float*)(ws + 237117440ull);   // 2048

  float* out = (float*)d_out;
  dim3 blk(256);

  // encoder: 512 -> 64 -> 128 -> 256 (bit-exact z_e path)
  enc1_128x64<<<dim3(NROWS / 128), blk, 0, stream>>>(x, ew1, eb1, h1);
  gemm128<0><<<dim3(NROWS / 128, 1), blk, 0, stream>>>(h1, ew2, eb2, h2,
      128, 64, nullptr, nullptr, nullptr);
  // h1 (region A) dead: decoder-side conversions (independent of z_e)
  cvt_emb_all<<<dim3(KE * 256 / 8 / 256), blk, 0, stream>>>(emb, emb16, e16f);
  cvt_w16f<<<dim3(16), blk, 0, stream>>>(dw1, w1f, 128, 4096);
  cvt_w16f<<<dim3(4), blk, 0, stream>>>(dw2, w2f, 64, 1024);
  cvt_w16f<<<dim3(16), blk, 0, stream>>>(dw3, w3f, 512, 4096);
  gemm128<0><<<dim3(NROWS / 128, 2), blk, 0, stream>>>(h2, ew3, eb3, z_e,
      256, 128, nullptr, nullptr, nullptr);

  // fused: zsq (bit-identical reduction) + z16t (bit-identical conversion)
  rowsq_z16t<<<dim3(NROWS / 4), blk, 0, stream>>>(z_e, zsq, z16t);
  rowsq<<<dim3(KE / 4), blk, 0, stream>>>(emb, esq, KE);
  max_esq<<<dim3(1), blk, 0, stream>>>(esq, maxesq);

  // bound + deferred exact rescore (bit-identical selection); keys init folded
  dist_g256<<<dim3(NROWS / 256), blk, 0, stream>>>(z16t, e16f, z_e, emb, zsq, esq,
      maxesq, keys);

  gather_quant<<<dim3(NROWS / 4), blk, 0, stream>>>(keys, emb, z_e, out, idx, qparts);

  // decoder: bf16 MFMA (loss-only path, 2% threshold; z16t dead -> h*_16)
  dec_mfma<256, 128, 128, true, false><<<dim3(NROWS / 128), blk, 0, stream>>>(
      emb16, w1f, db1, h2_16, nullptr, nullptr, idx);
  dec_mfma<128, 64, 64, false, false><<<dim3(NROWS / 128), blk, 0, stream>>>(
      h2_16, w2f, db2, h1_16, nullptr, nullptr, nullptr);
  dec_mfma<64, 256, 512, false, true><<<dim3((NROWS / 128) * 2), blk, 0, stream>>>(
      h1_16, w3f, db3, nullptr, x, rparts, nullptr);

  final_loss<<<dim3(1), blk, 0, stream>>>(qparts, NROWS / 4, rparts, 2048, out);
}